// Round 11
// baseline (564.538 us; speedup 1.0000x reference)
//
#include <hip/hip_runtime.h>
#include <hip/hip_bf16.h>

// GAT 3-layer: N=50000 nodes, E=800000 edges, H=6 heads.
// R1-R17: MFMA GEMMs + CSR fused softmax/aggregate ladder (545us).
// R20/R21: wave-per-node aggregates; h -> fp8 e4m3 (absmax 2.4e-4 passes).
// R22-R25: GEMM invariant under store/stage/pipeline/precision changes ->
//      per-block fixed overhead; R26: MT=4 M-tiles/block + persistent-B LDS
//      -> GEMMs out of top-5 (527us). R27: fp8 h for L1/L2 too (513us).
// R28: agg3 FETCH = 8 XCDs x full 19.2MB fp8 array (doesn't fit 4MB L2).
//      Fix: L3 h stored SLICE-MAJOR (8 slices x 48ch; 2.4MB/slice) and
//      aggregate blocks pinned slice->XCD via blockIdx&7 (round-robin
//      dispatch heuristic, same as the working m204 swizzle) -> per-XCD
//      working set 2.4MB h + 1.2MB es = L2-resident. + packed f32x2 FMA
//      (v_pk_fma_f32) in all aggregate accumulators. Downside bound: if the
//      XCD mapping is wrong, slicing is fetch-neutral.

#define HHEADS 6

typedef __attribute__((ext_vector_type(8))) short bf16x8;   // 8 bf16 = 4 VGPR
typedef __attribute__((ext_vector_type(4))) float f32x4;    // mfma C/D
typedef __attribute__((ext_vector_type(2))) float f32x2;

typedef __attribute__((address_space(3))) unsigned int lds_uint;
typedef const __attribute__((address_space(1))) unsigned int glb_uint;

__device__ __forceinline__ float bfl(unsigned u) { return __uint_as_float(u << 16); }
__device__ __forceinline__ float bfh(unsigned u) { return __uint_as_float(u & 0xffff0000u); }
__device__ __forceinline__ unsigned short f2bf(float v) {  // RNE f32->bf16
    unsigned u = __float_as_uint(v);
    return (unsigned short)((u + 0x7fffu + ((u >> 16) & 1u)) >> 16);
}
__device__ __forceinline__ float bf2f(unsigned short h) {
    return __uint_as_float((unsigned)h << 16);
}
// monotone float<->uint for atomicMax on floats (memset-0 = -inf identity)
__device__ __forceinline__ unsigned fkey(float f) {
    unsigned u = __float_as_uint(f);
    return (u >> 31) ? ~u : (u | 0x80000000u);
}
__device__ __forceinline__ float funkey(unsigned k) {
    return (k >> 31) ? __uint_as_float(k & 0x7fffffffu) : __uint_as_float(~k);
}

// 4x4 transpose across a 4-lane group (lanes share lane>>2). In: v0..v3 =
// rows 0..3 at this lane's column. Out: v0..v3 = cols 0..3 at row (lane&3).
__device__ __forceinline__ void xpose4(float& v0, float& v1, float& v2, float& v3, int b) {
    bool hi = (b & 2) != 0;
    float s0 = hi ? v0 : v2;
    float s1 = hi ? v1 : v3;
    s0 = __shfl_xor(s0, 2, 64);
    s1 = __shfl_xor(s1, 2, 64);
    v0 = hi ? s0 : v0;
    v1 = hi ? s1 : v1;
    v2 = hi ? v2 : s0;
    v3 = hi ? v3 : s1;
    bool od = (b & 1) != 0;
    float t0 = od ? v0 : v1;
    t0 = __shfl_xor(t0, 1, 64);
    v0 = od ? t0 : v0;
    v1 = od ? v1 : t0;
    float t1 = od ? v2 : v3;
    t1 = __shfl_xor(t1, 1, 64);
    v2 = od ? t1 : v2;
    v3 = od ? v3 : t1;
}

// ---------------- one-shot zero of all small scratch ----------------
__global__ void zero_misc(int* __restrict__ count, int* __restrict__ cursor,
                          float* __restrict__ g, unsigned* __restrict__ gmax,
                          unsigned short* __restrict__ apH,
                          long pad3_off, long pad3_cnt, long pad6_off, long pad6_cnt, int n) {
    long i = (long)blockIdx.x * blockDim.x + threadIdx.x;
    long stride = (long)gridDim.x * blockDim.x;
    for (long j = i; j < n; j += stride) {
        count[j] = 0;
        cursor[j] = 0;
    }
    if (i < 384) g[i] = 0.f;
    if (i < 12) gmax[i] = 0u;  // slots 0-5: L3, 6-11: L2
    for (long j = i; j < pad3_cnt; j += stride) apH[pad3_off + j] = 0;
    for (long j = i; j < pad6_cnt; j += stride) apH[pad6_off + j] = 0;
}

// ---------------- CSR build ----------------
__global__ void hist_kernel(const int* __restrict__ dst, int* __restrict__ count, int E) {
    int e = blockIdx.x * blockDim.x + threadIdx.x;
    if (e >= E) return;
    atomicAdd(&count[dst[e]], 1);
}

__global__ void scan_block(const int* __restrict__ count, int* __restrict__ offsets,
                           int* __restrict__ bsum, int n) {
    __shared__ int s[1024];
    int i = blockIdx.x * 1024 + threadIdx.x;
    int v = (i < n) ? count[i] : 0;
    s[threadIdx.x] = v;
    __syncthreads();
    for (int off = 1; off < 1024; off <<= 1) {
        int t = (threadIdx.x >= (unsigned)off) ? s[threadIdx.x - off] : 0;
        __syncthreads();
        s[threadIdx.x] += t;
        __syncthreads();
    }
    if (i < n) offsets[i] = s[threadIdx.x] - v;
    if (threadIdx.x == 1023) bsum[blockIdx.x] = s[1023];
}

__global__ void scan_tops(int* __restrict__ bsum, int nb) {
    __shared__ int s[64];
    int t = threadIdx.x;
    int v = (t < nb) ? bsum[t] : 0;
    s[t] = v;
    __syncthreads();
    for (int off = 1; off < 64; off <<= 1) {
        int tmp = (t >= off) ? s[t - off] : 0;
        __syncthreads();
        s[t] += tmp;
        __syncthreads();
    }
    if (t < nb) bsum[t] = s[t] - v;
}

__global__ void scan_add(int* __restrict__ offsets, const int* __restrict__ bsum, int n,
                         int total) {
    int i = blockIdx.x * 1024 + threadIdx.x;
    if (i < n) offsets[i] += bsum[blockIdx.x];
    if (i == 0) offsets[n] = total;
}

__global__ void scatter_kernel(const int* __restrict__ src, const int* __restrict__ dst,
                               const int* __restrict__ offsets, int* __restrict__ cursor,
                               int* __restrict__ ssrc, int E) {
    int e = blockIdx.x * blockDim.x + threadIdx.x;
    if (e >= E) return;
    int d = dst[e];
    int pos = offsets[d] + atomicAdd(&cursor[d], 1);
    ssrc[pos] = src[e];
}

// ---------------- weight repacks ----------------
__global__ void repack_w(const float* __restrict__ W, float* __restrict__ Wp, int FIN, int F) {
    int HF = HHEADS * F;
    int i = blockIdx.x * blockDim.x + threadIdx.x;
    if (i >= FIN * HF) return;
    int k = i / HF, c = i % HF;
    int hd = c / F, f = c % F;
    Wp[i] = W[(hd * FIN + k) * F + f];
}

// bf16 pack in MFMA B-fragment layout (B^T: lane n=..&15, k contiguous)
__global__ void repack_w_mfma(const float* __restrict__ W, unsigned short* __restrict__ bh,
                              int FIN, int F, int NPAD) {
    int i = blockIdx.x * blockDim.x + threadIdx.x;
    if (i >= FIN * NPAD) return;
    int k = i / NPAD, n = i % NPAD;
    int NKT = FIN / 32;
    int HF = HHEADS * F;
    float w = 0.f;
    if (n < HF) {
        int hd = n / F, f = n % F;
        w = W[(hd * FIN + k) * F + f];
    }
    size_t e = ((size_t)((n >> 4) * NKT + (k >> 5)) * 64 + ((n & 15) | (((k >> 3) & 3) << 4))) * 8 +
               (k & 7);
    bh[e] = f2bf(w);
}

// ---------------- small GEMM + fused attn (layer 1, K=11, F=16) ----------------
// C written fp8 e4m3 (feeds only aggregate_fused).
template <int BM, int BN, int BK>
__global__ __launch_bounds__(256) void gemm_small_attn(const float* __restrict__ A,
                                                       const float* __restrict__ B,
                                                       unsigned char* __restrict__ C8,
                                                       const float* __restrict__ as_,
                                                       const float* __restrict__ ad_,
                                                       float* __restrict__ es,
                                                       float* __restrict__ ed, int M, int K,
                                                       int N) {
    __shared__ float As[BK][BM + 4];
    __shared__ float Bs[BK][BN];
    int tid = threadIdx.x;
    int tx = tid % 16, ty = tid / 16;
    int m0 = blockIdx.y * BM, n0 = blockIdx.x * BN;
    float acc[4][4] = {};
    for (int kk0 = 0; kk0 < K; kk0 += BK) {
#pragma unroll
        for (int i = 0; i < (BM * BK) / 256; ++i) {
            int idx = tid + i * 256;
            int m = idx / BK, k = idx % BK;
            float v = 0.f;
            if (m0 + m < M && kk0 + k < K) v = A[(size_t)(m0 + m) * K + kk0 + k];
            As[k][m] = v;
        }
#pragma unroll
        for (int i = 0; i < (BK * BN) / 1024; ++i) {
            int idx = tid + i * 256;
            int k = idx / (BN / 4), n4 = idx % (BN / 4);
            float4 v = make_float4(0.f, 0.f, 0.f, 0.f);
            if (kk0 + k < K && n0 + n4 * 4 < N)
                v = *(const float4*)&B[(size_t)(kk0 + k) * N + n0 + n4 * 4];
            *(float4*)&Bs[k][n4 * 4] = v;
        }
        __syncthreads();
#pragma unroll
        for (int k = 0; k < BK; ++k) {
            float4 av = *(const float4*)&As[k][ty * 4];
            float4 bv = *(const float4*)&Bs[k][tx * 4];
            float a[4] = {av.x, av.y, av.z, av.w};
            float b[4] = {bv.x, bv.y, bv.z, bv.w};
#pragma unroll
            for (int i = 0; i < 4; ++i)
#pragma unroll
                for (int j = 0; j < 4; ++j) acc[i][j] += a[i] * b[j];
        }
        __syncthreads();
    }
    bool colok = (n0 + tx * 4) < N;
    float asv[4], adv[4];
#pragma unroll
    for (int j = 0; j < 4; ++j) {
        int col = n0 + tx * 4 + j;
        asv[j] = (col < N) ? as_[col] : 0.f;
        adv[j] = (col < N) ? ad_[col] : 0.f;
    }
#pragma unroll
    for (int i = 0; i < 4; ++i) {
        int m = m0 + ty * 4 + i;
        bool mok = m < M;
        if (mok && colok) {
            int pk = __builtin_amdgcn_cvt_pk_fp8_f32(acc[i][0], acc[i][1], 0, false);
            pk = __builtin_amdgcn_cvt_pk_fp8_f32(acc[i][2], acc[i][3], pk, true);
            *(unsigned*)&C8[(size_t)m * N + n0 + tx * 4] = (unsigned)pk;
        }
        float ps = 0.f, pd = 0.f;
#pragma unroll
        for (int j = 0; j < 4; ++j) {
            ps += acc[i][j] * asv[j];
            pd += acc[i][j] * adv[j];
        }
        ps += __shfl_down(ps, 2, 4);
        ps += __shfl_down(ps, 1, 4);
        pd += __shfl_down(pd, 2, 4);
        pd += __shfl_down(pd, 1, 4);
        if (mok && colok && (tx & 3) == 0) {
            int hd = (n0 + tx * 4) >> 4;  // F=16
            es[(size_t)m * HHEADS + hd] = ps;
            ed[(size_t)m * HHEADS + hd] = pd;
        }
    }
}

// ---------------- MFMA bf16 GEMM + fused attn (layers 2/3) ----------------
// MT M-tiles per block; persistent B in LDS; A double-buffered; fp8 C.
// F==64: C SLICE-MAJOR (8 slices x 48ch; slice stride M*48); gmax slots 0-5.
// F==32: C row-major; gmax slots 6-11.
template <int K, int NREAL, int NPAD, int F, int MT>
__global__ __launch_bounds__(256) void gemm_attn_mfma(
    const unsigned short* __restrict__ Ah, const unsigned short* __restrict__ Bh,
    unsigned char* __restrict__ C8, const float* __restrict__ as_,
    const float* __restrict__ ad_, float* __restrict__ es, float* __restrict__ ed,
    unsigned* __restrict__ gmax, int M) {
    constexpr int NKT = K / 32;
    __shared__ unsigned short sB[NKT * 4096];  // persistent B panel
    __shared__ unsigned short sA[2][4096];     // A double buffer
    int tid = threadIdx.x;
    int lane = tid & 63, wave = tid >> 6;
    int wrow = wave >> 1, wcol = wave & 1;
    int quad = lane >> 4, c16 = lane & 15;

    // XCD-bijective swizzle (m204): co-locate blocks sharing B panels.
    int nwg = gridDim.x * gridDim.y;
    int hh = blockIdx.y * gridDim.x + blockIdx.x;
    int q = nwg >> 3, r = nwg & 7;
    int xcd = hh & 7, pos = hh >> 3;
    int wk = (xcd < r ? xcd * (q + 1) : r * (q + 1) + (xcd - r) * q) + pos;
    int bx = wk % gridDim.x, by = wk / gridDim.x;

    int n0 = bx * 128;
    int bn16 = n0 >> 4;
    int nmt = (M + 127) >> 7;  // number of valid 128-row M-tiles

    // ---- stage entire B panel (once) ----
#pragma unroll
    for (int kt2 = 0; kt2 < NKT; ++kt2) {
#pragma unroll
        for (int rep = 0; rep < 2; ++rep) {
            int chunk = tid + rep * 256;
            int tile = chunk >> 6, e8 = chunk & 63;
            size_t boff = ((size_t)((bn16 + tile) * NKT + kt2) * 64 + e8) * 8;
            __builtin_amdgcn_global_load_lds((glb_uint*)&Bh[boff],
                                             (lds_uint*)&sB[kt2 * 4096 + chunk * 8], 16, 0, 0);
        }
    }
    auto STAGE_A = [&](int mti, int kt2, int buf) {
#pragma unroll
        for (int rep = 0; rep < 2; ++rep) {
            int chunk = tid + rep * 256;
            int tile = chunk >> 6, e8 = chunk & 63;
            size_t aoff = ((size_t)((mti * 8 + tile) * NKT + kt2) * 64 + e8) * 8;
            __builtin_amdgcn_global_load_lds((glb_uint*)&Ah[aoff],
                                             (lds_uint*)&sA[buf][chunk * 8], 16, 0, 0);
        }
    };
    STAGE_A(min(by * MT, nmt - 1), 0, 0);
    asm volatile("s_waitcnt vmcnt(0)" ::: "memory");
    __builtin_amdgcn_s_barrier();

    float asv[4], adv[4];
#pragma unroll
    for (int j = 0; j < 4; ++j) {
        int col = n0 + wcol * 64 + j * 16 + c16;
        bool ok = col < NREAL;
        asv[j] = ok ? as_[col] : 0.f;
        adv[j] = ok ? ad_[col] : 0.f;
    }
    float mx = -1e30f;                 // F==64 per-wave head max (across mts)
    float mxA = -1e30f, mxB = -1e30f;  // F==32 per-wave 2-head max
    bool colvalid = (n0 + wcol * 64) < NREAL;
    int b4 = lane & 3;

    f32x4 acc[4][4] = {};
    const int T = MT * NKT;
    int mt = 0, kt = 0;
    for (int t = 0; t < T; ++t) {
        int cur = t & 1;
        int nkt = kt + 1, nmt2 = mt;
        if (nkt == NKT) {
            nkt = 0;
            nmt2 = mt + 1;
        }
        if (t + 1 < T) STAGE_A(min(by * MT + nmt2, nmt - 1), nkt, cur ^ 1);  // issue-early
        bf16x8 fah[4], fbh[4];
#pragma unroll
        for (int i = 0; i < 4; ++i) {
            fah[i] = *(const bf16x8*)&sA[cur][(wrow * 4 + i) * 512 + lane * 8];
            fbh[i] = *(const bf16x8*)&sB[kt * 4096 + (wcol * 4 + i) * 512 + lane * 8];
        }
        asm volatile("s_waitcnt lgkmcnt(0)" ::: "memory");
        __builtin_amdgcn_sched_barrier(0);  // rule #18
#pragma unroll
        for (int i = 0; i < 4; ++i)
#pragma unroll
            for (int j = 0; j < 4; ++j)
                acc[i][j] = __builtin_amdgcn_mfma_f32_16x16x32_bf16(fah[i], fbh[j], acc[i][j],
                                                                    0, 0, 0);
        if (kt == NKT - 1) {  // M-tile complete: epilogue (uniform branch)
            int m0 = (by * MT + mt) * 128;
            if (m0 < M) {
                // ---- es/ed + gmax partial (fragment layout) ----
#pragma unroll
                for (int i = 0; i < 4; ++i) {
#pragma unroll
                    for (int r2 = 0; r2 < 4; ++r2) {
                        int m = m0 + wrow * 64 + i * 16 + quad * 4 + r2;
                        bool mok = m < M;
                        if (F == 64) {
                            float ps = acc[i][0][r2] * asv[0] + acc[i][1][r2] * asv[1] +
                                       acc[i][2][r2] * asv[2] + acc[i][3][r2] * asv[3];
                            float pd = acc[i][0][r2] * adv[0] + acc[i][1][r2] * adv[1] +
                                       acc[i][2][r2] * adv[2] + acc[i][3][r2] * adv[3];
#pragma unroll
                            for (int off = 8; off > 0; off >>= 1) {
                                ps += __shfl_down(ps, off, 16);
                                pd += __shfl_down(pd, off, 16);
                            }
                            if (mok && c16 == 0) {
                                int hd = (n0 + wcol * 64) / 64;
                                es[(size_t)m * HHEADS + hd] = ps;
                                ed[(size_t)m * HHEADS + hd] = pd;
                                mx = fmaxf(mx, ps);
                            }
                        } else {  // F == 32: two heads per wave-column
                            float psA = acc[i][0][r2] * asv[0] + acc[i][1][r2] * asv[1];
                            float pdA = acc[i][0][r2] * adv[0] + acc[i][1][r2] * adv[1];
                            float psB = acc[i][2][r2] * asv[2] + acc[i][3][r2] * asv[3];
                            float pdB = acc[i][2][r2] * adv[2] + acc[i][3][r2] * adv[3];
#pragma unroll
                            for (int off = 8; off > 0; off >>= 1) {
                                psA += __shfl_down(psA, off, 16);
                                pdA += __shfl_down(pdA, off, 16);
                                psB += __shfl_down(psB, off, 16);
                                pdB += __shfl_down(pdB, off, 16);
                            }
                            if (mok && c16 == 0 && colvalid) {
                                int colbase = n0 + wcol * 64;
                                int hd = colbase / 32;
                                es[(size_t)m * HHEADS + hd] = psA;
                                ed[(size_t)m * HHEADS + hd] = pdA;
                                es[(size_t)m * HHEADS + hd + 1] = psB;
                                ed[(size_t)m * HHEADS + hd + 1] = pdB;
                                mxA = fmaxf(mxA, psA);
                                mxB = fmaxf(mxB, psB);
                            }
                        }
                    }
                }
                // ---- C store (fp8): transpose 16x16 blocks, dword stores ----
#pragma unroll
                for (int i = 0; i < 4; ++i) {
                    int m = m0 + wrow * 64 + i * 16 + quad * 4 + b4;
                    bool mok = m < M;
#pragma unroll
                    for (int j = 0; j < 4; ++j) {
                        float v0 = acc[i][j][0], v1 = acc[i][j][1], v2 = acc[i][j][2],
                              v3 = acc[i][j][3];
                        xpose4(v0, v1, v2, v3, b4);
                        int colb = n0 + wcol * 64 + j * 16 + (c16 & 12);
                        if (mok && (F == 64 || colvalid)) {
                            int pk = __builtin_amdgcn_cvt_pk_fp8_f32(v0, v1, 0, false);
                            pk = __builtin_amdgcn_cvt_pk_fp8_f32(v2, v3, pk, true);
                            if (F == 64) {  // slice-major: sl=colb/48, off=colb%48
                                int sl = colb / 48, of = colb - sl * 48;
                                *(unsigned*)&C8[(size_t)sl * ((size_t)M * 48) +
                                                (size_t)m * 48 + of] = (unsigned)pk;
                            } else {
                                *(unsigned*)&C8[(size_t)m * NREAL + colb] = (unsigned)pk;
                            }
                        }
                    }
                }
            }
#pragma unroll
            for (int i = 0; i < 4; ++i)
#pragma unroll
                for (int j = 0; j < 4; ++j) acc[i][j] = (f32x4){0.f, 0.f, 0.f, 0.f};
        }
        asm volatile("s_waitcnt vmcnt(0)" ::: "memory");
        __builtin_amdgcn_s_barrier();
        kt = nkt;
        mt = nmt2;
    }

    if (F == 64) {  // per-head global es max, one atomic per wave per block
#pragma unroll
        for (int off = 32; off > 0; off >>= 1) mx = fmaxf(mx, __shfl_xor(mx, off));
        if (lane == 0) atomicMax(&gmax[(n0 + wcol * 64) / 64], fkey(mx));
    } else {
        mxA = fmaxf(mxA, __shfl_xor(mxA, 16));
        mxA = fmaxf(mxA, __shfl_xor(mxA, 32));
        mxB = fmaxf(mxB, __shfl_xor(mxB, 16));
        mxB = fmaxf(mxB, __shfl_xor(mxB, 32));
        if (lane == 0 && colvalid) {
            int hd = (n0 + wcol * 64) / 32;
            atomicMax(&gmax[6 + hd], fkey(mxA));
            atomicMax(&gmax[6 + hd + 1], fkey(mxB));
        }
    }
}

// ---------------- online-rescale softmax-aggregate (layer 1, fp8 h) -----------
// Thread per (node, 8ch); fp8 gather + HW unpack; packed f32x2 FMA accum.
template <int F>
__global__ __launch_bounds__(256) void aggregate_fused(
    const unsigned char* __restrict__ h8, const float* __restrict__ es,
    const float* __restrict__ ed, const int* __restrict__ offsets,
    const int* __restrict__ ssrc, unsigned short* __restrict__ oh, int n) {
    constexpr int HF = HHEADS * F;
    constexpr int C8 = HF / 8;
    int tid = blockIdx.x * blockDim.x + threadIdx.x;
    if (tid >= n * C8) return;
    int node = tid / C8, q = tid % C8;
    int c = q * 8, hd = c / F;
    int a = offsets[node], b = offsets[node + 1];
    float edv = ed[node * HHEADS + hd];
    float m = -1e30f, l = 0.f;
    f32x2 a0 = {0.f, 0.f}, a1 = {0.f, 0.f}, a2 = {0.f, 0.f}, a3 = {0.f, 0.f};
    for (int j = a; j < b; ++j) {
        int s = ssrc[j];
        float v = es[s * HHEADS + hd] + edv;
        v = v > 0.f ? v : 0.2f * v;  // leaky relu 0.2
        float mn = fmaxf(m, v);
        float r = __expf(m - mn);
        float wgt = __expf(v - mn);
        uint2 hv = *(const uint2*)&h8[(size_t)s * HF + c];
        f32x2 p0 = __builtin_amdgcn_cvt_pk_f32_fp8((int)hv.x, false);
        f32x2 p1 = __builtin_amdgcn_cvt_pk_f32_fp8((int)hv.x, true);
        f32x2 p2 = __builtin_amdgcn_cvt_pk_f32_fp8((int)hv.y, false);
        f32x2 p3 = __builtin_amdgcn_cvt_pk_f32_fp8((int)hv.y, true);
        l = l * r + wgt;
        f32x2 rv = {r, r}, wv = {wgt, wgt};
        a0 = a0 * rv + wv * p0;
        a1 = a1 * rv + wv * p1;
        a2 = a2 * rv + wv * p2;
        a3 = a3 * rv + wv * p3;
        m = mn;
    }
    float invd = 1.0f / (l + 1e-16f);
    float res[8] = {a0[0], a0[1], a1[0], a1[1], a2[0], a2[1], a3[0], a3[1]};
    unsigned short th[8];
#pragma unroll
    for (int k = 0; k < 8; ++k) {
        float v = res[k] * invd;
        v = v > 0.f ? v : (__expf(v) - 1.0f);  // elu
        th[k] = f2bf(v);
    }
    constexpr int NKT = HF / 32;
    int lq = (node & 15) | (((c >> 3) & 3) << 4);
    size_t base = ((size_t)((node >> 4) * NKT + (c >> 5)) * 64 + lq) * 8;
    *(uint4*)&oh[base] = *(uint4*)th;
}

// ---------------- wave-per-node single-pass aggregate (layer 2, fp8 h) --------
// Lanes 0..47 own 4 channels (uint = 4 fp8); packed f32x2 FMA accum.
__global__ __launch_bounds__(256) void aggregate_wpn2(
    const unsigned char* __restrict__ h8, const float* __restrict__ es,
    const float* __restrict__ ed, const unsigned* __restrict__ gmax,
    const int* __restrict__ offsets, const int* __restrict__ ssrc,
    unsigned short* __restrict__ oh, int n) {
    constexpr int HF = 192;
    int wid = (int)((blockIdx.x * (unsigned)blockDim.x + threadIdx.x) >> 6);
    int lane = threadIdx.x & 63;
    if (wid >= n || lane >= 48) return;
    int node = wid;
    int hd = lane >> 3;  // F=32: 8 lanes (32ch) per head
    int c = lane * 4;
    int a = offsets[node], b = offsets[node + 1];
    float edv = ed[node * HHEADS + hd];
    float mv = funkey(gmax[6 + hd]) + edv;
    float m = mv > 0.f ? mv : 0.2f * mv;
    float l = 0.f;
    f32x2 a0 = {0.f, 0.f}, a1 = {0.f, 0.f};
    const unsigned char* hbase = h8 + c;
    int j = a;
    for (; j + 1 < b; j += 2) {
        int s0 = ssrc[j], s1 = ssrc[j + 1];
        float ev0 = es[(size_t)s0 * HHEADS + hd];
        float ev1 = es[(size_t)s1 * HHEADS + hd];
        unsigned h0 = *(const unsigned*)(hbase + (size_t)s0 * HF);
        unsigned h1 = *(const unsigned*)(hbase + (size_t)s1 * HF);
        float v0 = ev0 + edv;
        v0 = v0 > 0.f ? v0 : 0.2f * v0;
        float v1 = ev1 + edv;
        v1 = v1 > 0.f ? v1 : 0.2f * v1;
        float w0 = __expf(v0 - m);
        float w1 = __expf(v1 - m);
        {
            f32x2 p0 = __builtin_amdgcn_cvt_pk_f32_fp8((int)h0, false);
            f32x2 p1 = __builtin_amdgcn_cvt_pk_f32_fp8((int)h0, true);
            f32x2 wv = {w0, w0};
            l += w0;
            a0 = a0 + wv * p0;
            a1 = a1 + wv * p1;
        }
        {
            f32x2 p0 = __builtin_amdgcn_cvt_pk_f32_fp8((int)h1, false);
            f32x2 p1 = __builtin_amdgcn_cvt_pk_f32_fp8((int)h1, true);
            f32x2 wv = {w1, w1};
            l += w1;
            a0 = a0 + wv * p0;
            a1 = a1 + wv * p1;
        }
    }
    if (j < b) {
        int s0 = ssrc[j];
        float ev0 = es[(size_t)s0 * HHEADS + hd];
        unsigned h0 = *(const unsigned*)(hbase + (size_t)s0 * HF);
        float v0 = ev0 + edv;
        v0 = v0 > 0.f ? v0 : 0.2f * v0;
        float w0 = __expf(v0 - m);
        f32x2 p0 = __builtin_amdgcn_cvt_pk_f32_fp8((int)h0, false);
        f32x2 p1 = __builtin_amdgcn_cvt_pk_f32_fp8((int)h0, true);
        f32x2 wv = {w0, w0};
        l += w0;
        a0 = a0 + wv * p0;
        a1 = a1 + wv * p1;
    }
    float invd = 1.0f / (l + 1e-16f);
    float res[4] = {a0[0], a0[1], a1[0], a1[1]};
    unsigned short th[4];
#pragma unroll
    for (int k = 0; k < 4; ++k) {
        float v = res[k] * invd;
        v = v > 0.f ? v : (__expf(v) - 1.0f);  // elu
        th[k] = f2bf(v);
    }
    int lq = (node & 15) | (((c >> 3) & 3) << 4);
    size_t base = ((size_t)((node >> 4) * (HF / 32) + (c >> 5)) * 64 + lq) * 8 + (c & 7);
    *(uint2*)&oh[base] = *(uint2*)th;
}

// ---------------- slice-XCD single-pass aggregate (layer 3, fp8 slice-major) --
// 8 slices of 48ch; block's slice = blockIdx.x & 7 (round-robin dispatch pins
// slice k -> XCD k; per-XCD working set = 2.4MB slice + 1.2MB es = L2-fit).
// Thread per (node, 8ch-in-slice): 6 threads/node/slice. Packed f32x2 FMA.
__global__ __launch_bounds__(256) void aggregate_sp3(
    const unsigned char* __restrict__ hs, const float* __restrict__ es,
    const float* __restrict__ ed, const unsigned* __restrict__ gmax,
    const int* __restrict__ offsets, const int* __restrict__ ssrc,
    __hip_bfloat16* __restrict__ outb, int n) {
    int sl = blockIdx.x & 7;
    long gt = (long)(blockIdx.x >> 3) * 256 + threadIdx.x;
    if (gt >= (long)n * 6) return;
    int node = (int)(gt / 6), q = (int)(gt % 6);
    int cbase = sl * 48 + q * 8;  // global channel base (never crosses a head)
    int hd = cbase >> 6;
    int a = offsets[node], b = offsets[node + 1];
    float edv = ed[node * HHEADS + hd];
    float mv = funkey(gmax[hd]) + edv;
    float m = mv > 0.f ? mv : 0.2f * mv;
    float l = 0.f;
    f32x2 a0 = {0.f, 0.f}, a1 = {0.f, 0.f}, a2 = {0.f, 0.f}, a3 = {0.f, 0.f};
    const unsigned char* base = hs + (size_t)sl * ((size_t)n * 48) + q * 8;
    for (int j = a; j < b; ++j) {
        int s = ssrc[j];
        float v = es[(size_t)s * HHEADS + hd] + edv;
        v = v > 0.f ? v : 0.2f * v;  // leaky relu 0.2
        float w = __expf(v - m);
        uint2 hv = *(const uint2*)(base + (size_t)s * 48);
        f32x2 p0 = __builtin_amdgcn_cvt_pk_f32_fp8((int)hv.x, false);
        f32x2 p1 = __builtin_amdgcn_cvt_pk_f32_fp8((int)hv.x, true);
        f32x2 p2 = __builtin_amdgcn_cvt_pk_f32_fp8((int)hv.y, false);
        f32x2 p3 = __builtin_amdgcn_cvt_pk_f32_fp8((int)hv.y, true);
        f32x2 wv = {w, w};
        l += w;
        a0 = a0 + wv * p0;
        a1 = a1 + wv * p1;
        a2 = a2 + wv * p2;
        a3 = a3 + wv * p3;
    }
    float invd = 1.0f / (l + 1e-16f);
    float res[8] = {a0[0], a0[1], a1[0], a1[1], a2[0], a2[1], a3[0], a3[1]};
    __hip_bfloat16 tb[8];
#pragma unroll
    for (int k = 0; k < 8; ++k) {
        float v = res[k] * invd;
        v = v > 0.f ? v : (__expf(v) - 1.0f);  // elu
        tb[k] = __float2bfloat16(v);
    }
    *(uint4*)&outb[(size_t)node * 384 + cbase] = *(uint4*)tb;
}

// ---------------- pooling (bf16 input) + head ----------------
__global__ void pool_kernel(const __hip_bfloat16* __restrict__ out3, float* __restrict__ g,
                            int n) {
    int b = blockIdx.x, t = threadIdx.x;  // blockDim = 192
    int chunk = (n + gridDim.x - 1) / gridDim.x;
    int n0 = b * chunk, n1 = min(n, n0 + chunk);
    float a0 = 0.f, a1 = 0.f;
    const unsigned* p = (const unsigned*)out3;
    for (int node = n0; node < n1; ++node) {
        unsigned u = p[(size_t)node * 192 + t];
        a0 += bfl(u);
        a1 += bfh(u);
    }
    atomicAdd(&g[2 * t], a0);
    atomicAdd(&g[2 * t + 1], a1);
}

__global__ void final_kernel(const float* __restrict__ g, const float* __restrict__ Wd,
                             const float* __restrict__ bd, float* __restrict__ outp) {
    __shared__ float red[384];
    int t = threadIdx.x;  // blockDim = 384
    float v = g[t];
    red[t] = v * v;
    __syncthreads();
    for (int s = 192; s >= 3; s >>= 1) {
        if (t < s) red[t] += red[t + s];
        __syncthreads();
    }
    __shared__ float scale_s;
    if (t == 0) {
        float norm = sqrtf(red[0] + red[1] + red[2]);
        scale_s = 1.0f / fmaxf(norm, 1e-12f);
    }
    __syncthreads();
    float scale = scale_s;
    red[t] = v * scale * Wd[t];
    __syncthreads();
    for (int s = 192; s >= 3; s >>= 1) {
        if (t < s) red[t] += red[t + s];
        __syncthreads();
    }
    if (t == 0) outp[0] = red[0] + red[1] + red[2] + bd[0];
}

// ---------------- host side ----------------
extern "C" void kernel_launch(void* const* d_in, const int* in_sizes, int n_in, void* d_out,
                              int out_size, void* d_ws, size_t ws_size, hipStream_t stream) {
    const float* x = (const float*)d_in[0];
    const int* ei = (const int*)d_in[1];
    const float* W1 = (const float*)d_in[2];
    const float* a1s = (const float*)d_in[3];
    const float* a1d = (const float*)d_in[4];
    const float* W2 = (const float*)d_in[5];
    const float* a2s = (const float*)d_in[6];
    const float* a2d = (const float*)d_in[7];
    const float* W3 = (const float*)d_in[8];
    const float* a3s = (const float*)d_in[9];
    const float* a3d = (const float*)d_in[10];
    const float* Wd = (const float*)d_in[11];
    const float* bd = (const float*)d_in[12];
    float* outp = (float*)d_out;

    const int N = in_sizes[0] / 11;
    const int E = in_sizes[1] / 2;
    const int* src = ei;
    const int* dst = ei + E;

    const int NT16 = ((N + 127) / 128) * 8;  // padded 16-row tiles
    const int NMT = (N + 127) / 128;         // 128-row M-tiles

    char* w = (char*)d_ws;
    size_t off = 0;
    auto A = [&](size_t bytes) {
        size_t o = off;
        off += (bytes + 255) & ~(size_t)255;
        return o;
    };
    unsigned char* bufH = (unsigned char*)(w + A((size_t)N * 384 * 2));   // h (fp8 all layers)
    __hip_bfloat16* bufO = (__hip_bfloat16*)(w + A((size_t)N * 384 * 2));  // layer3 out (bf16)
    unsigned short* apH = (unsigned short*)(w + A((size_t)NT16 * 6 * 512 * 2));  // A-pack
    unsigned short* b2H = (unsigned short*)(w + A((size_t)16 * 3 * 512 * 2));    // W2 pack
    unsigned short* b3H = (unsigned short*)(w + A((size_t)24 * 6 * 512 * 2));    // W3 pack
    float* es = (float*)(w + A((size_t)N * HHEADS * 4));
    float* ed = (float*)(w + A((size_t)N * HHEADS * 4));
    unsigned* gmax = (unsigned*)(w + A(256));
    float* wp = (float*)(w + A((size_t)11 * 96 * 4));  // layer-1 f32 repack
    int* count = (int*)(w + A((size_t)(N + 1) * 4));
    int* cursor = (int*)(w + A((size_t)(N + 1) * 4));
    int* offsets = (int*)(w + A((size_t)(N + 1) * 4));
    int* bsum = (int*)(w + A(64 * 4));
    int* ssrc = (int*)(w + A((size_t)E * 4));
    float* g = (float*)(w + A(384 * 4));

    // one-shot zero of all small scratch (count, cursor, g, gmax, A-pack pads)
    const long t16v = N / 16;
    const long padT = NT16 - t16v;
    zero_misc<<<(N + 255) / 256, 256, 0, stream>>>(count, cursor, g, gmax, apH,
                                                   t16v * 3 * 512, padT * 3 * 512,
                                                   t16v * 6 * 512, padT * 6 * 512, N);

    // CSR build (by dst)
    hist_kernel<<<(E + 255) / 256, 256, 0, stream>>>(dst, count, E);
    int nb = (N + 1023) / 1024;
    scan_block<<<nb, 1024, 0, stream>>>(count, offsets, bsum, N);
    scan_tops<<<1, 64, 0, stream>>>(bsum, nb);
    scan_add<<<nb, 1024, 0, stream>>>(offsets, bsum, N, E);
    scatter_kernel<<<(E + 255) / 256, 256, 0, stream>>>(src, dst, offsets, cursor, ssrc, E);

    // weight packs
    repack_w<<<(11 * 96 + 255) / 256, 256, 0, stream>>>(W1, wp, 11, 16);
    repack_w_mfma<<<(96 * 256 + 255) / 256, 256, 0, stream>>>(W2, b2H, 96, 32, 256);
    repack_w_mfma<<<(192 * 384 + 255) / 256, 256, 0, stream>>>(W3, b3H, 192, 64, 384);

    // ---- layer 1 (FIN=11, F=16): gemm (fp8 C) + fused attn terms ----
    {
        dim3 grid((96 + 63) / 64, (N + 63) / 64);
        gemm_small_attn<64, 64, 32><<<grid, 256, 0, stream>>>(x, wp, bufH, a1s, a1d, es, ed, N,
                                                              11, 96);
    }
    {
        long total = (long)N * (96 / 8);
        aggregate_fused<16><<<(total + 255) / 256, 256, 0, stream>>>(bufH, es, ed, offsets,
                                                                     ssrc, apH, N);
    }

    // ---- layer 2 (K=96, N=192 pad 256, F=32): fp8 C + fused gmax(6-11) ----
    {
        dim3 grid(2, (NMT + 3) / 4);
        gemm_attn_mfma<96, 192, 256, 32, 4><<<grid, 256, 0, stream>>>(apH, b2H, bufH, a2s,
                                                                      a2d, es, ed, gmax, N);
    }
    {
        int grid = (N + 3) / 4;  // 4 waves/block, wave-per-node
        aggregate_wpn2<<<grid, 256, 0, stream>>>(bufH, es, ed, gmax, offsets, ssrc, apH, N);
    }

    // ---- layer 3 (K=192, N=384, F=64): fp8 slice-major C + fused gmax(0-5) ----
    {
        dim3 grid(3, (NMT + 3) / 4);
        gemm_attn_mfma<192, 384, 384, 64, 4><<<grid, 256, 0, stream>>>(apH, b3H, bufH, a3s,
                                                                       a3d, es, ed, gmax, N);
    }
    {
        long groups = ((long)N * 6 + 255) / 256;
        aggregate_sp3<<<(int)(groups * 8), 256, 0, stream>>>(bufH, es, ed, gmax, offsets,
                                                             ssrc, bufO, N);
    }

    // sum-pool (bf16 in) -> normalize -> dense
    pool_kernel<<<256, 192, 0, stream>>>(bufO, g, N);
    final_kernel<<<1, 384, 0, stream>>>(g, Wd, bd, outp);
}

// Round 12
// 516.235 us; speedup vs baseline: 1.0936x; 1.0936x over previous
//
#include <hip/hip_runtime.h>
#include <hip/hip_bf16.h>

// GAT 3-layer: N=50000 nodes, E=800000 edges, H=6 heads.
// R1-R17: MFMA GEMMs + CSR fused softmax/aggregate ladder (545us).
// R20/R21: wave-per-node aggregates; h -> fp8 e4m3 (absmax 2.4e-4 passes).
// R22-R25: GEMM invariant under store/stage/pipeline/precision changes ->
//      per-block fixed overhead; R26: MT=4 M-tiles/block + persistent-B LDS
//      -> GEMMs out of top-5 (527us). R27: fp8 h for L1/L2 too (513us).
// R28 FAILED (564us): slice-major L3 + slice->XCD pinning. FETCH only
//      154->110MB (pinning heuristic too weak; ssrc read 8x, es 6x) and the
//      thread-per-(node,8ch-in-slice) layout reintroduced trip divergence
//      (~11 nodes/wave) + scattered 48B segments vs wpn3's one coalesced
//      384B row/edge. Lesson: wpn3's wave-per-node coalescing IS the win;
//      cross-XCD fetch (8x array) is not reachable via dispatch heuristics.
// R29: revert to R27 structure (row-major fp8 L3 + aggregate_wpn3), keeping
//      R28's one orthogonal micro-win: packed f32x2 FMA accumulators in all
//      aggregates (wpn3 was 60% VALU-busy; halves accumulator issue).

#define HHEADS 6

typedef __attribute__((ext_vector_type(8))) short bf16x8;   // 8 bf16 = 4 VGPR
typedef __attribute__((ext_vector_type(4))) float f32x4;    // mfma C/D
typedef __attribute__((ext_vector_type(2))) float f32x2;

typedef __attribute__((address_space(3))) unsigned int lds_uint;
typedef const __attribute__((address_space(1))) unsigned int glb_uint;

__device__ __forceinline__ float bfl(unsigned u) { return __uint_as_float(u << 16); }
__device__ __forceinline__ float bfh(unsigned u) { return __uint_as_float(u & 0xffff0000u); }
__device__ __forceinline__ unsigned short f2bf(float v) {  // RNE f32->bf16
    unsigned u = __float_as_uint(v);
    return (unsigned short)((u + 0x7fffu + ((u >> 16) & 1u)) >> 16);
}
__device__ __forceinline__ float bf2f(unsigned short h) {
    return __uint_as_float((unsigned)h << 16);
}
// monotone float<->uint for atomicMax on floats (memset-0 = -inf identity)
__device__ __forceinline__ unsigned fkey(float f) {
    unsigned u = __float_as_uint(f);
    return (u >> 31) ? ~u : (u | 0x80000000u);
}
__device__ __forceinline__ float funkey(unsigned k) {
    return (k >> 31) ? __uint_as_float(k & 0x7fffffffu) : __uint_as_float(~k);
}

// 4x4 transpose across a 4-lane group (lanes share lane>>2). In: v0..v3 =
// rows 0..3 at this lane's column. Out: v0..v3 = cols 0..3 at row (lane&3).
__device__ __forceinline__ void xpose4(float& v0, float& v1, float& v2, float& v3, int b) {
    bool hi = (b & 2) != 0;
    float s0 = hi ? v0 : v2;
    float s1 = hi ? v1 : v3;
    s0 = __shfl_xor(s0, 2, 64);
    s1 = __shfl_xor(s1, 2, 64);
    v0 = hi ? s0 : v0;
    v1 = hi ? s1 : v1;
    v2 = hi ? v2 : s0;
    v3 = hi ? v3 : s1;
    bool od = (b & 1) != 0;
    float t0 = od ? v0 : v1;
    t0 = __shfl_xor(t0, 1, 64);
    v0 = od ? t0 : v0;
    v1 = od ? v1 : t0;
    float t1 = od ? v2 : v3;
    t1 = __shfl_xor(t1, 1, 64);
    v2 = od ? t1 : v2;
    v3 = od ? v3 : t1;
}

// ---------------- one-shot zero of all small scratch ----------------
__global__ void zero_misc(int* __restrict__ count, int* __restrict__ cursor,
                          float* __restrict__ g, unsigned* __restrict__ gmax,
                          unsigned short* __restrict__ apH,
                          long pad3_off, long pad3_cnt, long pad6_off, long pad6_cnt, int n) {
    long i = (long)blockIdx.x * blockDim.x + threadIdx.x;
    long stride = (long)gridDim.x * blockDim.x;
    for (long j = i; j < n; j += stride) {
        count[j] = 0;
        cursor[j] = 0;
    }
    if (i < 384) g[i] = 0.f;
    if (i < 12) gmax[i] = 0u;  // slots 0-5: L3, 6-11: L2
    for (long j = i; j < pad3_cnt; j += stride) apH[pad3_off + j] = 0;
    for (long j = i; j < pad6_cnt; j += stride) apH[pad6_off + j] = 0;
}

// ---------------- CSR build ----------------
__global__ void hist_kernel(const int* __restrict__ dst, int* __restrict__ count, int E) {
    int e = blockIdx.x * blockDim.x + threadIdx.x;
    if (e >= E) return;
    atomicAdd(&count[dst[e]], 1);
}

__global__ void scan_block(const int* __restrict__ count, int* __restrict__ offsets,
                           int* __restrict__ bsum, int n) {
    __shared__ int s[1024];
    int i = blockIdx.x * 1024 + threadIdx.x;
    int v = (i < n) ? count[i] : 0;
    s[threadIdx.x] = v;
    __syncthreads();
    for (int off = 1; off < 1024; off <<= 1) {
        int t = (threadIdx.x >= (unsigned)off) ? s[threadIdx.x - off] : 0;
        __syncthreads();
        s[threadIdx.x] += t;
        __syncthreads();
    }
    if (i < n) offsets[i] = s[threadIdx.x] - v;
    if (threadIdx.x == 1023) bsum[blockIdx.x] = s[1023];
}

__global__ void scan_tops(int* __restrict__ bsum, int nb) {
    __shared__ int s[64];
    int t = threadIdx.x;
    int v = (t < nb) ? bsum[t] : 0;
    s[t] = v;
    __syncthreads();
    for (int off = 1; off < 64; off <<= 1) {
        int tmp = (t >= off) ? s[t - off] : 0;
        __syncthreads();
        s[t] += tmp;
        __syncthreads();
    }
    if (t < nb) bsum[t] = s[t] - v;
}

__global__ void scan_add(int* __restrict__ offsets, const int* __restrict__ bsum, int n,
                         int total) {
    int i = blockIdx.x * 1024 + threadIdx.x;
    if (i < n) offsets[i] += bsum[blockIdx.x];
    if (i == 0) offsets[n] = total;
}

__global__ void scatter_kernel(const int* __restrict__ src, const int* __restrict__ dst,
                               const int* __restrict__ offsets, int* __restrict__ cursor,
                               int* __restrict__ ssrc, int E) {
    int e = blockIdx.x * blockDim.x + threadIdx.x;
    if (e >= E) return;
    int d = dst[e];
    int pos = offsets[d] + atomicAdd(&cursor[d], 1);
    ssrc[pos] = src[e];
}

// ---------------- weight repacks ----------------
__global__ void repack_w(const float* __restrict__ W, float* __restrict__ Wp, int FIN, int F) {
    int HF = HHEADS * F;
    int i = blockIdx.x * blockDim.x + threadIdx.x;
    if (i >= FIN * HF) return;
    int k = i / HF, c = i % HF;
    int hd = c / F, f = c % F;
    Wp[i] = W[(hd * FIN + k) * F + f];
}

// bf16 pack in MFMA B-fragment layout (B^T: lane n=..&15, k contiguous)
__global__ void repack_w_mfma(const float* __restrict__ W, unsigned short* __restrict__ bh,
                              int FIN, int F, int NPAD) {
    int i = blockIdx.x * blockDim.x + threadIdx.x;
    if (i >= FIN * NPAD) return;
    int k = i / NPAD, n = i % NPAD;
    int NKT = FIN / 32;
    int HF = HHEADS * F;
    float w = 0.f;
    if (n < HF) {
        int hd = n / F, f = n % F;
        w = W[(hd * FIN + k) * F + f];
    }
    size_t e = ((size_t)((n >> 4) * NKT + (k >> 5)) * 64 + ((n & 15) | (((k >> 3) & 3) << 4))) * 8 +
               (k & 7);
    bh[e] = f2bf(w);
}

// ---------------- small GEMM + fused attn (layer 1, K=11, F=16) ----------------
// C written fp8 e4m3 (feeds only aggregate_fused).
template <int BM, int BN, int BK>
__global__ __launch_bounds__(256) void gemm_small_attn(const float* __restrict__ A,
                                                       const float* __restrict__ B,
                                                       unsigned char* __restrict__ C8,
                                                       const float* __restrict__ as_,
                                                       const float* __restrict__ ad_,
                                                       float* __restrict__ es,
                                                       float* __restrict__ ed, int M, int K,
                                                       int N) {
    __shared__ float As[BK][BM + 4];
    __shared__ float Bs[BK][BN];
    int tid = threadIdx.x;
    int tx = tid % 16, ty = tid / 16;
    int m0 = blockIdx.y * BM, n0 = blockIdx.x * BN;
    float acc[4][4] = {};
    for (int kk0 = 0; kk0 < K; kk0 += BK) {
#pragma unroll
        for (int i = 0; i < (BM * BK) / 256; ++i) {
            int idx = tid + i * 256;
            int m = idx / BK, k = idx % BK;
            float v = 0.f;
            if (m0 + m < M && kk0 + k < K) v = A[(size_t)(m0 + m) * K + kk0 + k];
            As[k][m] = v;
        }
#pragma unroll
        for (int i = 0; i < (BK * BN) / 1024; ++i) {
            int idx = tid + i * 256;
            int k = idx / (BN / 4), n4 = idx % (BN / 4);
            float4 v = make_float4(0.f, 0.f, 0.f, 0.f);
            if (kk0 + k < K && n0 + n4 * 4 < N)
                v = *(const float4*)&B[(size_t)(kk0 + k) * N + n0 + n4 * 4];
            *(float4*)&Bs[k][n4 * 4] = v;
        }
        __syncthreads();
#pragma unroll
        for (int k = 0; k < BK; ++k) {
            float4 av = *(const float4*)&As[k][ty * 4];
            float4 bv = *(const float4*)&Bs[k][tx * 4];
            float a[4] = {av.x, av.y, av.z, av.w};
            float b[4] = {bv.x, bv.y, bv.z, bv.w};
#pragma unroll
            for (int i = 0; i < 4; ++i)
#pragma unroll
                for (int j = 0; j < 4; ++j) acc[i][j] += a[i] * b[j];
        }
        __syncthreads();
    }
    bool colok = (n0 + tx * 4) < N;
    float asv[4], adv[4];
#pragma unroll
    for (int j = 0; j < 4; ++j) {
        int col = n0 + tx * 4 + j;
        asv[j] = (col < N) ? as_[col] : 0.f;
        adv[j] = (col < N) ? ad_[col] : 0.f;
    }
#pragma unroll
    for (int i = 0; i < 4; ++i) {
        int m = m0 + ty * 4 + i;
        bool mok = m < M;
        if (mok && colok) {
            int pk = __builtin_amdgcn_cvt_pk_fp8_f32(acc[i][0], acc[i][1], 0, false);
            pk = __builtin_amdgcn_cvt_pk_fp8_f32(acc[i][2], acc[i][3], pk, true);
            *(unsigned*)&C8[(size_t)m * N + n0 + tx * 4] = (unsigned)pk;
        }
        float ps = 0.f, pd = 0.f;
#pragma unroll
        for (int j = 0; j < 4; ++j) {
            ps += acc[i][j] * asv[j];
            pd += acc[i][j] * adv[j];
        }
        ps += __shfl_down(ps, 2, 4);
        ps += __shfl_down(ps, 1, 4);
        pd += __shfl_down(pd, 2, 4);
        pd += __shfl_down(pd, 1, 4);
        if (mok && colok && (tx & 3) == 0) {
            int hd = (n0 + tx * 4) >> 4;  // F=16
            es[(size_t)m * HHEADS + hd] = ps;
            ed[(size_t)m * HHEADS + hd] = pd;
        }
    }
}

// ---------------- MFMA bf16 GEMM + fused attn (layers 2/3) ----------------
// MT M-tiles per block; persistent B in LDS; A double-buffered; fp8 row-major C.
// F==64: gmax slots 0-5. F==32: gmax slots 6-11.
template <int K, int NREAL, int NPAD, int F, int MT>
__global__ __launch_bounds__(256) void gemm_attn_mfma(
    const unsigned short* __restrict__ Ah, const unsigned short* __restrict__ Bh,
    unsigned char* __restrict__ C8, const float* __restrict__ as_,
    const float* __restrict__ ad_, float* __restrict__ es, float* __restrict__ ed,
    unsigned* __restrict__ gmax, int M) {
    constexpr int NKT = K / 32;
    __shared__ unsigned short sB[NKT * 4096];  // persistent B panel
    __shared__ unsigned short sA[2][4096];     // A double buffer
    int tid = threadIdx.x;
    int lane = tid & 63, wave = tid >> 6;
    int wrow = wave >> 1, wcol = wave & 1;
    int quad = lane >> 4, c16 = lane & 15;

    // XCD-bijective swizzle (m204): co-locate blocks sharing B panels.
    int nwg = gridDim.x * gridDim.y;
    int hh = blockIdx.y * gridDim.x + blockIdx.x;
    int q = nwg >> 3, r = nwg & 7;
    int xcd = hh & 7, pos = hh >> 3;
    int wk = (xcd < r ? xcd * (q + 1) : r * (q + 1) + (xcd - r) * q) + pos;
    int bx = wk % gridDim.x, by = wk / gridDim.x;

    int n0 = bx * 128;
    int bn16 = n0 >> 4;
    int nmt = (M + 127) >> 7;  // number of valid 128-row M-tiles

    // ---- stage entire B panel (once) ----
#pragma unroll
    for (int kt2 = 0; kt2 < NKT; ++kt2) {
#pragma unroll
        for (int rep = 0; rep < 2; ++rep) {
            int chunk = tid + rep * 256;
            int tile = chunk >> 6, e8 = chunk & 63;
            size_t boff = ((size_t)((bn16 + tile) * NKT + kt2) * 64 + e8) * 8;
            __builtin_amdgcn_global_load_lds((glb_uint*)&Bh[boff],
                                             (lds_uint*)&sB[kt2 * 4096 + chunk * 8], 16, 0, 0);
        }
    }
    auto STAGE_A = [&](int mti, int kt2, int buf) {
#pragma unroll
        for (int rep = 0; rep < 2; ++rep) {
            int chunk = tid + rep * 256;
            int tile = chunk >> 6, e8 = chunk & 63;
            size_t aoff = ((size_t)((mti * 8 + tile) * NKT + kt2) * 64 + e8) * 8;
            __builtin_amdgcn_global_load_lds((glb_uint*)&Ah[aoff],
                                             (lds_uint*)&sA[buf][chunk * 8], 16, 0, 0);
        }
    };
    STAGE_A(min(by * MT, nmt - 1), 0, 0);
    asm volatile("s_waitcnt vmcnt(0)" ::: "memory");
    __builtin_amdgcn_s_barrier();

    float asv[4], adv[4];
#pragma unroll
    for (int j = 0; j < 4; ++j) {
        int col = n0 + wcol * 64 + j * 16 + c16;
        bool ok = col < NREAL;
        asv[j] = ok ? as_[col] : 0.f;
        adv[j] = ok ? ad_[col] : 0.f;
    }
    float mx = -1e30f;                 // F==64 per-wave head max (across mts)
    float mxA = -1e30f, mxB = -1e30f;  // F==32 per-wave 2-head max
    bool colvalid = (n0 + wcol * 64) < NREAL;
    int b4 = lane & 3;

    f32x4 acc[4][4] = {};
    const int T = MT * NKT;
    int mt = 0, kt = 0;
    for (int t = 0; t < T; ++t) {
        int cur = t & 1;
        int nkt = kt + 1, nmt2 = mt;
        if (nkt == NKT) {
            nkt = 0;
            nmt2 = mt + 1;
        }
        if (t + 1 < T) STAGE_A(min(by * MT + nmt2, nmt - 1), nkt, cur ^ 1);  // issue-early
        bf16x8 fah[4], fbh[4];
#pragma unroll
        for (int i = 0; i < 4; ++i) {
            fah[i] = *(const bf16x8*)&sA[cur][(wrow * 4 + i) * 512 + lane * 8];
            fbh[i] = *(const bf16x8*)&sB[kt * 4096 + (wcol * 4 + i) * 512 + lane * 8];
        }
        asm volatile("s_waitcnt lgkmcnt(0)" ::: "memory");
        __builtin_amdgcn_sched_barrier(0);  // rule #18
#pragma unroll
        for (int i = 0; i < 4; ++i)
#pragma unroll
            for (int j = 0; j < 4; ++j)
                acc[i][j] = __builtin_amdgcn_mfma_f32_16x16x32_bf16(fah[i], fbh[j], acc[i][j],
                                                                    0, 0, 0);
        if (kt == NKT - 1) {  // M-tile complete: epilogue (uniform branch)
            int m0 = (by * MT + mt) * 128;
            if (m0 < M) {
                // ---- es/ed + gmax partial (fragment layout) ----
#pragma unroll
                for (int i = 0; i < 4; ++i) {
#pragma unroll
                    for (int r2 = 0; r2 < 4; ++r2) {
                        int m = m0 + wrow * 64 + i * 16 + quad * 4 + r2;
                        bool mok = m < M;
                        if (F == 64) {
                            float ps = acc[i][0][r2] * asv[0] + acc[i][1][r2] * asv[1] +
                                       acc[i][2][r2] * asv[2] + acc[i][3][r2] * asv[3];
                            float pd = acc[i][0][r2] * adv[0] + acc[i][1][r2] * adv[1] +
                                       acc[i][2][r2] * adv[2] + acc[i][3][r2] * adv[3];
#pragma unroll
                            for (int off = 8; off > 0; off >>= 1) {
                                ps += __shfl_down(ps, off, 16);
                                pd += __shfl_down(pd, off, 16);
                            }
                            if (mok && c16 == 0) {
                                int hd = (n0 + wcol * 64) / 64;
                                es[(size_t)m * HHEADS + hd] = ps;
                                ed[(size_t)m * HHEADS + hd] = pd;
                                mx = fmaxf(mx, ps);
                            }
                        } else {  // F == 32: two heads per wave-column
                            float psA = acc[i][0][r2] * asv[0] + acc[i][1][r2] * asv[1];
                            float pdA = acc[i][0][r2] * adv[0] + acc[i][1][r2] * adv[1];
                            float psB = acc[i][2][r2] * asv[2] + acc[i][3][r2] * asv[3];
                            float pdB = acc[i][2][r2] * adv[2] + acc[i][3][r2] * adv[3];
#pragma unroll
                            for (int off = 8; off > 0; off >>= 1) {
                                psA += __shfl_down(psA, off, 16);
                                pdA += __shfl_down(pdA, off, 16);
                                psB += __shfl_down(psB, off, 16);
                                pdB += __shfl_down(pdB, off, 16);
                            }
                            if (mok && c16 == 0 && colvalid) {
                                int colbase = n0 + wcol * 64;
                                int hd = colbase / 32;
                                es[(size_t)m * HHEADS + hd] = psA;
                                ed[(size_t)m * HHEADS + hd] = pdA;
                                es[(size_t)m * HHEADS + hd + 1] = psB;
                                ed[(size_t)m * HHEADS + hd + 1] = pdB;
                                mxA = fmaxf(mxA, psA);
                                mxB = fmaxf(mxB, psB);
                            }
                        }
                    }
                }
                // ---- C store (fp8): transpose 16x16 blocks, dword stores ----
#pragma unroll
                for (int i = 0; i < 4; ++i) {
                    int m = m0 + wrow * 64 + i * 16 + quad * 4 + b4;
                    bool mok = m < M;
#pragma unroll
                    for (int j = 0; j < 4; ++j) {
                        float v0 = acc[i][j][0], v1 = acc[i][j][1], v2 = acc[i][j][2],
                              v3 = acc[i][j][3];
                        xpose4(v0, v1, v2, v3, b4);
                        int colb = n0 + wcol * 64 + j * 16 + (c16 & 12);
                        if (mok && (F == 64 || colvalid)) {
                            int pk = __builtin_amdgcn_cvt_pk_fp8_f32(v0, v1, 0, false);
                            pk = __builtin_amdgcn_cvt_pk_fp8_f32(v2, v3, pk, true);
                            *(unsigned*)&C8[(size_t)m * NREAL + colb] = (unsigned)pk;
                        }
                    }
                }
            }
#pragma unroll
            for (int i = 0; i < 4; ++i)
#pragma unroll
                for (int j = 0; j < 4; ++j) acc[i][j] = (f32x4){0.f, 0.f, 0.f, 0.f};
        }
        asm volatile("s_waitcnt vmcnt(0)" ::: "memory");
        __builtin_amdgcn_s_barrier();
        kt = nkt;
        mt = nmt2;
    }

    if (F == 64) {  // per-head global es max, one atomic per wave per block
#pragma unroll
        for (int off = 32; off > 0; off >>= 1) mx = fmaxf(mx, __shfl_xor(mx, off));
        if (lane == 0) atomicMax(&gmax[(n0 + wcol * 64) / 64], fkey(mx));
    } else {
        mxA = fmaxf(mxA, __shfl_xor(mxA, 16));
        mxA = fmaxf(mxA, __shfl_xor(mxA, 32));
        mxB = fmaxf(mxB, __shfl_xor(mxB, 16));
        mxB = fmaxf(mxB, __shfl_xor(mxB, 32));
        if (lane == 0 && colvalid) {
            int hd = (n0 + wcol * 64) / 32;
            atomicMax(&gmax[6 + hd], fkey(mxA));
            atomicMax(&gmax[6 + hd + 1], fkey(mxB));
        }
    }
}

// ---------------- online-rescale softmax-aggregate (layer 1, fp8 h) -----------
// Thread per (node, 8ch); fp8 gather + HW unpack; packed f32x2 FMA accum.
template <int F>
__global__ __launch_bounds__(256) void aggregate_fused(
    const unsigned char* __restrict__ h8, const float* __restrict__ es,
    const float* __restrict__ ed, const int* __restrict__ offsets,
    const int* __restrict__ ssrc, unsigned short* __restrict__ oh, int n) {
    constexpr int HF = HHEADS * F;
    constexpr int C8 = HF / 8;
    int tid = blockIdx.x * blockDim.x + threadIdx.x;
    if (tid >= n * C8) return;
    int node = tid / C8, q = tid % C8;
    int c = q * 8, hd = c / F;
    int a = offsets[node], b = offsets[node + 1];
    float edv = ed[node * HHEADS + hd];
    float m = -1e30f, l = 0.f;
    f32x2 a0 = {0.f, 0.f}, a1 = {0.f, 0.f}, a2 = {0.f, 0.f}, a3 = {0.f, 0.f};
    for (int j = a; j < b; ++j) {
        int s = ssrc[j];
        float v = es[s * HHEADS + hd] + edv;
        v = v > 0.f ? v : 0.2f * v;  // leaky relu 0.2
        float mn = fmaxf(m, v);
        float r = __expf(m - mn);
        float wgt = __expf(v - mn);
        uint2 hv = *(const uint2*)&h8[(size_t)s * HF + c];
        f32x2 p0 = __builtin_amdgcn_cvt_pk_f32_fp8((int)hv.x, false);
        f32x2 p1 = __builtin_amdgcn_cvt_pk_f32_fp8((int)hv.x, true);
        f32x2 p2 = __builtin_amdgcn_cvt_pk_f32_fp8((int)hv.y, false);
        f32x2 p3 = __builtin_amdgcn_cvt_pk_f32_fp8((int)hv.y, true);
        l = l * r + wgt;
        f32x2 rv = {r, r}, wv = {wgt, wgt};
        a0 = a0 * rv + wv * p0;
        a1 = a1 * rv + wv * p1;
        a2 = a2 * rv + wv * p2;
        a3 = a3 * rv + wv * p3;
        m = mn;
    }
    float invd = 1.0f / (l + 1e-16f);
    float res[8] = {a0[0], a0[1], a1[0], a1[1], a2[0], a2[1], a3[0], a3[1]};
    unsigned short th[8];
#pragma unroll
    for (int k = 0; k < 8; ++k) {
        float v = res[k] * invd;
        v = v > 0.f ? v : (__expf(v) - 1.0f);  // elu
        th[k] = f2bf(v);
    }
    constexpr int NKT = HF / 32;
    int lq = (node & 15) | (((c >> 3) & 3) << 4);
    size_t base = ((size_t)((node >> 4) * NKT + (c >> 5)) * 64 + lq) * 8;
    *(uint4*)&oh[base] = *(uint4*)th;
}

// ---------------- wave-per-node single-pass aggregate (layer 2, fp8 h) --------
// Lanes 0..47 own 4 channels (uint = 4 fp8); packed f32x2 FMA accum.
__global__ __launch_bounds__(256) void aggregate_wpn2(
    const unsigned char* __restrict__ h8, const float* __restrict__ es,
    const float* __restrict__ ed, const unsigned* __restrict__ gmax,
    const int* __restrict__ offsets, const int* __restrict__ ssrc,
    unsigned short* __restrict__ oh, int n) {
    constexpr int HF = 192;
    int wid = (int)((blockIdx.x * (unsigned)blockDim.x + threadIdx.x) >> 6);
    int lane = threadIdx.x & 63;
    if (wid >= n || lane >= 48) return;
    int node = wid;
    int hd = lane >> 3;  // F=32: 8 lanes (32ch) per head
    int c = lane * 4;
    int a = offsets[node], b = offsets[node + 1];
    float edv = ed[node * HHEADS + hd];
    float mv = funkey(gmax[6 + hd]) + edv;
    float m = mv > 0.f ? mv : 0.2f * mv;
    float l = 0.f;
    f32x2 a0 = {0.f, 0.f}, a1 = {0.f, 0.f};
    const unsigned char* hbase = h8 + c;
    int j = a;
    for (; j + 1 < b; j += 2) {
        int s0 = ssrc[j], s1 = ssrc[j + 1];
        float ev0 = es[(size_t)s0 * HHEADS + hd];
        float ev1 = es[(size_t)s1 * HHEADS + hd];
        unsigned h0 = *(const unsigned*)(hbase + (size_t)s0 * HF);
        unsigned h1 = *(const unsigned*)(hbase + (size_t)s1 * HF);
        float v0 = ev0 + edv;
        v0 = v0 > 0.f ? v0 : 0.2f * v0;
        float v1 = ev1 + edv;
        v1 = v1 > 0.f ? v1 : 0.2f * v1;
        float w0 = __expf(v0 - m);
        float w1 = __expf(v1 - m);
        {
            f32x2 p0 = __builtin_amdgcn_cvt_pk_f32_fp8((int)h0, false);
            f32x2 p1 = __builtin_amdgcn_cvt_pk_f32_fp8((int)h0, true);
            f32x2 wv = {w0, w0};
            l += w0;
            a0 = a0 + wv * p0;
            a1 = a1 + wv * p1;
        }
        {
            f32x2 p0 = __builtin_amdgcn_cvt_pk_f32_fp8((int)h1, false);
            f32x2 p1 = __builtin_amdgcn_cvt_pk_f32_fp8((int)h1, true);
            f32x2 wv = {w1, w1};
            l += w1;
            a0 = a0 + wv * p0;
            a1 = a1 + wv * p1;
        }
    }
    if (j < b) {
        int s0 = ssrc[j];
        float ev0 = es[(size_t)s0 * HHEADS + hd];
        unsigned h0 = *(const unsigned*)(hbase + (size_t)s0 * HF);
        float v0 = ev0 + edv;
        v0 = v0 > 0.f ? v0 : 0.2f * v0;
        float w0 = __expf(v0 - m);
        f32x2 p0 = __builtin_amdgcn_cvt_pk_f32_fp8((int)h0, false);
        f32x2 p1 = __builtin_amdgcn_cvt_pk_f32_fp8((int)h0, true);
        f32x2 wv = {w0, w0};
        l += w0;
        a0 = a0 + wv * p0;
        a1 = a1 + wv * p1;
    }
    float invd = 1.0f / (l + 1e-16f);
    float res[4] = {a0[0], a0[1], a1[0], a1[1]};
    unsigned short th[4];
#pragma unroll
    for (int k = 0; k < 4; ++k) {
        float v = res[k] * invd;
        v = v > 0.f ? v : (__expf(v) - 1.0f);  // elu
        th[k] = f2bf(v);
    }
    int lq = (node & 15) | (((c >> 3) & 3) << 4);
    size_t base = ((size_t)((node >> 4) * (HF / 32) + (c >> 5)) * 64 + lq) * 8 + (c & 7);
    *(uint2*)&oh[base] = *(uint2*)th;
}

// ---------------- wave-per-node single-pass aggregate (layer 3, fp8 h) --------
// Lanes 0..47 own 8 fp8 ch (uint2); one coalesced 384B row/edge; scalar ssrc;
// packed f32x2 FMA accum; 2-edge unroll.
__global__ __launch_bounds__(256) void aggregate_wpn3(
    const unsigned char* __restrict__ h8, const float* __restrict__ es,
    const float* __restrict__ ed, const unsigned* __restrict__ gmax,
    const int* __restrict__ offsets, const int* __restrict__ ssrc,
    __hip_bfloat16* __restrict__ outb, int n) {
    constexpr int HF = 384;
    int wid = (int)((blockIdx.x * (unsigned)blockDim.x + threadIdx.x) >> 6);
    int lane = threadIdx.x & 63;
    if (wid >= n || lane >= 48) return;
    int node = wid;
    int hd = lane >> 3;  // 8 lanes (64ch) per head
    int c = lane * 8;
    int a = offsets[node], b = offsets[node + 1];
    float edv = ed[node * HHEADS + hd];
    float mv = funkey(gmax[hd]) + edv;
    float m = mv > 0.f ? mv : 0.2f * mv;
    float l = 0.f;
    f32x2 a0 = {0.f, 0.f}, a1 = {0.f, 0.f}, a2 = {0.f, 0.f}, a3 = {0.f, 0.f};
    const unsigned char* hbase = h8 + c;
    int j = a;
    for (; j + 1 < b; j += 2) {
        int s0 = ssrc[j], s1 = ssrc[j + 1];
        float ev0 = es[(size_t)s0 * HHEADS + hd];
        float ev1 = es[(size_t)s1 * HHEADS + hd];
        uint2 h0 = *(const uint2*)(hbase + (size_t)s0 * HF);
        uint2 h1 = *(const uint2*)(hbase + (size_t)s1 * HF);
        float v0 = ev0 + edv;
        v0 = v0 > 0.f ? v0 : 0.2f * v0;
        float v1 = ev1 + edv;
        v1 = v1 > 0.f ? v1 : 0.2f * v1;
        float w0 = __expf(v0 - m);
        float w1 = __expf(v1 - m);
        {
            f32x2 p0 = __builtin_amdgcn_cvt_pk_f32_fp8((int)h0.x, false);
            f32x2 p1 = __builtin_amdgcn_cvt_pk_f32_fp8((int)h0.x, true);
            f32x2 p2 = __builtin_amdgcn_cvt_pk_f32_fp8((int)h0.y, false);
            f32x2 p3 = __builtin_amdgcn_cvt_pk_f32_fp8((int)h0.y, true);
            f32x2 wv = {w0, w0};
            l += w0;
            a0 = a0 + wv * p0;
            a1 = a1 + wv * p1;
            a2 = a2 + wv * p2;
            a3 = a3 + wv * p3;
        }
        {
            f32x2 p0 = __builtin_amdgcn_cvt_pk_f32_fp8((int)h1.x, false);
            f32x2 p1 = __builtin_amdgcn_cvt_pk_f32_fp8((int)h1.x, true);
            f32x2 p2 = __builtin_amdgcn_cvt_pk_f32_fp8((int)h1.y, false);
            f32x2 p3 = __builtin_amdgcn_cvt_pk_f32_fp8((int)h1.y, true);
            f32x2 wv = {w1, w1};
            l += w1;
            a0 = a0 + wv * p0;
            a1 = a1 + wv * p1;
            a2 = a2 + wv * p2;
            a3 = a3 + wv * p3;
        }
    }
    if (j < b) {
        int s0 = ssrc[j];
        float ev0 = es[(size_t)s0 * HHEADS + hd];
        uint2 h0 = *(const uint2*)(hbase + (size_t)s0 * HF);
        float v0 = ev0 + edv;
        v0 = v0 > 0.f ? v0 : 0.2f * v0;
        float w0 = __expf(v0 - m);
        f32x2 p0 = __builtin_amdgcn_cvt_pk_f32_fp8((int)h0.x, false);
        f32x2 p1 = __builtin_amdgcn_cvt_pk_f32_fp8((int)h0.x, true);
        f32x2 p2 = __builtin_amdgcn_cvt_pk_f32_fp8((int)h0.y, false);
        f32x2 p3 = __builtin_amdgcn_cvt_pk_f32_fp8((int)h0.y, true);
        f32x2 wv = {w0, w0};
        l += w0;
        a0 = a0 + wv * p0;
        a1 = a1 + wv * p1;
        a2 = a2 + wv * p2;
        a3 = a3 + wv * p3;
    }
    float invd = 1.0f / (l + 1e-16f);
    float res[8] = {a0[0], a0[1], a1[0], a1[1], a2[0], a2[1], a3[0], a3[1]};
    __hip_bfloat16 tb[8];
#pragma unroll
    for (int k = 0; k < 8; ++k) {
        float v = res[k] * invd;
        v = v > 0.f ? v : (__expf(v) - 1.0f);  // elu
        tb[k] = __float2bfloat16(v);
    }
    *(uint4*)&outb[(size_t)node * HF + c] = *(uint4*)tb;
}

// ---------------- pooling (bf16 input) + head ----------------
__global__ void pool_kernel(const __hip_bfloat16* __restrict__ out3, float* __restrict__ g,
                            int n) {
    int b = blockIdx.x, t = threadIdx.x;  // blockDim = 192
    int chunk = (n + gridDim.x - 1) / gridDim.x;
    int n0 = b * chunk, n1 = min(n, n0 + chunk);
    float a0 = 0.f, a1 = 0.f;
    const unsigned* p = (const unsigned*)out3;
    for (int node = n0; node < n1; ++node) {
        unsigned u = p[(size_t)node * 192 + t];
        a0 += bfl(u);
        a1 += bfh(u);
    }
    atomicAdd(&g[2 * t], a0);
    atomicAdd(&g[2 * t + 1], a1);
}

__global__ void final_kernel(const float* __restrict__ g, const float* __restrict__ Wd,
                             const float* __restrict__ bd, float* __restrict__ outp) {
    __shared__ float red[384];
    int t = threadIdx.x;  // blockDim = 384
    float v = g[t];
    red[t] = v * v;
    __syncthreads();
    for (int s = 192; s >= 3; s >>= 1) {
        if (t < s) red[t] += red[t + s];
        __syncthreads();
    }
    __shared__ float scale_s;
    if (t == 0) {
        float norm = sqrtf(red[0] + red[1] + red[2]);
        scale_s = 1.0f / fmaxf(norm, 1e-12f);
    }
    __syncthreads();
    float scale = scale_s;
    red[t] = v * scale * Wd[t];
    __syncthreads();
    for (int s = 192; s >= 3; s >>= 1) {
        if (t < s) red[t] += red[t + s];
        __syncthreads();
    }
    if (t == 0) outp[0] = red[0] + red[1] + red[2] + bd[0];
}

// ---------------- host side ----------------
extern "C" void kernel_launch(void* const* d_in, const int* in_sizes, int n_in, void* d_out,
                              int out_size, void* d_ws, size_t ws_size, hipStream_t stream) {
    const float* x = (const float*)d_in[0];
    const int* ei = (const int*)d_in[1];
    const float* W1 = (const float*)d_in[2];
    const float* a1s = (const float*)d_in[3];
    const float* a1d = (const float*)d_in[4];
    const float* W2 = (const float*)d_in[5];
    const float* a2s = (const float*)d_in[6];
    const float* a2d = (const float*)d_in[7];
    const float* W3 = (const float*)d_in[8];
    const float* a3s = (const float*)d_in[9];
    const float* a3d = (const float*)d_in[10];
    const float* Wd = (const float*)d_in[11];
    const float* bd = (const float*)d_in[12];
    float* outp = (float*)d_out;

    const int N = in_sizes[0] / 11;
    const int E = in_sizes[1] / 2;
    const int* src = ei;
    const int* dst = ei + E;

    const int NT16 = ((N + 127) / 128) * 8;  // padded 16-row tiles
    const int NMT = (N + 127) / 128;         // 128-row M-tiles

    char* w = (char*)d_ws;
    size_t off = 0;
    auto A = [&](size_t bytes) {
        size_t o = off;
        off += (bytes + 255) & ~(size_t)255;
        return o;
    };
    unsigned char* bufH = (unsigned char*)(w + A((size_t)N * 384 * 2));   // h (fp8 all layers)
    __hip_bfloat16* bufO = (__hip_bfloat16*)(w + A((size_t)N * 384 * 2));  // layer3 out (bf16)
    unsigned short* apH = (unsigned short*)(w + A((size_t)NT16 * 6 * 512 * 2));  // A-pack
    unsigned short* b2H = (unsigned short*)(w + A((size_t)16 * 3 * 512 * 2));    // W2 pack
    unsigned short* b3H = (unsigned short*)(w + A((size_t)24 * 6 * 512 * 2));    // W3 pack
    float* es = (float*)(w + A((size_t)N * HHEADS * 4));
    float* ed = (float*)(w + A((size_t)N * HHEADS * 4));
    unsigned* gmax = (unsigned*)(w + A(256));
    float* wp = (float*)(w + A((size_t)11 * 96 * 4));  // layer-1 f32 repack
    int* count = (int*)(w + A((size_t)(N + 1) * 4));
    int* cursor = (int*)(w + A((size_t)(N + 1) * 4));
    int* offsets = (int*)(w + A((size_t)(N + 1) * 4));
    int* bsum = (int*)(w + A(64 * 4));
    int* ssrc = (int*)(w + A((size_t)E * 4));
    float* g = (float*)(w + A(384 * 4));

    // one-shot zero of all small scratch (count, cursor, g, gmax, A-pack pads)
    const long t16v = N / 16;
    const long padT = NT16 - t16v;
    zero_misc<<<(N + 255) / 256, 256, 0, stream>>>(count, cursor, g, gmax, apH,
                                                   t16v * 3 * 512, padT * 3 * 512,
                                                   t16v * 6 * 512, padT * 6 * 512, N);

    // CSR build (by dst)
    hist_kernel<<<(E + 255) / 256, 256, 0, stream>>>(dst, count, E);
    int nb = (N + 1023) / 1024;
    scan_block<<<nb, 1024, 0, stream>>>(count, offsets, bsum, N);
    scan_tops<<<1, 64, 0, stream>>>(bsum, nb);
    scan_add<<<nb, 1024, 0, stream>>>(offsets, bsum, N, E);
    scatter_kernel<<<(E + 255) / 256, 256, 0, stream>>>(src, dst, offsets, cursor, ssrc, E);

    // weight packs
    repack_w<<<(11 * 96 + 255) / 256, 256, 0, stream>>>(W1, wp, 11, 16);
    repack_w_mfma<<<(96 * 256 + 255) / 256, 256, 0, stream>>>(W2, b2H, 96, 32, 256);
    repack_w_mfma<<<(192 * 384 + 255) / 256, 256, 0, stream>>>(W3, b3H, 192, 64, 384);

    // ---- layer 1 (FIN=11, F=16): gemm (fp8 C) + fused attn terms ----
    {
        dim3 grid((96 + 63) / 64, (N + 63) / 64);
        gemm_small_attn<64, 64, 32><<<grid, 256, 0, stream>>>(x, wp, bufH, a1s, a1d, es, ed, N,
                                                              11, 96);
    }
    {
        long total = (long)N * (96 / 8);
        aggregate_fused<16><<<(total + 255) / 256, 256, 0, stream>>>(bufH, es, ed, offsets,
                                                                     ssrc, apH, N);
    }

    // ---- layer 2 (K=96, N=192 pad 256, F=32): fp8 C + fused gmax(6-11) ----
    {
        dim3 grid(2, (NMT + 3) / 4);
        gemm_attn_mfma<96, 192, 256, 32, 4><<<grid, 256, 0, stream>>>(apH, b2H, bufH, a2s,
                                                                      a2d, es, ed, gmax, N);
    }
    {
        int grid = (N + 3) / 4;  // 4 waves/block, wave-per-node
        aggregate_wpn2<<<grid, 256, 0, stream>>>(bufH, es, ed, gmax, offsets, ssrc, apH, N);
    }

    // ---- layer 3 (K=192, N=384, F=64): fp8 C + fused gmax(0-5) ----
    {
        dim3 grid(3, (NMT + 3) / 4);
        gemm_attn_mfma<192, 384, 384, 64, 4><<<grid, 256, 0, stream>>>(apH, b3H, bufH, a3s,
                                                                       a3d, es, ed, gmax, N);
    }
    {
        int grid = (N + 3) / 4;
        aggregate_wpn3<<<grid, 256, 0, stream>>>(bufH, es, ed, gmax, offsets, ssrc, bufO, N);
    }

    // sum-pool (bf16 in) -> normalize -> dense
    pool_kernel<<<256, 192, 0, stream>>>(bufO, g, N);
    final_kernel<<<1, 384, 0, stream>>>(g, Wd, bd, outp);
}

// Round 13
// 489.281 us; speedup vs baseline: 1.1538x; 1.0551x over previous
//
#include <hip/hip_runtime.h>
#include <hip/hip_bf16.h>

// GAT 3-layer: N=50000 nodes, E=800000 edges, H=6 heads.
// R1-R17: MFMA GEMMs + CSR fused softmax/aggregate ladder (545us).
// R20/R21: wave-per-node aggregates; h -> fp8 e4m3 (absmax 2.4e-4 passes).
// R22-R26: GEMM per-block-overhead fix (MT=4 M-tiles, persistent-B): 527us.
// R27: fp8 h for all layers' gathers: 513us.
// R28 FAILED: slice->XCD pinning (564us) - 8x XCD fetch amplification is
//      structural for dst-centric gather on a random graph; wave-per-node
//      coalescing is the win, don't break it.
// R29: revert + packed f32x2 FMA: 516us; wpn3 67us, FETCH 154.6MB (floor),
//      but service rate only 2.9 TB/s vs 3.7 TB/s the same structure hit in
//      R20 -> latency/MLP gap, not bandwidth wall.
// R30: 4-edge unroll in wpn3/wpn2 (4 independent h-loads + 4 es in flight
//      per wave iteration, 2x outstanding lines; VGPR 24->~36, no occupancy
//      cliff). Accumulation order strictly sequential -> bit-identical.

#define HHEADS 6

typedef __attribute__((ext_vector_type(8))) short bf16x8;   // 8 bf16 = 4 VGPR
typedef __attribute__((ext_vector_type(4))) float f32x4;    // mfma C/D
typedef __attribute__((ext_vector_type(2))) float f32x2;

typedef __attribute__((address_space(3))) unsigned int lds_uint;
typedef const __attribute__((address_space(1))) unsigned int glb_uint;

__device__ __forceinline__ float bfl(unsigned u) { return __uint_as_float(u << 16); }
__device__ __forceinline__ float bfh(unsigned u) { return __uint_as_float(u & 0xffff0000u); }
__device__ __forceinline__ unsigned short f2bf(float v) {  // RNE f32->bf16
    unsigned u = __float_as_uint(v);
    return (unsigned short)((u + 0x7fffu + ((u >> 16) & 1u)) >> 16);
}
__device__ __forceinline__ float bf2f(unsigned short h) {
    return __uint_as_float((unsigned)h << 16);
}
// monotone float<->uint for atomicMax on floats (memset-0 = -inf identity)
__device__ __forceinline__ unsigned fkey(float f) {
    unsigned u = __float_as_uint(f);
    return (u >> 31) ? ~u : (u | 0x80000000u);
}
__device__ __forceinline__ float funkey(unsigned k) {
    return (k >> 31) ? __uint_as_float(k & 0x7fffffffu) : __uint_as_float(~k);
}

// 4x4 transpose across a 4-lane group (lanes share lane>>2). In: v0..v3 =
// rows 0..3 at this lane's column. Out: v0..v3 = cols 0..3 at row (lane&3).
__device__ __forceinline__ void xpose4(float& v0, float& v1, float& v2, float& v3, int b) {
    bool hi = (b & 2) != 0;
    float s0 = hi ? v0 : v2;
    float s1 = hi ? v1 : v3;
    s0 = __shfl_xor(s0, 2, 64);
    s1 = __shfl_xor(s1, 2, 64);
    v0 = hi ? s0 : v0;
    v1 = hi ? s1 : v1;
    v2 = hi ? v2 : s0;
    v3 = hi ? v3 : s1;
    bool od = (b & 1) != 0;
    float t0 = od ? v0 : v1;
    t0 = __shfl_xor(t0, 1, 64);
    v0 = od ? t0 : v0;
    v1 = od ? v1 : t0;
    float t1 = od ? v2 : v3;
    t1 = __shfl_xor(t1, 1, 64);
    v2 = od ? t1 : v2;
    v3 = od ? v3 : t1;
}

// ---------------- one-shot zero of all small scratch ----------------
__global__ void zero_misc(int* __restrict__ count, int* __restrict__ cursor,
                          float* __restrict__ g, unsigned* __restrict__ gmax,
                          unsigned short* __restrict__ apH,
                          long pad3_off, long pad3_cnt, long pad6_off, long pad6_cnt, int n) {
    long i = (long)blockIdx.x * blockDim.x + threadIdx.x;
    long stride = (long)gridDim.x * blockDim.x;
    for (long j = i; j < n; j += stride) {
        count[j] = 0;
        cursor[j] = 0;
    }
    if (i < 384) g[i] = 0.f;
    if (i < 12) gmax[i] = 0u;  // slots 0-5: L3, 6-11: L2
    for (long j = i; j < pad3_cnt; j += stride) apH[pad3_off + j] = 0;
    for (long j = i; j < pad6_cnt; j += stride) apH[pad6_off + j] = 0;
}

// ---------------- CSR build ----------------
__global__ void hist_kernel(const int* __restrict__ dst, int* __restrict__ count, int E) {
    int e = blockIdx.x * blockDim.x + threadIdx.x;
    if (e >= E) return;
    atomicAdd(&count[dst[e]], 1);
}

__global__ void scan_block(const int* __restrict__ count, int* __restrict__ offsets,
                           int* __restrict__ bsum, int n) {
    __shared__ int s[1024];
    int i = blockIdx.x * 1024 + threadIdx.x;
    int v = (i < n) ? count[i] : 0;
    s[threadIdx.x] = v;
    __syncthreads();
    for (int off = 1; off < 1024; off <<= 1) {
        int t = (threadIdx.x >= (unsigned)off) ? s[threadIdx.x - off] : 0;
        __syncthreads();
        s[threadIdx.x] += t;
        __syncthreads();
    }
    if (i < n) offsets[i] = s[threadIdx.x] - v;
    if (threadIdx.x == 1023) bsum[blockIdx.x] = s[1023];
}

__global__ void scan_tops(int* __restrict__ bsum, int nb) {
    __shared__ int s[64];
    int t = threadIdx.x;
    int v = (t < nb) ? bsum[t] : 0;
    s[t] = v;
    __syncthreads();
    for (int off = 1; off < 64; off <<= 1) {
        int tmp = (t >= off) ? s[t - off] : 0;
        __syncthreads();
        s[t] += tmp;
        __syncthreads();
    }
    if (t < nb) bsum[t] = s[t] - v;
}

__global__ void scan_add(int* __restrict__ offsets, const int* __restrict__ bsum, int n,
                         int total) {
    int i = blockIdx.x * 1024 + threadIdx.x;
    if (i < n) offsets[i] += bsum[blockIdx.x];
    if (i == 0) offsets[n] = total;
}

__global__ void scatter_kernel(const int* __restrict__ src, const int* __restrict__ dst,
                               const int* __restrict__ offsets, int* __restrict__ cursor,
                               int* __restrict__ ssrc, int E) {
    int e = blockIdx.x * blockDim.x + threadIdx.x;
    if (e >= E) return;
    int d = dst[e];
    int pos = offsets[d] + atomicAdd(&cursor[d], 1);
    ssrc[pos] = src[e];
}

// ---------------- weight repacks ----------------
__global__ void repack_w(const float* __restrict__ W, float* __restrict__ Wp, int FIN, int F) {
    int HF = HHEADS * F;
    int i = blockIdx.x * blockDim.x + threadIdx.x;
    if (i >= FIN * HF) return;
    int k = i / HF, c = i % HF;
    int hd = c / F, f = c % F;
    Wp[i] = W[(hd * FIN + k) * F + f];
}

// bf16 pack in MFMA B-fragment layout (B^T: lane n=..&15, k contiguous)
__global__ void repack_w_mfma(const float* __restrict__ W, unsigned short* __restrict__ bh,
                              int FIN, int F, int NPAD) {
    int i = blockIdx.x * blockDim.x + threadIdx.x;
    if (i >= FIN * NPAD) return;
    int k = i / NPAD, n = i % NPAD;
    int NKT = FIN / 32;
    int HF = HHEADS * F;
    float w = 0.f;
    if (n < HF) {
        int hd = n / F, f = n % F;
        w = W[(hd * FIN + k) * F + f];
    }
    size_t e = ((size_t)((n >> 4) * NKT + (k >> 5)) * 64 + ((n & 15) | (((k >> 3) & 3) << 4))) * 8 +
               (k & 7);
    bh[e] = f2bf(w);
}

// ---------------- small GEMM + fused attn (layer 1, K=11, F=16) ----------------
// C written fp8 e4m3 (feeds only aggregate_fused).
template <int BM, int BN, int BK>
__global__ __launch_bounds__(256) void gemm_small_attn(const float* __restrict__ A,
                                                       const float* __restrict__ B,
                                                       unsigned char* __restrict__ C8,
                                                       const float* __restrict__ as_,
                                                       const float* __restrict__ ad_,
                                                       float* __restrict__ es,
                                                       float* __restrict__ ed, int M, int K,
                                                       int N) {
    __shared__ float As[BK][BM + 4];
    __shared__ float Bs[BK][BN];
    int tid = threadIdx.x;
    int tx = tid % 16, ty = tid / 16;
    int m0 = blockIdx.y * BM, n0 = blockIdx.x * BN;
    float acc[4][4] = {};
    for (int kk0 = 0; kk0 < K; kk0 += BK) {
#pragma unroll
        for (int i = 0; i < (BM * BK) / 256; ++i) {
            int idx = tid + i * 256;
            int m = idx / BK, k = idx % BK;
            float v = 0.f;
            if (m0 + m < M && kk0 + k < K) v = A[(size_t)(m0 + m) * K + kk0 + k];
            As[k][m] = v;
        }
#pragma unroll
        for (int i = 0; i < (BK * BN) / 1024; ++i) {
            int idx = tid + i * 256;
            int k = idx / (BN / 4), n4 = idx % (BN / 4);
            float4 v = make_float4(0.f, 0.f, 0.f, 0.f);
            if (kk0 + k < K && n0 + n4 * 4 < N)
                v = *(const float4*)&B[(size_t)(kk0 + k) * N + n0 + n4 * 4];
            *(float4*)&Bs[k][n4 * 4] = v;
        }
        __syncthreads();
#pragma unroll
        for (int k = 0; k < BK; ++k) {
            float4 av = *(const float4*)&As[k][ty * 4];
            float4 bv = *(const float4*)&Bs[k][tx * 4];
            float a[4] = {av.x, av.y, av.z, av.w};
            float b[4] = {bv.x, bv.y, bv.z, bv.w};
#pragma unroll
            for (int i = 0; i < 4; ++i)
#pragma unroll
                for (int j = 0; j < 4; ++j) acc[i][j] += a[i] * b[j];
        }
        __syncthreads();
    }
    bool colok = (n0 + tx * 4) < N;
    float asv[4], adv[4];
#pragma unroll
    for (int j = 0; j < 4; ++j) {
        int col = n0 + tx * 4 + j;
        asv[j] = (col < N) ? as_[col] : 0.f;
        adv[j] = (col < N) ? ad_[col] : 0.f;
    }
#pragma unroll
    for (int i = 0; i < 4; ++i) {
        int m = m0 + ty * 4 + i;
        bool mok = m < M;
        if (mok && colok) {
            int pk = __builtin_amdgcn_cvt_pk_fp8_f32(acc[i][0], acc[i][1], 0, false);
            pk = __builtin_amdgcn_cvt_pk_fp8_f32(acc[i][2], acc[i][3], pk, true);
            *(unsigned*)&C8[(size_t)m * N + n0 + tx * 4] = (unsigned)pk;
        }
        float ps = 0.f, pd = 0.f;
#pragma unroll
        for (int j = 0; j < 4; ++j) {
            ps += acc[i][j] * asv[j];
            pd += acc[i][j] * adv[j];
        }
        ps += __shfl_down(ps, 2, 4);
        ps += __shfl_down(ps, 1, 4);
        pd += __shfl_down(pd, 2, 4);
        pd += __shfl_down(pd, 1, 4);
        if (mok && colok && (tx & 3) == 0) {
            int hd = (n0 + tx * 4) >> 4;  // F=16
            es[(size_t)m * HHEADS + hd] = ps;
            ed[(size_t)m * HHEADS + hd] = pd;
        }
    }
}

// ---------------- MFMA bf16 GEMM + fused attn (layers 2/3) ----------------
// MT M-tiles per block; persistent B in LDS; A double-buffered; fp8 row-major C.
// F==64: gmax slots 0-5. F==32: gmax slots 6-11.
template <int K, int NREAL, int NPAD, int F, int MT>
__global__ __launch_bounds__(256) void gemm_attn_mfma(
    const unsigned short* __restrict__ Ah, const unsigned short* __restrict__ Bh,
    unsigned char* __restrict__ C8, const float* __restrict__ as_,
    const float* __restrict__ ad_, float* __restrict__ es, float* __restrict__ ed,
    unsigned* __restrict__ gmax, int M) {
    constexpr int NKT = K / 32;
    __shared__ unsigned short sB[NKT * 4096];  // persistent B panel
    __shared__ unsigned short sA[2][4096];     // A double buffer
    int tid = threadIdx.x;
    int lane = tid & 63, wave = tid >> 6;
    int wrow = wave >> 1, wcol = wave & 1;
    int quad = lane >> 4, c16 = lane & 15;

    // XCD-bijective swizzle (m204): co-locate blocks sharing B panels.
    int nwg = gridDim.x * gridDim.y;
    int hh = blockIdx.y * gridDim.x + blockIdx.x;
    int q = nwg >> 3, r = nwg & 7;
    int xcd = hh & 7, pos = hh >> 3;
    int wk = (xcd < r ? xcd * (q + 1) : r * (q + 1) + (xcd - r) * q) + pos;
    int bx = wk % gridDim.x, by = wk / gridDim.x;

    int n0 = bx * 128;
    int bn16 = n0 >> 4;
    int nmt = (M + 127) >> 7;  // number of valid 128-row M-tiles

    // ---- stage entire B panel (once) ----
#pragma unroll
    for (int kt2 = 0; kt2 < NKT; ++kt2) {
#pragma unroll
        for (int rep = 0; rep < 2; ++rep) {
            int chunk = tid + rep * 256;
            int tile = chunk >> 6, e8 = chunk & 63;
            size_t boff = ((size_t)((bn16 + tile) * NKT + kt2) * 64 + e8) * 8;
            __builtin_amdgcn_global_load_lds((glb_uint*)&Bh[boff],
                                             (lds_uint*)&sB[kt2 * 4096 + chunk * 8], 16, 0, 0);
        }
    }
    auto STAGE_A = [&](int mti, int kt2, int buf) {
#pragma unroll
        for (int rep = 0; rep < 2; ++rep) {
            int chunk = tid + rep * 256;
            int tile = chunk >> 6, e8 = chunk & 63;
            size_t aoff = ((size_t)((mti * 8 + tile) * NKT + kt2) * 64 + e8) * 8;
            __builtin_amdgcn_global_load_lds((glb_uint*)&Ah[aoff],
                                             (lds_uint*)&sA[buf][chunk * 8], 16, 0, 0);
        }
    };
    STAGE_A(min(by * MT, nmt - 1), 0, 0);
    asm volatile("s_waitcnt vmcnt(0)" ::: "memory");
    __builtin_amdgcn_s_barrier();

    float asv[4], adv[4];
#pragma unroll
    for (int j = 0; j < 4; ++j) {
        int col = n0 + wcol * 64 + j * 16 + c16;
        bool ok = col < NREAL;
        asv[j] = ok ? as_[col] : 0.f;
        adv[j] = ok ? ad_[col] : 0.f;
    }
    float mx = -1e30f;                 // F==64 per-wave head max (across mts)
    float mxA = -1e30f, mxB = -1e30f;  // F==32 per-wave 2-head max
    bool colvalid = (n0 + wcol * 64) < NREAL;
    int b4 = lane & 3;

    f32x4 acc[4][4] = {};
    const int T = MT * NKT;
    int mt = 0, kt = 0;
    for (int t = 0; t < T; ++t) {
        int cur = t & 1;
        int nkt = kt + 1, nmt2 = mt;
        if (nkt == NKT) {
            nkt = 0;
            nmt2 = mt + 1;
        }
        if (t + 1 < T) STAGE_A(min(by * MT + nmt2, nmt - 1), nkt, cur ^ 1);  // issue-early
        bf16x8 fah[4], fbh[4];
#pragma unroll
        for (int i = 0; i < 4; ++i) {
            fah[i] = *(const bf16x8*)&sA[cur][(wrow * 4 + i) * 512 + lane * 8];
            fbh[i] = *(const bf16x8*)&sB[kt * 4096 + (wcol * 4 + i) * 512 + lane * 8];
        }
        asm volatile("s_waitcnt lgkmcnt(0)" ::: "memory");
        __builtin_amdgcn_sched_barrier(0);  // rule #18
#pragma unroll
        for (int i = 0; i < 4; ++i)
#pragma unroll
            for (int j = 0; j < 4; ++j)
                acc[i][j] = __builtin_amdgcn_mfma_f32_16x16x32_bf16(fah[i], fbh[j], acc[i][j],
                                                                    0, 0, 0);
        if (kt == NKT - 1) {  // M-tile complete: epilogue (uniform branch)
            int m0 = (by * MT + mt) * 128;
            if (m0 < M) {
                // ---- es/ed + gmax partial (fragment layout) ----
#pragma unroll
                for (int i = 0; i < 4; ++i) {
#pragma unroll
                    for (int r2 = 0; r2 < 4; ++r2) {
                        int m = m0 + wrow * 64 + i * 16 + quad * 4 + r2;
                        bool mok = m < M;
                        if (F == 64) {
                            float ps = acc[i][0][r2] * asv[0] + acc[i][1][r2] * asv[1] +
                                       acc[i][2][r2] * asv[2] + acc[i][3][r2] * asv[3];
                            float pd = acc[i][0][r2] * adv[0] + acc[i][1][r2] * adv[1] +
                                       acc[i][2][r2] * adv[2] + acc[i][3][r2] * adv[3];
#pragma unroll
                            for (int off = 8; off > 0; off >>= 1) {
                                ps += __shfl_down(ps, off, 16);
                                pd += __shfl_down(pd, off, 16);
                            }
                            if (mok && c16 == 0) {
                                int hd = (n0 + wcol * 64) / 64;
                                es[(size_t)m * HHEADS + hd] = ps;
                                ed[(size_t)m * HHEADS + hd] = pd;
                                mx = fmaxf(mx, ps);
                            }
                        } else {  // F == 32: two heads per wave-column
                            float psA = acc[i][0][r2] * asv[0] + acc[i][1][r2] * asv[1];
                            float pdA = acc[i][0][r2] * adv[0] + acc[i][1][r2] * adv[1];
                            float psB = acc[i][2][r2] * asv[2] + acc[i][3][r2] * asv[3];
                            float pdB = acc[i][2][r2] * adv[2] + acc[i][3][r2] * adv[3];
#pragma unroll
                            for (int off = 8; off > 0; off >>= 1) {
                                psA += __shfl_down(psA, off, 16);
                                pdA += __shfl_down(pdA, off, 16);
                                psB += __shfl_down(psB, off, 16);
                                pdB += __shfl_down(pdB, off, 16);
                            }
                            if (mok && c16 == 0 && colvalid) {
                                int colbase = n0 + wcol * 64;
                                int hd = colbase / 32;
                                es[(size_t)m * HHEADS + hd] = psA;
                                ed[(size_t)m * HHEADS + hd] = pdA;
                                es[(size_t)m * HHEADS + hd + 1] = psB;
                                ed[(size_t)m * HHEADS + hd + 1] = pdB;
                                mxA = fmaxf(mxA, psA);
                                mxB = fmaxf(mxB, psB);
                            }
                        }
                    }
                }
                // ---- C store (fp8): transpose 16x16 blocks, dword stores ----
#pragma unroll
                for (int i = 0; i < 4; ++i) {
                    int m = m0 + wrow * 64 + i * 16 + quad * 4 + b4;
                    bool mok = m < M;
#pragma unroll
                    for (int j = 0; j < 4; ++j) {
                        float v0 = acc[i][j][0], v1 = acc[i][j][1], v2 = acc[i][j][2],
                              v3 = acc[i][j][3];
                        xpose4(v0, v1, v2, v3, b4);
                        int colb = n0 + wcol * 64 + j * 16 + (c16 & 12);
                        if (mok && (F == 64 || colvalid)) {
                            int pk = __builtin_amdgcn_cvt_pk_fp8_f32(v0, v1, 0, false);
                            pk = __builtin_amdgcn_cvt_pk_fp8_f32(v2, v3, pk, true);
                            *(unsigned*)&C8[(size_t)m * NREAL + colb] = (unsigned)pk;
                        }
                    }
                }
            }
#pragma unroll
            for (int i = 0; i < 4; ++i)
#pragma unroll
                for (int j = 0; j < 4; ++j) acc[i][j] = (f32x4){0.f, 0.f, 0.f, 0.f};
        }
        asm volatile("s_waitcnt vmcnt(0)" ::: "memory");
        __builtin_amdgcn_s_barrier();
        kt = nkt;
        mt = nmt2;
    }

    if (F == 64) {  // per-head global es max, one atomic per wave per block
#pragma unroll
        for (int off = 32; off > 0; off >>= 1) mx = fmaxf(mx, __shfl_xor(mx, off));
        if (lane == 0) atomicMax(&gmax[(n0 + wcol * 64) / 64], fkey(mx));
    } else {
        mxA = fmaxf(mxA, __shfl_xor(mxA, 16));
        mxA = fmaxf(mxA, __shfl_xor(mxA, 32));
        mxB = fmaxf(mxB, __shfl_xor(mxB, 16));
        mxB = fmaxf(mxB, __shfl_xor(mxB, 32));
        if (lane == 0 && colvalid) {
            int hd = (n0 + wcol * 64) / 32;
            atomicMax(&gmax[6 + hd], fkey(mxA));
            atomicMax(&gmax[6 + hd + 1], fkey(mxB));
        }
    }
}

// ---------------- online-rescale softmax-aggregate (layer 1, fp8 h) -----------
// Thread per (node, 8ch); fp8 gather + HW unpack; packed f32x2 FMA accum.
template <int F>
__global__ __launch_bounds__(256) void aggregate_fused(
    const unsigned char* __restrict__ h8, const float* __restrict__ es,
    const float* __restrict__ ed, const int* __restrict__ offsets,
    const int* __restrict__ ssrc, unsigned short* __restrict__ oh, int n) {
    constexpr int HF = HHEADS * F;
    constexpr int C8 = HF / 8;
    int tid = blockIdx.x * blockDim.x + threadIdx.x;
    if (tid >= n * C8) return;
    int node = tid / C8, q = tid % C8;
    int c = q * 8, hd = c / F;
    int a = offsets[node], b = offsets[node + 1];
    float edv = ed[node * HHEADS + hd];
    float m = -1e30f, l = 0.f;
    f32x2 a0 = {0.f, 0.f}, a1 = {0.f, 0.f}, a2 = {0.f, 0.f}, a3 = {0.f, 0.f};
    for (int j = a; j < b; ++j) {
        int s = ssrc[j];
        float v = es[s * HHEADS + hd] + edv;
        v = v > 0.f ? v : 0.2f * v;  // leaky relu 0.2
        float mn = fmaxf(m, v);
        float r = __expf(m - mn);
        float wgt = __expf(v - mn);
        uint2 hv = *(const uint2*)&h8[(size_t)s * HF + c];
        f32x2 p0 = __builtin_amdgcn_cvt_pk_f32_fp8((int)hv.x, false);
        f32x2 p1 = __builtin_amdgcn_cvt_pk_f32_fp8((int)hv.x, true);
        f32x2 p2 = __builtin_amdgcn_cvt_pk_f32_fp8((int)hv.y, false);
        f32x2 p3 = __builtin_amdgcn_cvt_pk_f32_fp8((int)hv.y, true);
        l = l * r + wgt;
        f32x2 rv = {r, r}, wv = {wgt, wgt};
        a0 = a0 * rv + wv * p0;
        a1 = a1 * rv + wv * p1;
        a2 = a2 * rv + wv * p2;
        a3 = a3 * rv + wv * p3;
        m = mn;
    }
    float invd = 1.0f / (l + 1e-16f);
    float res[8] = {a0[0], a0[1], a1[0], a1[1], a2[0], a2[1], a3[0], a3[1]};
    unsigned short th[8];
#pragma unroll
    for (int k = 0; k < 8; ++k) {
        float v = res[k] * invd;
        v = v > 0.f ? v : (__expf(v) - 1.0f);  // elu
        th[k] = f2bf(v);
    }
    constexpr int NKT = HF / 32;
    int lq = (node & 15) | (((c >> 3) & 3) << 4);
    size_t base = ((size_t)((node >> 4) * NKT + (c >> 5)) * 64 + lq) * 8;
    *(uint4*)&oh[base] = *(uint4*)th;
}

// ---------------- wave-per-node single-pass aggregate (layer 2, fp8 h) --------
// Lanes 0..47 own 4 channels (uint = 4 fp8); packed f32x2 FMA; 4-edge unroll.
__global__ __launch_bounds__(256) void aggregate_wpn2(
    const unsigned char* __restrict__ h8, const float* __restrict__ es,
    const float* __restrict__ ed, const unsigned* __restrict__ gmax,
    const int* __restrict__ offsets, const int* __restrict__ ssrc,
    unsigned short* __restrict__ oh, int n) {
    constexpr int HF = 192;
    int wid = (int)((blockIdx.x * (unsigned)blockDim.x + threadIdx.x) >> 6);
    int lane = threadIdx.x & 63;
    if (wid >= n || lane >= 48) return;
    int node = wid;
    int hd = lane >> 3;  // F=32: 8 lanes (32ch) per head
    int c = lane * 4;
    int a = offsets[node], b = offsets[node + 1];
    float edv = ed[node * HHEADS + hd];
    float mv = funkey(gmax[6 + hd]) + edv;
    float m = mv > 0.f ? mv : 0.2f * mv;
    float l = 0.f;
    f32x2 a0 = {0.f, 0.f}, a1 = {0.f, 0.f};
    const unsigned char* hbase = h8 + c;
    int j = a;
    for (; j + 3 < b; j += 4) {
        int s0 = ssrc[j], s1 = ssrc[j + 1], s2 = ssrc[j + 2], s3 = ssrc[j + 3];
        float ev0 = es[(size_t)s0 * HHEADS + hd];
        float ev1 = es[(size_t)s1 * HHEADS + hd];
        float ev2 = es[(size_t)s2 * HHEADS + hd];
        float ev3 = es[(size_t)s3 * HHEADS + hd];
        unsigned h0 = *(const unsigned*)(hbase + (size_t)s0 * HF);
        unsigned h1 = *(const unsigned*)(hbase + (size_t)s1 * HF);
        unsigned h2 = *(const unsigned*)(hbase + (size_t)s2 * HF);
        unsigned h3 = *(const unsigned*)(hbase + (size_t)s3 * HF);
        float v0 = ev0 + edv;
        v0 = v0 > 0.f ? v0 : 0.2f * v0;
        float v1 = ev1 + edv;
        v1 = v1 > 0.f ? v1 : 0.2f * v1;
        float v2 = ev2 + edv;
        v2 = v2 > 0.f ? v2 : 0.2f * v2;
        float v3 = ev3 + edv;
        v3 = v3 > 0.f ? v3 : 0.2f * v3;
        float w0 = __expf(v0 - m);
        float w1 = __expf(v1 - m);
        float w2 = __expf(v2 - m);
        float w3 = __expf(v3 - m);
        {
            f32x2 p0 = __builtin_amdgcn_cvt_pk_f32_fp8((int)h0, false);
            f32x2 p1 = __builtin_amdgcn_cvt_pk_f32_fp8((int)h0, true);
            f32x2 wv = {w0, w0};
            l += w0;
            a0 = a0 + wv * p0;
            a1 = a1 + wv * p1;
        }
        {
            f32x2 p0 = __builtin_amdgcn_cvt_pk_f32_fp8((int)h1, false);
            f32x2 p1 = __builtin_amdgcn_cvt_pk_f32_fp8((int)h1, true);
            f32x2 wv = {w1, w1};
            l += w1;
            a0 = a0 + wv * p0;
            a1 = a1 + wv * p1;
        }
        {
            f32x2 p0 = __builtin_amdgcn_cvt_pk_f32_fp8((int)h2, false);
            f32x2 p1 = __builtin_amdgcn_cvt_pk_f32_fp8((int)h2, true);
            f32x2 wv = {w2, w2};
            l += w2;
            a0 = a0 + wv * p0;
            a1 = a1 + wv * p1;
        }
        {
            f32x2 p0 = __builtin_amdgcn_cvt_pk_f32_fp8((int)h3, false);
            f32x2 p1 = __builtin_amdgcn_cvt_pk_f32_fp8((int)h3, true);
            f32x2 wv = {w3, w3};
            l += w3;
            a0 = a0 + wv * p0;
            a1 = a1 + wv * p1;
        }
    }
    for (; j < b; ++j) {
        int s0 = ssrc[j];
        float ev0 = es[(size_t)s0 * HHEADS + hd];
        unsigned h0 = *(const unsigned*)(hbase + (size_t)s0 * HF);
        float v0 = ev0 + edv;
        v0 = v0 > 0.f ? v0 : 0.2f * v0;
        float w0 = __expf(v0 - m);
        f32x2 p0 = __builtin_amdgcn_cvt_pk_f32_fp8((int)h0, false);
        f32x2 p1 = __builtin_amdgcn_cvt_pk_f32_fp8((int)h0, true);
        f32x2 wv = {w0, w0};
        l += w0;
        a0 = a0 + wv * p0;
        a1 = a1 + wv * p1;
    }
    float invd = 1.0f / (l + 1e-16f);
    float res[4] = {a0[0], a0[1], a1[0], a1[1]};
    unsigned short th[4];
#pragma unroll
    for (int k = 0; k < 4; ++k) {
        float v = res[k] * invd;
        v = v > 0.f ? v : (__expf(v) - 1.0f);  // elu
        th[k] = f2bf(v);
    }
    int lq = (node & 15) | (((c >> 3) & 3) << 4);
    size_t base = ((size_t)((node >> 4) * (HF / 32) + (c >> 5)) * 64 + lq) * 8 + (c & 7);
    *(uint2*)&oh[base] = *(uint2*)th;
}

// ---------------- wave-per-node single-pass aggregate (layer 3, fp8 h) --------
// Lanes 0..47 own 8 fp8 ch (uint2); one coalesced 384B row/edge; scalar ssrc;
// packed f32x2 FMA; 4-edge unroll (4 rows + 4 es in flight per iteration).
__global__ __launch_bounds__(256) void aggregate_wpn3(
    const unsigned char* __restrict__ h8, const float* __restrict__ es,
    const float* __restrict__ ed, const unsigned* __restrict__ gmax,
    const int* __restrict__ offsets, const int* __restrict__ ssrc,
    __hip_bfloat16* __restrict__ outb, int n) {
    constexpr int HF = 384;
    int wid = (int)((blockIdx.x * (unsigned)blockDim.x + threadIdx.x) >> 6);
    int lane = threadIdx.x & 63;
    if (wid >= n || lane >= 48) return;
    int node = wid;
    int hd = lane >> 3;  // 8 lanes (64ch) per head
    int c = lane * 8;
    int a = offsets[node], b = offsets[node + 1];
    float edv = ed[node * HHEADS + hd];
    float mv = funkey(gmax[hd]) + edv;
    float m = mv > 0.f ? mv : 0.2f * mv;
    float l = 0.f;
    f32x2 a0 = {0.f, 0.f}, a1 = {0.f, 0.f}, a2 = {0.f, 0.f}, a3 = {0.f, 0.f};
    const unsigned char* hbase = h8 + c;
    int j = a;
    for (; j + 3 < b; j += 4) {
        int s0 = ssrc[j], s1 = ssrc[j + 1], s2 = ssrc[j + 2], s3 = ssrc[j + 3];
        float ev0 = es[(size_t)s0 * HHEADS + hd];
        float ev1 = es[(size_t)s1 * HHEADS + hd];
        float ev2 = es[(size_t)s2 * HHEADS + hd];
        float ev3 = es[(size_t)s3 * HHEADS + hd];
        uint2 h0 = *(const uint2*)(hbase + (size_t)s0 * HF);
        uint2 h1 = *(const uint2*)(hbase + (size_t)s1 * HF);
        uint2 h2 = *(const uint2*)(hbase + (size_t)s2 * HF);
        uint2 h3 = *(const uint2*)(hbase + (size_t)s3 * HF);
        float v0 = ev0 + edv;
        v0 = v0 > 0.f ? v0 : 0.2f * v0;
        float v1 = ev1 + edv;
        v1 = v1 > 0.f ? v1 : 0.2f * v1;
        float v2 = ev2 + edv;
        v2 = v2 > 0.f ? v2 : 0.2f * v2;
        float v3 = ev3 + edv;
        v3 = v3 > 0.f ? v3 : 0.2f * v3;
        float w0 = __expf(v0 - m);
        float w1 = __expf(v1 - m);
        float w2 = __expf(v2 - m);
        float w3 = __expf(v3 - m);
        {
            f32x2 p0 = __builtin_amdgcn_cvt_pk_f32_fp8((int)h0.x, false);
            f32x2 p1 = __builtin_amdgcn_cvt_pk_f32_fp8((int)h0.x, true);
            f32x2 p2 = __builtin_amdgcn_cvt_pk_f32_fp8((int)h0.y, false);
            f32x2 p3 = __builtin_amdgcn_cvt_pk_f32_fp8((int)h0.y, true);
            f32x2 wv = {w0, w0};
            l += w0;
            a0 = a0 + wv * p0;
            a1 = a1 + wv * p1;
            a2 = a2 + wv * p2;
            a3 = a3 + wv * p3;
        }
        {
            f32x2 p0 = __builtin_amdgcn_cvt_pk_f32_fp8((int)h1.x, false);
            f32x2 p1 = __builtin_amdgcn_cvt_pk_f32_fp8((int)h1.x, true);
            f32x2 p2 = __builtin_amdgcn_cvt_pk_f32_fp8((int)h1.y, false);
            f32x2 p3 = __builtin_amdgcn_cvt_pk_f32_fp8((int)h1.y, true);
            f32x2 wv = {w1, w1};
            l += w1;
            a0 = a0 + wv * p0;
            a1 = a1 + wv * p1;
            a2 = a2 + wv * p2;
            a3 = a3 + wv * p3;
        }
        {
            f32x2 p0 = __builtin_amdgcn_cvt_pk_f32_fp8((int)h2.x, false);
            f32x2 p1 = __builtin_amdgcn_cvt_pk_f32_fp8((int)h2.x, true);
            f32x2 p2 = __builtin_amdgcn_cvt_pk_f32_fp8((int)h2.y, false);
            f32x2 p3 = __builtin_amdgcn_cvt_pk_f32_fp8((int)h2.y, true);
            f32x2 wv = {w2, w2};
            l += w2;
            a0 = a0 + wv * p0;
            a1 = a1 + wv * p1;
            a2 = a2 + wv * p2;
            a3 = a3 + wv * p3;
        }
        {
            f32x2 p0 = __builtin_amdgcn_cvt_pk_f32_fp8((int)h3.x, false);
            f32x2 p1 = __builtin_amdgcn_cvt_pk_f32_fp8((int)h3.x, true);
            f32x2 p2 = __builtin_amdgcn_cvt_pk_f32_fp8((int)h3.y, false);
            f32x2 p3 = __builtin_amdgcn_cvt_pk_f32_fp8((int)h3.y, true);
            f32x2 wv = {w3, w3};
            l += w3;
            a0 = a0 + wv * p0;
            a1 = a1 + wv * p1;
            a2 = a2 + wv * p2;
            a3 = a3 + wv * p3;
        }
    }
    for (; j < b; ++j) {
        int s0 = ssrc[j];
        float ev0 = es[(size_t)s0 * HHEADS + hd];
        uint2 h0 = *(const uint2*)(hbase + (size_t)s0 * HF);
        float v0 = ev0 + edv;
        v0 = v0 > 0.f ? v0 : 0.2f * v0;
        float w0 = __expf(v0 - m);
        f32x2 p0 = __builtin_amdgcn_cvt_pk_f32_fp8((int)h0.x, false);
        f32x2 p1 = __builtin_amdgcn_cvt_pk_f32_fp8((int)h0.x, true);
        f32x2 p2 = __builtin_amdgcn_cvt_pk_f32_fp8((int)h0.y, false);
        f32x2 p3 = __builtin_amdgcn_cvt_pk_f32_fp8((int)h0.y, true);
        f32x2 wv = {w0, w0};
        l += w0;
        a0 = a0 + wv * p0;
        a1 = a1 + wv * p1;
        a2 = a2 + wv * p2;
        a3 = a3 + wv * p3;
    }
    float invd = 1.0f / (l + 1e-16f);
    float res[8] = {a0[0], a0[1], a1[0], a1[1], a2[0], a2[1], a3[0], a3[1]};
    __hip_bfloat16 tb[8];
#pragma unroll
    for (int k = 0; k < 8; ++k) {
        float v = res[k] * invd;
        v = v > 0.f ? v : (__expf(v) - 1.0f);  // elu
        tb[k] = __float2bfloat16(v);
    }
    *(uint4*)&outb[(size_t)node * HF + c] = *(uint4*)tb;
}

// ---------------- pooling (bf16 input) + head ----------------
__global__ void pool_kernel(const __hip_bfloat16* __restrict__ out3, float* __restrict__ g,
                            int n) {
    int b = blockIdx.x, t = threadIdx.x;  // blockDim = 192
    int chunk = (n + gridDim.x - 1) / gridDim.x;
    int n0 = b * chunk, n1 = min(n, n0 + chunk);
    float a0 = 0.f, a1 = 0.f;
    const unsigned* p = (const unsigned*)out3;
    for (int node = n0; node < n1; ++node) {
        unsigned u = p[(size_t)node * 192 + t];
        a0 += bfl(u);
        a1 += bfh(u);
    }
    atomicAdd(&g[2 * t], a0);
    atomicAdd(&g[2 * t + 1], a1);
}

__global__ void final_kernel(const float* __restrict__ g, const float* __restrict__ Wd,
                             const float* __restrict__ bd, float* __restrict__ outp) {
    __shared__ float red[384];
    int t = threadIdx.x;  // blockDim = 384
    float v = g[t];
    red[t] = v * v;
    __syncthreads();
    for (int s = 192; s >= 3; s >>= 1) {
        if (t < s) red[t] += red[t + s];
        __syncthreads();
    }
    __shared__ float scale_s;
    if (t == 0) {
        float norm = sqrtf(red[0] + red[1] + red[2]);
        scale_s = 1.0f / fmaxf(norm, 1e-12f);
    }
    __syncthreads();
    float scale = scale_s;
    red[t] = v * scale * Wd[t];
    __syncthreads();
    for (int s = 192; s >= 3; s >>= 1) {
        if (t < s) red[t] += red[t + s];
        __syncthreads();
    }
    if (t == 0) outp[0] = red[0] + red[1] + red[2] + bd[0];
}

// ---------------- host side ----------------
extern "C" void kernel_launch(void* const* d_in, const int* in_sizes, int n_in, void* d_out,
                              int out_size, void* d_ws, size_t ws_size, hipStream_t stream) {
    const float* x = (const float*)d_in[0];
    const int* ei = (const int*)d_in[1];
    const float* W1 = (const float*)d_in[2];
    const float* a1s = (const float*)d_in[3];
    const float* a1d = (const float*)d_in[4];
    const float* W2 = (const float*)d_in[5];
    const float* a2s = (const float*)d_in[6];
    const float* a2d = (const float*)d_in[7];
    const float* W3 = (const float*)d_in[8];
    const float* a3s = (const float*)d_in[9];
    const float* a3d = (const float*)d_in[10];
    const float* Wd = (const float*)d_in[11];
    const float* bd = (const float*)d_in[12];
    float* outp = (float*)d_out;

    const int N = in_sizes[0] / 11;
    const int E = in_sizes[1] / 2;
    const int* src = ei;
    const int* dst = ei + E;

    const int NT16 = ((N + 127) / 128) * 8;  // padded 16-row tiles
    const int NMT = (N + 127) / 128;         // 128-row M-tiles

    char* w = (char*)d_ws;
    size_t off = 0;
    auto A = [&](size_t bytes) {
        size_t o = off;
        off += (bytes + 255) & ~(size_t)255;
        return o;
    };
    unsigned char* bufH = (unsigned char*)(w + A((size_t)N * 384 * 2));   // h (fp8 all layers)
    __hip_bfloat16* bufO = (__hip_bfloat16*)(w + A((size_t)N * 384 * 2));  // layer3 out (bf16)
    unsigned short* apH = (unsigned short*)(w + A((size_t)NT16 * 6 * 512 * 2));  // A-pack
    unsigned short* b2H = (unsigned short*)(w + A((size_t)16 * 3 * 512 * 2));    // W2 pack
    unsigned short* b3H = (unsigned short*)(w + A((size_t)24 * 6 * 512 * 2));    // W3 pack
    float* es = (float*)(w + A((size_t)N * HHEADS * 4));
    float* ed = (float*)(w + A((size_t)N * HHEADS * 4));
    unsigned* gmax = (unsigned*)(w + A(256));
    float* wp = (float*)(w + A((size_t)11 * 96 * 4));  // layer-1 f32 repack
    int* count = (int*)(w + A((size_t)(N + 1) * 4));
    int* cursor = (int*)(w + A((size_t)(N + 1) * 4));
    int* offsets = (int*)(w + A((size_t)(N + 1) * 4));
    int* bsum = (int*)(w + A(64 * 4));
    int* ssrc = (int*)(w + A((size_t)E * 4));
    float* g = (float*)(w + A(384 * 4));

    // one-shot zero of all small scratch (count, cursor, g, gmax, A-pack pads)
    const long t16v = N / 16;
    const long padT = NT16 - t16v;
    zero_misc<<<(N + 255) / 256, 256, 0, stream>>>(count, cursor, g, gmax, apH,
                                                   t16v * 3 * 512, padT * 3 * 512,
                                                   t16v * 6 * 512, padT * 6 * 512, N);

    // CSR build (by dst)
    hist_kernel<<<(E + 255) / 256, 256, 0, stream>>>(dst, count, E);
    int nb = (N + 1023) / 1024;
    scan_block<<<nb, 1024, 0, stream>>>(count, offsets, bsum, N);
    scan_tops<<<1, 64, 0, stream>>>(bsum, nb);
    scan_add<<<nb, 1024, 0, stream>>>(offsets, bsum, N, E);
    scatter_kernel<<<(E + 255) / 256, 256, 0, stream>>>(src, dst, offsets, cursor, ssrc, E);

    // weight packs
    repack_w<<<(11 * 96 + 255) / 256, 256, 0, stream>>>(W1, wp, 11, 16);
    repack_w_mfma<<<(96 * 256 + 255) / 256, 256, 0, stream>>>(W2, b2H, 96, 32, 256);
    repack_w_mfma<<<(192 * 384 + 255) / 256, 256, 0, stream>>>(W3, b3H, 192, 64, 384);

    // ---- layer 1 (FIN=11, F=16): gemm (fp8 C) + fused attn terms ----
    {
        dim3 grid((96 + 63) / 64, (N + 63) / 64);
        gemm_small_attn<64, 64, 32><<<grid, 256, 0, stream>>>(x, wp, bufH, a1s, a1d, es, ed, N,
                                                              11, 96);
    }
    {
        long total = (long)N * (96 / 8);
        aggregate_fused<16><<<(total + 255) / 256, 256, 0, stream>>>(bufH, es, ed, offsets,
                                                                     ssrc, apH, N);
    }

    // ---- layer 2 (K=96, N=192 pad 256, F=32): fp8 C + fused gmax(6-11) ----
    {
        dim3 grid(2, (NMT + 3) / 4);
        gemm_attn_mfma<96, 192, 256, 32, 4><<<grid, 256, 0, stream>>>(apH, b2H, bufH, a2s,
                                                                      a2d, es, ed, gmax, N);
    }
    {
        int grid = (N + 3) / 4;  // 4 waves/block, wave-per-node
        aggregate_wpn2<<<grid, 256, 0, stream>>>(bufH, es, ed, gmax, offsets, ssrc, apH, N);
    }

    // ---- layer 3 (K=192, N=384, F=64): fp8 C + fused gmax(0-5) ----
    {
        dim3 grid(3, (NMT + 3) / 4);
        gemm_attn_mfma<192, 384, 384, 64, 4><<<grid, 256, 0, stream>>>(apH, b3H, bufH, a3s,
                                                                       a3d, es, ed, gmax, N);
    }
    {
        int grid = (N + 3) / 4;
        aggregate_wpn3<<<grid, 256, 0, stream>>>(bufH, es, ed, gmax, offsets, ssrc, bufO, N);
    }

    // sum-pool (bf16 in) -> normalize -> dense
    pool_kernel<<<256, 192, 0, stream>>>(bufO, g, N);
    final_kernel<<<1, 384, 0, stream>>>(g, Wd, bd, outp);
}

// Round 15
// 432.455 us; speedup vs baseline: 1.3054x; 1.1314x over previous
//
#include <hip/hip_runtime.h>
#include <hip/hip_bf16.h>

// GAT 3-layer: N=50000 nodes, E=800000 edges, H=6 heads.
// R1-R17: MFMA GEMMs + CSR fused softmax/aggregate ladder (545us).
// R20/R21: wave-per-node aggregates; h -> fp8 e4m3 (absmax 2.4e-4 passes).
// R22-R26: GEMM per-block-overhead fix (MT=4 M-tiles, persistent-B): 527us.
// R27: fp8 h for all layers' gathers: 513us. R28 slice/XCD pinning FAILED.
// R29: revert + packed f32x2 FMA (516us). R30: 4-edge unroll (489us).
// R31: fuse sum-pool into wpn3 (bufO consumed only by pool): per-wave res in
//      registers -> LDS gp[4][384] -> 64-replica global accumulator. FAILED
//      on a one-line bug: c=(lane&47)*8 clears bit 4 (lanes 16-31 -> wrong
//      channels + gp[128..255] never written).
// R32: fix c = lane*8 (lane<48 guard suffices; OOB pointer arith never
//      dereferenced for lanes 48-63). Everything else identical to R31.

#define HHEADS 6

typedef __attribute__((ext_vector_type(8))) short bf16x8;   // 8 bf16 = 4 VGPR
typedef __attribute__((ext_vector_type(4))) float f32x4;    // mfma C/D
typedef __attribute__((ext_vector_type(2))) float f32x2;

typedef __attribute__((address_space(3))) unsigned int lds_uint;
typedef const __attribute__((address_space(1))) unsigned int glb_uint;

__device__ __forceinline__ float bfl(unsigned u) { return __uint_as_float(u << 16); }
__device__ __forceinline__ float bfh(unsigned u) { return __uint_as_float(u & 0xffff0000u); }
__device__ __forceinline__ unsigned short f2bf(float v) {  // RNE f32->bf16
    unsigned u = __float_as_uint(v);
    return (unsigned short)((u + 0x7fffu + ((u >> 16) & 1u)) >> 16);
}
__device__ __forceinline__ float bf2f(unsigned short h) {
    return __uint_as_float((unsigned)h << 16);
}
// monotone float<->uint for atomicMax on floats (memset-0 = -inf identity)
__device__ __forceinline__ unsigned fkey(float f) {
    unsigned u = __float_as_uint(f);
    return (u >> 31) ? ~u : (u | 0x80000000u);
}
__device__ __forceinline__ float funkey(unsigned k) {
    return (k >> 31) ? __uint_as_float(k & 0x7fffffffu) : __uint_as_float(~k);
}

// 4x4 transpose across a 4-lane group (lanes share lane>>2). In: v0..v3 =
// rows 0..3 at this lane's column. Out: v0..v3 = cols 0..3 at row (lane&3).
__device__ __forceinline__ void xpose4(float& v0, float& v1, float& v2, float& v3, int b) {
    bool hi = (b & 2) != 0;
    float s0 = hi ? v0 : v2;
    float s1 = hi ? v1 : v3;
    s0 = __shfl_xor(s0, 2, 64);
    s1 = __shfl_xor(s1, 2, 64);
    v0 = hi ? s0 : v0;
    v1 = hi ? s1 : v1;
    v2 = hi ? v2 : s0;
    v3 = hi ? v3 : s1;
    bool od = (b & 1) != 0;
    float t0 = od ? v0 : v1;
    t0 = __shfl_xor(t0, 1, 64);
    v0 = od ? t0 : v0;
    v1 = od ? v1 : t0;
    float t1 = od ? v2 : v3;
    t1 = __shfl_xor(t1, 1, 64);
    v2 = od ? t1 : v2;
    v3 = od ? v3 : t1;
}

// ---------------- one-shot zero of all small scratch ----------------
__global__ void zero_misc(int* __restrict__ count, int* __restrict__ cursor,
                          float* __restrict__ gmid, unsigned* __restrict__ gmax,
                          unsigned short* __restrict__ apH,
                          long pad3_off, long pad3_cnt, long pad6_off, long pad6_cnt, int n) {
    long i = (long)blockIdx.x * blockDim.x + threadIdx.x;
    long stride = (long)gridDim.x * blockDim.x;
    for (long j = i; j < n; j += stride) {
        count[j] = 0;
        cursor[j] = 0;
    }
    for (long j = i; j < 64 * 384; j += stride) gmid[j] = 0.f;
    if (i < 12) gmax[i] = 0u;  // slots 0-5: L3, 6-11: L2
    for (long j = i; j < pad3_cnt; j += stride) apH[pad3_off + j] = 0;
    for (long j = i; j < pad6_cnt; j += stride) apH[pad6_off + j] = 0;
}

// ---------------- CSR build ----------------
__global__ void hist_kernel(const int* __restrict__ dst, int* __restrict__ count, int E) {
    int e = blockIdx.x * blockDim.x + threadIdx.x;
    if (e >= E) return;
    atomicAdd(&count[dst[e]], 1);
}

__global__ void scan_block(const int* __restrict__ count, int* __restrict__ offsets,
                           int* __restrict__ bsum, int n) {
    __shared__ int s[1024];
    int i = blockIdx.x * 1024 + threadIdx.x;
    int v = (i < n) ? count[i] : 0;
    s[threadIdx.x] = v;
    __syncthreads();
    for (int off = 1; off < 1024; off <<= 1) {
        int t = (threadIdx.x >= (unsigned)off) ? s[threadIdx.x - off] : 0;
        __syncthreads();
        s[threadIdx.x] += t;
        __syncthreads();
    }
    if (i < n) offsets[i] = s[threadIdx.x] - v;
    if (threadIdx.x == 1023) bsum[blockIdx.x] = s[1023];
}

__global__ void scan_tops(int* __restrict__ bsum, int nb) {
    __shared__ int s[64];
    int t = threadIdx.x;
    int v = (t < nb) ? bsum[t] : 0;
    s[t] = v;
    __syncthreads();
    for (int off = 1; off < 64; off <<= 1) {
        int tmp = (t >= off) ? s[t - off] : 0;
        __syncthreads();
        s[t] += tmp;
        __syncthreads();
    }
    if (t < nb) bsum[t] = s[t] - v;
}

__global__ void scan_add(int* __restrict__ offsets, const int* __restrict__ bsum, int n,
                         int total) {
    int i = blockIdx.x * 1024 + threadIdx.x;
    if (i < n) offsets[i] += bsum[blockIdx.x];
    if (i == 0) offsets[n] = total;
}

__global__ void scatter_kernel(const int* __restrict__ src, const int* __restrict__ dst,
                               const int* __restrict__ offsets, int* __restrict__ cursor,
                               int* __restrict__ ssrc, int E) {
    int e = blockIdx.x * blockDim.x + threadIdx.x;
    if (e >= E) return;
    int d = dst[e];
    int pos = offsets[d] + atomicAdd(&cursor[d], 1);
    ssrc[pos] = src[e];
}

// ---------------- weight repacks ----------------
__global__ void repack_w(const float* __restrict__ W, float* __restrict__ Wp, int FIN, int F) {
    int HF = HHEADS * F;
    int i = blockIdx.x * blockDim.x + threadIdx.x;
    if (i >= FIN * HF) return;
    int k = i / HF, c = i % HF;
    int hd = c / F, f = c % F;
    Wp[i] = W[(hd * FIN + k) * F + f];
}

// bf16 pack in MFMA B-fragment layout (B^T: lane n=..&15, k contiguous)
__global__ void repack_w_mfma(const float* __restrict__ W, unsigned short* __restrict__ bh,
                              int FIN, int F, int NPAD) {
    int i = blockIdx.x * blockDim.x + threadIdx.x;
    if (i >= FIN * NPAD) return;
    int k = i / NPAD, n = i % NPAD;
    int NKT = FIN / 32;
    int HF = HHEADS * F;
    float w = 0.f;
    if (n < HF) {
        int hd = n / F, f = n % F;
        w = W[(hd * FIN + k) * F + f];
    }
    size_t e = ((size_t)((n >> 4) * NKT + (k >> 5)) * 64 + ((n & 15) | (((k >> 3) & 3) << 4))) * 8 +
               (k & 7);
    bh[e] = f2bf(w);
}

// ---------------- small GEMM + fused attn (layer 1, K=11, F=16) ----------------
// C written fp8 e4m3 (feeds only aggregate_fused).
template <int BM, int BN, int BK>
__global__ __launch_bounds__(256) void gemm_small_attn(const float* __restrict__ A,
                                                       const float* __restrict__ B,
                                                       unsigned char* __restrict__ C8,
                                                       const float* __restrict__ as_,
                                                       const float* __restrict__ ad_,
                                                       float* __restrict__ es,
                                                       float* __restrict__ ed, int M, int K,
                                                       int N) {
    __shared__ float As[BK][BM + 4];
    __shared__ float Bs[BK][BN];
    int tid = threadIdx.x;
    int tx = tid % 16, ty = tid / 16;
    int m0 = blockIdx.y * BM, n0 = blockIdx.x * BN;
    float acc[4][4] = {};
    for (int kk0 = 0; kk0 < K; kk0 += BK) {
#pragma unroll
        for (int i = 0; i < (BM * BK) / 256; ++i) {
            int idx = tid + i * 256;
            int m = idx / BK, k = idx % BK;
            float v = 0.f;
            if (m0 + m < M && kk0 + k < K) v = A[(size_t)(m0 + m) * K + kk0 + k];
            As[k][m] = v;
        }
#pragma unroll
        for (int i = 0; i < (BK * BN) / 1024; ++i) {
            int idx = tid + i * 256;
            int k = idx / (BN / 4), n4 = idx % (BN / 4);
            float4 v = make_float4(0.f, 0.f, 0.f, 0.f);
            if (kk0 + k < K && n0 + n4 * 4 < N)
                v = *(const float4*)&B[(size_t)(kk0 + k) * N + n0 + n4 * 4];
            *(float4*)&Bs[k][n4 * 4] = v;
        }
        __syncthreads();
#pragma unroll
        for (int k = 0; k < BK; ++k) {
            float4 av = *(const float4*)&As[k][ty * 4];
            float4 bv = *(const float4*)&Bs[k][tx * 4];
            float a[4] = {av.x, av.y, av.z, av.w};
            float b[4] = {bv.x, bv.y, bv.z, bv.w};
#pragma unroll
            for (int i = 0; i < 4; ++i)
#pragma unroll
                for (int j = 0; j < 4; ++j) acc[i][j] += a[i] * b[j];
        }
        __syncthreads();
    }
    bool colok = (n0 + tx * 4) < N;
    float asv[4], adv[4];
#pragma unroll
    for (int j = 0; j < 4; ++j) {
        int col = n0 + tx * 4 + j;
        asv[j] = (col < N) ? as_[col] : 0.f;
        adv[j] = (col < N) ? ad_[col] : 0.f;
    }
#pragma unroll
    for (int i = 0; i < 4; ++i) {
        int m = m0 + ty * 4 + i;
        bool mok = m < M;
        if (mok && colok) {
            int pk = __builtin_amdgcn_cvt_pk_fp8_f32(acc[i][0], acc[i][1], 0, false);
            pk = __builtin_amdgcn_cvt_pk_fp8_f32(acc[i][2], acc[i][3], pk, true);
            *(unsigned*)&C8[(size_t)m * N + n0 + tx * 4] = (unsigned)pk;
        }
        float ps = 0.f, pd = 0.f;
#pragma unroll
        for (int j = 0; j < 4; ++j) {
            ps += acc[i][j] * asv[j];
            pd += acc[i][j] * adv[j];
        }
        ps += __shfl_down(ps, 2, 4);
        ps += __shfl_down(ps, 1, 4);
        pd += __shfl_down(pd, 2, 4);
        pd += __shfl_down(pd, 1, 4);
        if (mok && colok && (tx & 3) == 0) {
            int hd = (n0 + tx * 4) >> 4;  // F=16
            es[(size_t)m * HHEADS + hd] = ps;
            ed[(size_t)m * HHEADS + hd] = pd;
        }
    }
}

// ---------------- MFMA bf16 GEMM + fused attn (layers 2/3) ----------------
// MT M-tiles per block; persistent B in LDS; A double-buffered; fp8 row-major C.
// F==64: gmax slots 0-5. F==32: gmax slots 6-11.
template <int K, int NREAL, int NPAD, int F, int MT>
__global__ __launch_bounds__(256) void gemm_attn_mfma(
    const unsigned short* __restrict__ Ah, const unsigned short* __restrict__ Bh,
    unsigned char* __restrict__ C8, const float* __restrict__ as_,
    const float* __restrict__ ad_, float* __restrict__ es, float* __restrict__ ed,
    unsigned* __restrict__ gmax, int M) {
    constexpr int NKT = K / 32;
    __shared__ unsigned short sB[NKT * 4096];  // persistent B panel
    __shared__ unsigned short sA[2][4096];     // A double buffer
    int tid = threadIdx.x;
    int lane = tid & 63, wave = tid >> 6;
    int wrow = wave >> 1, wcol = wave & 1;
    int quad = lane >> 4, c16 = lane & 15;

    // XCD-bijective swizzle (m204): co-locate blocks sharing B panels.
    int nwg = gridDim.x * gridDim.y;
    int hh = blockIdx.y * gridDim.x + blockIdx.x;
    int q = nwg >> 3, r = nwg & 7;
    int xcd = hh & 7, pos = hh >> 3;
    int wk = (xcd < r ? xcd * (q + 1) : r * (q + 1) + (xcd - r) * q) + pos;
    int bx = wk % gridDim.x, by = wk / gridDim.x;

    int n0 = bx * 128;
    int bn16 = n0 >> 4;
    int nmt = (M + 127) >> 7;  // number of valid 128-row M-tiles

    // ---- stage entire B panel (once) ----
#pragma unroll
    for (int kt2 = 0; kt2 < NKT; ++kt2) {
#pragma unroll
        for (int rep = 0; rep < 2; ++rep) {
            int chunk = tid + rep * 256;
            int tile = chunk >> 6, e8 = chunk & 63;
            size_t boff = ((size_t)((bn16 + tile) * NKT + kt2) * 64 + e8) * 8;
            __builtin_amdgcn_global_load_lds((glb_uint*)&Bh[boff],
                                             (lds_uint*)&sB[kt2 * 4096 + chunk * 8], 16, 0, 0);
        }
    }
    auto STAGE_A = [&](int mti, int kt2, int buf) {
#pragma unroll
        for (int rep = 0; rep < 2; ++rep) {
            int chunk = tid + rep * 256;
            int tile = chunk >> 6, e8 = chunk & 63;
            size_t aoff = ((size_t)((mti * 8 + tile) * NKT + kt2) * 64 + e8) * 8;
            __builtin_amdgcn_global_load_lds((glb_uint*)&Ah[aoff],
                                             (lds_uint*)&sA[buf][chunk * 8], 16, 0, 0);
        }
    };
    STAGE_A(min(by * MT, nmt - 1), 0, 0);
    asm volatile("s_waitcnt vmcnt(0)" ::: "memory");
    __builtin_amdgcn_s_barrier();

    float asv[4], adv[4];
#pragma unroll
    for (int j = 0; j < 4; ++j) {
        int col = n0 + wcol * 64 + j * 16 + c16;
        bool ok = col < NREAL;
        asv[j] = ok ? as_[col] : 0.f;
        adv[j] = ok ? ad_[col] : 0.f;
    }
    float mx = -1e30f;                 // F==64 per-wave head max (across mts)
    float mxA = -1e30f, mxB = -1e30f;  // F==32 per-wave 2-head max
    bool colvalid = (n0 + wcol * 64) < NREAL;
    int b4 = lane & 3;

    f32x4 acc[4][4] = {};
    const int T = MT * NKT;
    int mt = 0, kt = 0;
    for (int t = 0; t < T; ++t) {
        int cur = t & 1;
        int nkt = kt + 1, nmt2 = mt;
        if (nkt == NKT) {
            nkt = 0;
            nmt2 = mt + 1;
        }
        if (t + 1 < T) STAGE_A(min(by * MT + nmt2, nmt - 1), nkt, cur ^ 1);  // issue-early
        bf16x8 fah[4], fbh[4];
#pragma unroll
        for (int i = 0; i < 4; ++i) {
            fah[i] = *(const bf16x8*)&sA[cur][(wrow * 4 + i) * 512 + lane * 8];
            fbh[i] = *(const bf16x8*)&sB[kt * 4096 + (wcol * 4 + i) * 512 + lane * 8];
        }
        asm volatile("s_waitcnt lgkmcnt(0)" ::: "memory");
        __builtin_amdgcn_sched_barrier(0);  // rule #18
#pragma unroll
        for (int i = 0; i < 4; ++i)
#pragma unroll
            for (int j = 0; j < 4; ++j)
                acc[i][j] = __builtin_amdgcn_mfma_f32_16x16x32_bf16(fah[i], fbh[j], acc[i][j],
                                                                    0, 0, 0);
        if (kt == NKT - 1) {  // M-tile complete: epilogue (uniform branch)
            int m0 = (by * MT + mt) * 128;
            if (m0 < M) {
                // ---- es/ed + gmax partial (fragment layout) ----
#pragma unroll
                for (int i = 0; i < 4; ++i) {
#pragma unroll
                    for (int r2 = 0; r2 < 4; ++r2) {
                        int m = m0 + wrow * 64 + i * 16 + quad * 4 + r2;
                        bool mok = m < M;
                        if (F == 64) {
                            float ps = acc[i][0][r2] * asv[0] + acc[i][1][r2] * asv[1] +
                                       acc[i][2][r2] * asv[2] + acc[i][3][r2] * asv[3];
                            float pd = acc[i][0][r2] * adv[0] + acc[i][1][r2] * adv[1] +
                                       acc[i][2][r2] * adv[2] + acc[i][3][r2] * adv[3];
#pragma unroll
                            for (int off = 8; off > 0; off >>= 1) {
                                ps += __shfl_down(ps, off, 16);
                                pd += __shfl_down(pd, off, 16);
                            }
                            if (mok && c16 == 0) {
                                int hd = (n0 + wcol * 64) / 64;
                                es[(size_t)m * HHEADS + hd] = ps;
                                ed[(size_t)m * HHEADS + hd] = pd;
                                mx = fmaxf(mx, ps);
                            }
                        } else {  // F == 32: two heads per wave-column
                            float psA = acc[i][0][r2] * asv[0] + acc[i][1][r2] * asv[1];
                            float pdA = acc[i][0][r2] * adv[0] + acc[i][1][r2] * adv[1];
                            float psB = acc[i][2][r2] * asv[2] + acc[i][3][r2] * asv[3];
                            float pdB = acc[i][2][r2] * adv[2] + acc[i][3][r2] * adv[3];
#pragma unroll
                            for (int off = 8; off > 0; off >>= 1) {
                                psA += __shfl_down(psA, off, 16);
                                pdA += __shfl_down(pdA, off, 16);
                                psB += __shfl_down(psB, off, 16);
                                pdB += __shfl_down(pdB, off, 16);
                            }
                            if (mok && c16 == 0 && colvalid) {
                                int colbase = n0 + wcol * 64;
                                int hd = colbase / 32;
                                es[(size_t)m * HHEADS + hd] = psA;
                                ed[(size_t)m * HHEADS + hd] = pdA;
                                es[(size_t)m * HHEADS + hd + 1] = psB;
                                ed[(size_t)m * HHEADS + hd + 1] = pdB;
                                mxA = fmaxf(mxA, psA);
                                mxB = fmaxf(mxB, psB);
                            }
                        }
                    }
                }
                // ---- C store (fp8): transpose 16x16 blocks, dword stores ----
#pragma unroll
                for (int i = 0; i < 4; ++i) {
                    int m = m0 + wrow * 64 + i * 16 + quad * 4 + b4;
                    bool mok = m < M;
#pragma unroll
                    for (int j = 0; j < 4; ++j) {
                        float v0 = acc[i][j][0], v1 = acc[i][j][1], v2 = acc[i][j][2],
                              v3 = acc[i][j][3];
                        xpose4(v0, v1, v2, v3, b4);
                        int colb = n0 + wcol * 64 + j * 16 + (c16 & 12);
                        if (mok && (F == 64 || colvalid)) {
                            int pk = __builtin_amdgcn_cvt_pk_fp8_f32(v0, v1, 0, false);
                            pk = __builtin_amdgcn_cvt_pk_fp8_f32(v2, v3, pk, true);
                            *(unsigned*)&C8[(size_t)m * NREAL + colb] = (unsigned)pk;
                        }
                    }
                }
            }
#pragma unroll
            for (int i = 0; i < 4; ++i)
#pragma unroll
                for (int j = 0; j < 4; ++j) acc[i][j] = (f32x4){0.f, 0.f, 0.f, 0.f};
        }
        asm volatile("s_waitcnt vmcnt(0)" ::: "memory");
        __builtin_amdgcn_s_barrier();
        kt = nkt;
        mt = nmt2;
    }

    if (F == 64) {  // per-head global es max, one atomic per wave per block
#pragma unroll
        for (int off = 32; off > 0; off >>= 1) mx = fmaxf(mx, __shfl_xor(mx, off));
        if (lane == 0) atomicMax(&gmax[(n0 + wcol * 64) / 64], fkey(mx));
    } else {
        mxA = fmaxf(mxA, __shfl_xor(mxA, 16));
        mxA = fmaxf(mxA, __shfl_xor(mxA, 32));
        mxB = fmaxf(mxB, __shfl_xor(mxB, 16));
        mxB = fmaxf(mxB, __shfl_xor(mxB, 32));
        if (lane == 0 && colvalid) {
            int hd = (n0 + wcol * 64) / 32;
            atomicMax(&gmax[6 + hd], fkey(mxA));
            atomicMax(&gmax[6 + hd + 1], fkey(mxB));
        }
    }
}

// ---------------- online-rescale softmax-aggregate (layer 1, fp8 h) -----------
// Thread per (node, 8ch); fp8 gather + HW unpack; packed f32x2 FMA accum.
template <int F>
__global__ __launch_bounds__(256) void aggregate_fused(
    const unsigned char* __restrict__ h8, const float* __restrict__ es,
    const float* __restrict__ ed, const int* __restrict__ offsets,
    const int* __restrict__ ssrc, unsigned short* __restrict__ oh, int n) {
    constexpr int HF = HHEADS * F;
    constexpr int C8 = HF / 8;
    int tid = blockIdx.x * blockDim.x + threadIdx.x;
    if (tid >= n * C8) return;
    int node = tid / C8, q = tid % C8;
    int c = q * 8, hd = c / F;
    int a = offsets[node], b = offsets[node + 1];
    float edv = ed[node * HHEADS + hd];
    float m = -1e30f, l = 0.f;
    f32x2 a0 = {0.f, 0.f}, a1 = {0.f, 0.f}, a2 = {0.f, 0.f}, a3 = {0.f, 0.f};
    for (int j = a; j < b; ++j) {
        int s = ssrc[j];
        float v = es[s * HHEADS + hd] + edv;
        v = v > 0.f ? v : 0.2f * v;  // leaky relu 0.2
        float mn = fmaxf(m, v);
        float r = __expf(m - mn);
        float wgt = __expf(v - mn);
        uint2 hv = *(const uint2*)&h8[(size_t)s * HF + c];
        f32x2 p0 = __builtin_amdgcn_cvt_pk_f32_fp8((int)hv.x, false);
        f32x2 p1 = __builtin_amdgcn_cvt_pk_f32_fp8((int)hv.x, true);
        f32x2 p2 = __builtin_amdgcn_cvt_pk_f32_fp8((int)hv.y, false);
        f32x2 p3 = __builtin_amdgcn_cvt_pk_f32_fp8((int)hv.y, true);
        l = l * r + wgt;
        f32x2 rv = {r, r}, wv = {wgt, wgt};
        a0 = a0 * rv + wv * p0;
        a1 = a1 * rv + wv * p1;
        a2 = a2 * rv + wv * p2;
        a3 = a3 * rv + wv * p3;
        m = mn;
    }
    float invd = 1.0f / (l + 1e-16f);
    float res[8] = {a0[0], a0[1], a1[0], a1[1], a2[0], a2[1], a3[0], a3[1]};
    unsigned short th[8];
#pragma unroll
    for (int k = 0; k < 8; ++k) {
        float v = res[k] * invd;
        v = v > 0.f ? v : (__expf(v) - 1.0f);  // elu
        th[k] = f2bf(v);
    }
    constexpr int NKT = HF / 32;
    int lq = (node & 15) | (((c >> 3) & 3) << 4);
    size_t base = ((size_t)((node >> 4) * NKT + (c >> 5)) * 64 + lq) * 8;
    *(uint4*)&oh[base] = *(uint4*)th;
}

// ---------------- wave-per-node single-pass aggregate (layer 2, fp8 h) --------
// Lanes 0..47 own 4 channels (uint = 4 fp8); packed f32x2 FMA; 4-edge unroll.
__global__ __launch_bounds__(256) void aggregate_wpn2(
    const unsigned char* __restrict__ h8, const float* __restrict__ es,
    const float* __restrict__ ed, const unsigned* __restrict__ gmax,
    const int* __restrict__ offsets, const int* __restrict__ ssrc,
    unsigned short* __restrict__ oh, int n) {
    constexpr int HF = 192;
    int wid = (int)((blockIdx.x * (unsigned)blockDim.x + threadIdx.x) >> 6);
    int lane = threadIdx.x & 63;
    if (wid >= n || lane >= 48) return;
    int node = wid;
    int hd = lane >> 3;  // F=32: 8 lanes (32ch) per head
    int c = lane * 4;
    int a = offsets[node], b = offsets[node + 1];
    float edv = ed[node * HHEADS + hd];
    float mv = funkey(gmax[6 + hd]) + edv;
    float m = mv > 0.f ? mv : 0.2f * mv;
    float l = 0.f;
    f32x2 a0 = {0.f, 0.f}, a1 = {0.f, 0.f};
    const unsigned char* hbase = h8 + c;
    int j = a;
    for (; j + 3 < b; j += 4) {
        int s0 = ssrc[j], s1 = ssrc[j + 1], s2 = ssrc[j + 2], s3 = ssrc[j + 3];
        float ev0 = es[(size_t)s0 * HHEADS + hd];
        float ev1 = es[(size_t)s1 * HHEADS + hd];
        float ev2 = es[(size_t)s2 * HHEADS + hd];
        float ev3 = es[(size_t)s3 * HHEADS + hd];
        unsigned h0 = *(const unsigned*)(hbase + (size_t)s0 * HF);
        unsigned h1 = *(const unsigned*)(hbase + (size_t)s1 * HF);
        unsigned h2 = *(const unsigned*)(hbase + (size_t)s2 * HF);
        unsigned h3 = *(const unsigned*)(hbase + (size_t)s3 * HF);
        float v0 = ev0 + edv;
        v0 = v0 > 0.f ? v0 : 0.2f * v0;
        float v1 = ev1 + edv;
        v1 = v1 > 0.f ? v1 : 0.2f * v1;
        float v2 = ev2 + edv;
        v2 = v2 > 0.f ? v2 : 0.2f * v2;
        float v3 = ev3 + edv;
        v3 = v3 > 0.f ? v3 : 0.2f * v3;
        float w0 = __expf(v0 - m);
        float w1 = __expf(v1 - m);
        float w2 = __expf(v2 - m);
        float w3 = __expf(v3 - m);
        {
            f32x2 p0 = __builtin_amdgcn_cvt_pk_f32_fp8((int)h0, false);
            f32x2 p1 = __builtin_amdgcn_cvt_pk_f32_fp8((int)h0, true);
            f32x2 wv = {w0, w0};
            l += w0;
            a0 = a0 + wv * p0;
            a1 = a1 + wv * p1;
        }
        {
            f32x2 p0 = __builtin_amdgcn_cvt_pk_f32_fp8((int)h1, false);
            f32x2 p1 = __builtin_amdgcn_cvt_pk_f32_fp8((int)h1, true);
            f32x2 wv = {w1, w1};
            l += w1;
            a0 = a0 + wv * p0;
            a1 = a1 + wv * p1;
        }
        {
            f32x2 p0 = __builtin_amdgcn_cvt_pk_f32_fp8((int)h2, false);
            f32x2 p1 = __builtin_amdgcn_cvt_pk_f32_fp8((int)h2, true);
            f32x2 wv = {w2, w2};
            l += w2;
            a0 = a0 + wv * p0;
            a1 = a1 + wv * p1;
        }
        {
            f32x2 p0 = __builtin_amdgcn_cvt_pk_f32_fp8((int)h3, false);
            f32x2 p1 = __builtin_amdgcn_cvt_pk_f32_fp8((int)h3, true);
            f32x2 wv = {w3, w3};
            l += w3;
            a0 = a0 + wv * p0;
            a1 = a1 + wv * p1;
        }
    }
    for (; j < b; ++j) {
        int s0 = ssrc[j];
        float ev0 = es[(size_t)s0 * HHEADS + hd];
        unsigned h0 = *(const unsigned*)(hbase + (size_t)s0 * HF);
        float v0 = ev0 + edv;
        v0 = v0 > 0.f ? v0 : 0.2f * v0;
        float w0 = __expf(v0 - m);
        f32x2 p0 = __builtin_amdgcn_cvt_pk_f32_fp8((int)h0, false);
        f32x2 p1 = __builtin_amdgcn_cvt_pk_f32_fp8((int)h0, true);
        f32x2 wv = {w0, w0};
        l += w0;
        a0 = a0 + wv * p0;
        a1 = a1 + wv * p1;
    }
    float invd = 1.0f / (l + 1e-16f);
    float res[4] = {a0[0], a0[1], a1[0], a1[1]};
    unsigned short th[4];
#pragma unroll
    for (int k = 0; k < 4; ++k) {
        float v = res[k] * invd;
        v = v > 0.f ? v : (__expf(v) - 1.0f);  // elu
        th[k] = f2bf(v);
    }
    int lq = (node & 15) | (((c >> 3) & 3) << 4);
    size_t base = ((size_t)((node >> 4) * (HF / 32) + (c >> 5)) * 64 + lq) * 8 + (c & 7);
    *(uint2*)&oh[base] = *(uint2*)th;
}

// ---------------- wave-per-node aggregate + fused sum-pool (layer 3) ----------
// Lanes 0..47 own 8 fp8 ch (uint2); coalesced 384B row/edge; 4-edge unroll;
// packed f32x2 FMA. No bufO write: per-wave res -> LDS gp[4][384] ->
// 64-replica global accumulator gmid (blockIdx&63).
__global__ __launch_bounds__(256) void aggregate_wpn3(
    const unsigned char* __restrict__ h8, const float* __restrict__ es,
    const float* __restrict__ ed, const unsigned* __restrict__ gmax,
    const int* __restrict__ offsets, const int* __restrict__ ssrc,
    float* __restrict__ gmid, int n) {
    constexpr int HF = 384;
    __shared__ float gp[4][384];
    int wave = threadIdx.x >> 6, lane = threadIdx.x & 63;
    int wid = blockIdx.x * 4 + wave;
    int node = wid;
    int hd = lane >> 3;  // 8 lanes (64ch) per head
    int c = lane * 8;    // R32 fix: no mask (lane<48 guard covers all uses)
    bool active = (wid < n) && (lane < 48);
    float res[8] = {};
    if (active) {
        int a = offsets[node], b = offsets[node + 1];
        float edv = ed[node * HHEADS + hd];
        float mv = funkey(gmax[hd]) + edv;
        float m = mv > 0.f ? mv : 0.2f * mv;
        float l = 0.f;
        f32x2 a0 = {0.f, 0.f}, a1 = {0.f, 0.f}, a2 = {0.f, 0.f}, a3 = {0.f, 0.f};
        const unsigned char* hbase = h8 + c;
        int j = a;
        for (; j + 3 < b; j += 4) {
            int s0 = ssrc[j], s1 = ssrc[j + 1], s2 = ssrc[j + 2], s3 = ssrc[j + 3];
            float ev0 = es[(size_t)s0 * HHEADS + hd];
            float ev1 = es[(size_t)s1 * HHEADS + hd];
            float ev2 = es[(size_t)s2 * HHEADS + hd];
            float ev3 = es[(size_t)s3 * HHEADS + hd];
            uint2 h0 = *(const uint2*)(hbase + (size_t)s0 * HF);
            uint2 h1 = *(const uint2*)(hbase + (size_t)s1 * HF);
            uint2 h2 = *(const uint2*)(hbase + (size_t)s2 * HF);
            uint2 h3 = *(const uint2*)(hbase + (size_t)s3 * HF);
            float v0 = ev0 + edv;
            v0 = v0 > 0.f ? v0 : 0.2f * v0;
            float v1 = ev1 + edv;
            v1 = v1 > 0.f ? v1 : 0.2f * v1;
            float v2 = ev2 + edv;
            v2 = v2 > 0.f ? v2 : 0.2f * v2;
            float v3 = ev3 + edv;
            v3 = v3 > 0.f ? v3 : 0.2f * v3;
            float w0 = __expf(v0 - m);
            float w1 = __expf(v1 - m);
            float w2 = __expf(v2 - m);
            float w3 = __expf(v3 - m);
            {
                f32x2 p0 = __builtin_amdgcn_cvt_pk_f32_fp8((int)h0.x, false);
                f32x2 p1 = __builtin_amdgcn_cvt_pk_f32_fp8((int)h0.x, true);
                f32x2 p2 = __builtin_amdgcn_cvt_pk_f32_fp8((int)h0.y, false);
                f32x2 p3 = __builtin_amdgcn_cvt_pk_f32_fp8((int)h0.y, true);
                f32x2 wv = {w0, w0};
                l += w0;
                a0 = a0 + wv * p0;
                a1 = a1 + wv * p1;
                a2 = a2 + wv * p2;
                a3 = a3 + wv * p3;
            }
            {
                f32x2 p0 = __builtin_amdgcn_cvt_pk_f32_fp8((int)h1.x, false);
                f32x2 p1 = __builtin_amdgcn_cvt_pk_f32_fp8((int)h1.x, true);
                f32x2 p2 = __builtin_amdgcn_cvt_pk_f32_fp8((int)h1.y, false);
                f32x2 p3 = __builtin_amdgcn_cvt_pk_f32_fp8((int)h1.y, true);
                f32x2 wv = {w1, w1};
                l += w1;
                a0 = a0 + wv * p0;
                a1 = a1 + wv * p1;
                a2 = a2 + wv * p2;
                a3 = a3 + wv * p3;
            }
            {
                f32x2 p0 = __builtin_amdgcn_cvt_pk_f32_fp8((int)h2.x, false);
                f32x2 p1 = __builtin_amdgcn_cvt_pk_f32_fp8((int)h2.x, true);
                f32x2 p2 = __builtin_amdgcn_cvt_pk_f32_fp8((int)h2.y, false);
                f32x2 p3 = __builtin_amdgcn_cvt_pk_f32_fp8((int)h2.y, true);
                f32x2 wv = {w2, w2};
                l += w2;
                a0 = a0 + wv * p0;
                a1 = a1 + wv * p1;
                a2 = a2 + wv * p2;
                a3 = a3 + wv * p3;
            }
            {
                f32x2 p0 = __builtin_amdgcn_cvt_pk_f32_fp8((int)h3.x, false);
                f32x2 p1 = __builtin_amdgcn_cvt_pk_f32_fp8((int)h3.x, true);
                f32x2 p2 = __builtin_amdgcn_cvt_pk_f32_fp8((int)h3.y, false);
                f32x2 p3 = __builtin_amdgcn_cvt_pk_f32_fp8((int)h3.y, true);
                f32x2 wv = {w3, w3};
                l += w3;
                a0 = a0 + wv * p0;
                a1 = a1 + wv * p1;
                a2 = a2 + wv * p2;
                a3 = a3 + wv * p3;
            }
        }
        for (; j < b; ++j) {
            int s0 = ssrc[j];
            float ev0 = es[(size_t)s0 * HHEADS + hd];
            uint2 h0 = *(const uint2*)(hbase + (size_t)s0 * HF);
            float v0 = ev0 + edv;
            v0 = v0 > 0.f ? v0 : 0.2f * v0;
            float w0 = __expf(v0 - m);
            f32x2 p0 = __builtin_amdgcn_cvt_pk_f32_fp8((int)h0.x, false);
            f32x2 p1 = __builtin_amdgcn_cvt_pk_f32_fp8((int)h0.x, true);
            f32x2 p2 = __builtin_amdgcn_cvt_pk_f32_fp8((int)h0.y, false);
            f32x2 p3 = __builtin_amdgcn_cvt_pk_f32_fp8((int)h0.y, true);
            f32x2 wv = {w0, w0};
            l += w0;
            a0 = a0 + wv * p0;
            a1 = a1 + wv * p1;
            a2 = a2 + wv * p2;
            a3 = a3 + wv * p3;
        }
        float invd = 1.0f / (l + 1e-16f);
        float t[8] = {a0[0], a0[1], a1[0], a1[1], a2[0], a2[1], a3[0], a3[1]};
#pragma unroll
        for (int k = 0; k < 8; ++k) {
            float v = t[k] * invd;
            res[k] = v > 0.f ? v : (__expf(v) - 1.0f);  // elu
        }
    }
    if (lane < 48) {
#pragma unroll
        for (int k = 0; k < 8; ++k) gp[wave][c + k] = res[k];
    }
    __syncthreads();
    int rep = blockIdx.x & 63;
    for (int i = threadIdx.x; i < 384; i += 256) {
        float s = gp[0][i] + gp[1][i] + gp[2][i] + gp[3][i];
        atomicAdd(&gmid[rep * 384 + i], s);
    }
}

// ---------------- final: reduce 64 replicas -> normalize -> dense ----------------
__global__ void final_kernel(const float* __restrict__ gmid, const float* __restrict__ Wd,
                             const float* __restrict__ bd, float* __restrict__ outp) {
    __shared__ float red[384];
    int t = threadIdx.x;  // blockDim = 384
    float v = 0.f;
    for (int r = 0; r < 64; ++r) v += gmid[r * 384 + t];
    red[t] = v * v;
    __syncthreads();
    for (int s = 192; s >= 3; s >>= 1) {
        if (t < s) red[t] += red[t + s];
        __syncthreads();
    }
    __shared__ float scale_s;
    if (t == 0) {
        float norm = sqrtf(red[0] + red[1] + red[2]);
        scale_s = 1.0f / fmaxf(norm, 1e-12f);
    }
    __syncthreads();
    float scale = scale_s;
    red[t] = v * scale * Wd[t];
    __syncthreads();
    for (int s = 192; s >= 3; s >>= 1) {
        if (t < s) red[t] += red[t + s];
        __syncthreads();
    }
    if (t == 0) outp[0] = red[0] + red[1] + red[2] + bd[0];
}

// ---------------- host side ----------------
extern "C" void kernel_launch(void* const* d_in, const int* in_sizes, int n_in, void* d_out,
                              int out_size, void* d_ws, size_t ws_size, hipStream_t stream) {
    const float* x = (const float*)d_in[0];
    const int* ei = (const int*)d_in[1];
    const float* W1 = (const float*)d_in[2];
    const float* a1s = (const float*)d_in[3];
    const float* a1d = (const float*)d_in[4];
    const float* W2 = (const float*)d_in[5];
    const float* a2s = (const float*)d_in[6];
    const float* a2d = (const float*)d_in[7];
    const float* W3 = (const float*)d_in[8];
    const float* a3s = (const float*)d_in[9];
    const float* a3d = (const float*)d_in[10];
    const float* Wd = (const float*)d_in[11];
    const float* bd = (const float*)d_in[12];
    float* outp = (float*)d_out;

    const int N = in_sizes[0] / 11;
    const int E = in_sizes[1] / 2;
    const int* src = ei;
    const int* dst = ei + E;

    const int NT16 = ((N + 127) / 128) * 8;  // padded 16-row tiles
    const int NMT = (N + 127) / 128;         // 128-row M-tiles

    char* w = (char*)d_ws;
    size_t off = 0;
    auto A = [&](size_t bytes) {
        size_t o = off;
        off += (bytes + 255) & ~(size_t)255;
        return o;
    };
    unsigned char* bufH = (unsigned char*)(w + A((size_t)N * 384 * 2));   // h (fp8 all layers)
    float* gmid = (float*)(w + A((size_t)N * 384 * 2));  // 64x384 pool replicas (ex-bufO)
    unsigned short* apH = (unsigned short*)(w + A((size_t)NT16 * 6 * 512 * 2));  // A-pack
    unsigned short* b2H = (unsigned short*)(w + A((size_t)16 * 3 * 512 * 2));    // W2 pack
    unsigned short* b3H = (unsigned short*)(w + A((size_t)24 * 6 * 512 * 2));    // W3 pack
    float* es = (float*)(w + A((size_t)N * HHEADS * 4));
    float* ed = (float*)(w + A((size_t)N * HHEADS * 4));
    unsigned* gmax = (unsigned*)(w + A(256));
    float* wp = (float*)(w + A((size_t)11 * 96 * 4));  // layer-1 f32 repack
    int* count = (int*)(w + A((size_t)(N + 1) * 4));
    int* cursor = (int*)(w + A((size_t)(N + 1) * 4));
    int* offsets = (int*)(w + A((size_t)(N + 1) * 4));
    int* bsum = (int*)(w + A(64 * 4));
    int* ssrc = (int*)(w + A((size_t)E * 4));

    // one-shot zero of all small scratch (count, cursor, gmid, gmax, pads)
    const long t16v = N / 16;
    const long padT = NT16 - t16v;
    zero_misc<<<(N + 255) / 256, 256, 0, stream>>>(count, cursor, gmid, gmax, apH,
                                                   t16v * 3 * 512, padT * 3 * 512,
                                                   t16v * 6 * 512, padT * 6 * 512, N);

    // CSR build (by dst)
    hist_kernel<<<(E + 255) / 256, 256, 0, stream>>>(dst, count, E);
    int nb = (N + 1023) / 1024;
    scan_block<<<nb, 1024, 0, stream>>>(count, offsets, bsum, N);
    scan_tops<<<1, 64, 0, stream>>>(bsum, nb);
    scan_add<<<nb, 1024, 0, stream>>>(offsets, bsum, N, E);
    scatter_kernel<<<(E + 255) / 256, 256, 0, stream>>>(src, dst, offsets, cursor, ssrc, E);

    // weight packs
    repack_w<<<(11 * 96 + 255) / 256, 256, 0, stream>>>(W1, wp, 11, 16);
    repack_w_mfma<<<(96 * 256 + 255) / 256, 256, 0, stream>>>(W2, b2H, 96, 32, 256);
    repack_w_mfma<<<(192 * 384 + 255) / 256, 256, 0, stream>>>(W3, b3H, 192, 64, 384);

    // ---- layer 1 (FIN=11, F=16): gemm (fp8 C) + fused attn terms ----
    {
        dim3 grid((96 + 63) / 64, (N + 63) / 64);
        gemm_small_attn<64, 64, 32><<<grid, 256, 0, stream>>>(x, wp, bufH, a1s, a1d, es, ed, N,
                                                              11, 96);
    }
    {
        long total = (long)N * (96 / 8);
        aggregate_fused<16><<<(total + 255) / 256, 256, 0, stream>>>(bufH, es, ed, offsets,
                                                                     ssrc, apH, N);
    }

    // ---- layer 2 (K=96, N=192 pad 256, F=32): fp8 C + fused gmax(6-11) ----
    {
        dim3 grid(2, (NMT + 3) / 4);
        gemm_attn_mfma<96, 192, 256, 32, 4><<<grid, 256, 0, stream>>>(apH, b2H, bufH, a2s,
                                                                      a2d, es, ed, gmax, N);
    }
    {
        int grid = (N + 3) / 4;  // 4 waves/block, wave-per-node
        aggregate_wpn2<<<grid, 256, 0, stream>>>(bufH, es, ed, gmax, offsets, ssrc, apH, N);
    }

    // ---- layer 3 (K=192, N=384, F=64): fp8 C + fused gmax(0-5) ----
    {
        dim3 grid(3, (NMT + 3) / 4);
        gemm_attn_mfma<192, 384, 384, 64, 4><<<grid, 256, 0, stream>>>(apH, b3H, bufH, a3s,
                                                                       a3d, es, ed, gmax, N);
    }
    {
        int grid = (N + 3) / 4;  // fused aggregate + sum-pool (no bufO)
        aggregate_wpn3<<<grid, 256, 0, stream>>>(bufH, es, ed, gmax, offsets, ssrc, gmid, N);
    }

    // reduce replicas -> normalize -> dense
    final_kernel<<<1, 384, 0, stream>>>(gmid, Wd, bd, outp);
}

// Round 16
// 431.303 us; speedup vs baseline: 1.3089x; 1.0027x over previous
//
#include <hip/hip_runtime.h>
#include <hip/hip_bf16.h>

// GAT 3-layer: N=50000 nodes, E=800000 edges, H=6 heads.
// R1-R17: MFMA GEMMs + CSR fused softmax/aggregate ladder (545us).
// R20/R21: wave-per-node aggregates; h -> fp8 e4m3.
// R22-R26: GEMM per-block-overhead fix (MT=4 M-tiles, persistent-B): 527us.
// R27: fp8 h everywhere (513us). R29: +pk-FMA (516us, noise). R30: 4-edge
//      unroll in aggregates (489us). R31/R32: sum-pool fused into wpn3 via
//      LDS partials + 64-replica accumulator (432us; pool_kernel deleted).
// R33: L2 GEMM now top real kernel (~72us; 196 blocks < 256 CUs -> duration =
//      single-block lifetime; per-phase vmcnt(0) drains the just-issued
//      prefetch = full latency exposed each phase). Fix = T4 counted vmcnt:
//      3-buffer A, stage t+2 during phase t, wait vmcnt(2) (A(t+1) landed,
//      A(t+2) stays in flight). Numerics identical.

#define HHEADS 6

typedef __attribute__((ext_vector_type(8))) short bf16x8;   // 8 bf16 = 4 VGPR
typedef __attribute__((ext_vector_type(4))) float f32x4;    // mfma C/D
typedef __attribute__((ext_vector_type(2))) float f32x2;

typedef __attribute__((address_space(3))) unsigned int lds_uint;
typedef const __attribute__((address_space(1))) unsigned int glb_uint;

__device__ __forceinline__ float bfl(unsigned u) { return __uint_as_float(u << 16); }
__device__ __forceinline__ float bfh(unsigned u) { return __uint_as_float(u & 0xffff0000u); }
__device__ __forceinline__ unsigned short f2bf(float v) {  // RNE f32->bf16
    unsigned u = __float_as_uint(v);
    return (unsigned short)((u + 0x7fffu + ((u >> 16) & 1u)) >> 16);
}
__device__ __forceinline__ float bf2f(unsigned short h) {
    return __uint_as_float((unsigned)h << 16);
}
// monotone float<->uint for atomicMax on floats (memset-0 = -inf identity)
__device__ __forceinline__ unsigned fkey(float f) {
    unsigned u = __float_as_uint(f);
    return (u >> 31) ? ~u : (u | 0x80000000u);
}
__device__ __forceinline__ float funkey(unsigned k) {
    return (k >> 31) ? __uint_as_float(k & 0x7fffffffu) : __uint_as_float(~k);
}

// 4x4 transpose across a 4-lane group (lanes share lane>>2). In: v0..v3 =
// rows 0..3 at this lane's column. Out: v0..v3 = cols 0..3 at row (lane&3).
__device__ __forceinline__ void xpose4(float& v0, float& v1, float& v2, float& v3, int b) {
    bool hi = (b & 2) != 0;
    float s0 = hi ? v0 : v2;
    float s1 = hi ? v1 : v3;
    s0 = __shfl_xor(s0, 2, 64);
    s1 = __shfl_xor(s1, 2, 64);
    v0 = hi ? s0 : v0;
    v1 = hi ? s1 : v1;
    v2 = hi ? v2 : s0;
    v3 = hi ? v3 : s1;
    bool od = (b & 1) != 0;
    float t0 = od ? v0 : v1;
    t0 = __shfl_xor(t0, 1, 64);
    v0 = od ? t0 : v0;
    v1 = od ? v1 : t0;
    float t1 = od ? v2 : v3;
    t1 = __shfl_xor(t1, 1, 64);
    v2 = od ? t1 : v2;
    v3 = od ? v3 : t1;
}

// ---------------- one-shot zero of all small scratch ----------------
__global__ void zero_misc(int* __restrict__ count, int* __restrict__ cursor,
                          float* __restrict__ gmid, unsigned* __restrict__ gmax,
                          unsigned short* __restrict__ apH,
                          long pad3_off, long pad3_cnt, long pad6_off, long pad6_cnt, int n) {
    long i = (long)blockIdx.x * blockDim.x + threadIdx.x;
    long stride = (long)gridDim.x * blockDim.x;
    for (long j = i; j < n; j += stride) {
        count[j] = 0;
        cursor[j] = 0;
    }
    for (long j = i; j < 64 * 384; j += stride) gmid[j] = 0.f;
    if (i < 12) gmax[i] = 0u;  // slots 0-5: L3, 6-11: L2
    for (long j = i; j < pad3_cnt; j += stride) apH[pad3_off + j] = 0;
    for (long j = i; j < pad6_cnt; j += stride) apH[pad6_off + j] = 0;
}

// ---------------- CSR build ----------------
__global__ void hist_kernel(const int* __restrict__ dst, int* __restrict__ count, int E) {
    int e = blockIdx.x * blockDim.x + threadIdx.x;
    if (e >= E) return;
    atomicAdd(&count[dst[e]], 1);
}

__global__ void scan_block(const int* __restrict__ count, int* __restrict__ offsets,
                           int* __restrict__ bsum, int n) {
    __shared__ int s[1024];
    int i = blockIdx.x * 1024 + threadIdx.x;
    int v = (i < n) ? count[i] : 0;
    s[threadIdx.x] = v;
    __syncthreads();
    for (int off = 1; off < 1024; off <<= 1) {
        int t = (threadIdx.x >= (unsigned)off) ? s[threadIdx.x - off] : 0;
        __syncthreads();
        s[threadIdx.x] += t;
        __syncthreads();
    }
    if (i < n) offsets[i] = s[threadIdx.x] - v;
    if (threadIdx.x == 1023) bsum[blockIdx.x] = s[1023];
}

__global__ void scan_tops(int* __restrict__ bsum, int nb) {
    __shared__ int s[64];
    int t = threadIdx.x;
    int v = (t < nb) ? bsum[t] : 0;
    s[t] = v;
    __syncthreads();
    for (int off = 1; off < 64; off <<= 1) {
        int tmp = (t >= off) ? s[t - off] : 0;
        __syncthreads();
        s[t] += tmp;
        __syncthreads();
    }
    if (t < nb) bsum[t] = s[t] - v;
}

__global__ void scan_add(int* __restrict__ offsets, const int* __restrict__ bsum, int n,
                         int total) {
    int i = blockIdx.x * 1024 + threadIdx.x;
    if (i < n) offsets[i] += bsum[blockIdx.x];
    if (i == 0) offsets[n] = total;
}

__global__ void scatter_kernel(const int* __restrict__ src, const int* __restrict__ dst,
                               const int* __restrict__ offsets, int* __restrict__ cursor,
                               int* __restrict__ ssrc, int E) {
    int e = blockIdx.x * blockDim.x + threadIdx.x;
    if (e >= E) return;
    int d = dst[e];
    int pos = offsets[d] + atomicAdd(&cursor[d], 1);
    ssrc[pos] = src[e];
}

// ---------------- weight repacks ----------------
__global__ void repack_w(const float* __restrict__ W, float* __restrict__ Wp, int FIN, int F) {
    int HF = HHEADS * F;
    int i = blockIdx.x * blockDim.x + threadIdx.x;
    if (i >= FIN * HF) return;
    int k = i / HF, c = i % HF;
    int hd = c / F, f = c % F;
    Wp[i] = W[(hd * FIN + k) * F + f];
}

// bf16 pack in MFMA B-fragment layout (B^T: lane n=..&15, k contiguous)
__global__ void repack_w_mfma(const float* __restrict__ W, unsigned short* __restrict__ bh,
                              int FIN, int F, int NPAD) {
    int i = blockIdx.x * blockDim.x + threadIdx.x;
    if (i >= FIN * NPAD) return;
    int k = i / NPAD, n = i % NPAD;
    int NKT = FIN / 32;
    int HF = HHEADS * F;
    float w = 0.f;
    if (n < HF) {
        int hd = n / F, f = n % F;
        w = W[(hd * FIN + k) * F + f];
    }
    size_t e = ((size_t)((n >> 4) * NKT + (k >> 5)) * 64 + ((n & 15) | (((k >> 3) & 3) << 4))) * 8 +
               (k & 7);
    bh[e] = f2bf(w);
}

// ---------------- small GEMM + fused attn (layer 1, K=11, F=16) ----------------
// C written fp8 e4m3 (feeds only aggregate_fused).
template <int BM, int BN, int BK>
__global__ __launch_bounds__(256) void gemm_small_attn(const float* __restrict__ A,
                                                       const float* __restrict__ B,
                                                       unsigned char* __restrict__ C8,
                                                       const float* __restrict__ as_,
                                                       const float* __restrict__ ad_,
                                                       float* __restrict__ es,
                                                       float* __restrict__ ed, int M, int K,
                                                       int N) {
    __shared__ float As[BK][BM + 4];
    __shared__ float Bs[BK][BN];
    int tid = threadIdx.x;
    int tx = tid % 16, ty = tid / 16;
    int m0 = blockIdx.y * BM, n0 = blockIdx.x * BN;
    float acc[4][4] = {};
    for (int kk0 = 0; kk0 < K; kk0 += BK) {
#pragma unroll
        for (int i = 0; i < (BM * BK) / 256; ++i) {
            int idx = tid + i * 256;
            int m = idx / BK, k = idx % BK;
            float v = 0.f;
            if (m0 + m < M && kk0 + k < K) v = A[(size_t)(m0 + m) * K + kk0 + k];
            As[k][m] = v;
        }
#pragma unroll
        for (int i = 0; i < (BK * BN) / 1024; ++i) {
            int idx = tid + i * 256;
            int k = idx / (BN / 4), n4 = idx % (BN / 4);
            float4 v = make_float4(0.f, 0.f, 0.f, 0.f);
            if (kk0 + k < K && n0 + n4 * 4 < N)
                v = *(const float4*)&B[(size_t)(kk0 + k) * N + n0 + n4 * 4];
            *(float4*)&Bs[k][n4 * 4] = v;
        }
        __syncthreads();
#pragma unroll
        for (int k = 0; k < BK; ++k) {
            float4 av = *(const float4*)&As[k][ty * 4];
            float4 bv = *(const float4*)&Bs[k][tx * 4];
            float a[4] = {av.x, av.y, av.z, av.w};
            float b[4] = {bv.x, bv.y, bv.z, bv.w};
#pragma unroll
            for (int i = 0; i < 4; ++i)
#pragma unroll
                for (int j = 0; j < 4; ++j) acc[i][j] += a[i] * b[j];
        }
        __syncthreads();
    }
    bool colok = (n0 + tx * 4) < N;
    float asv[4], adv[4];
#pragma unroll
    for (int j = 0; j < 4; ++j) {
        int col = n0 + tx * 4 + j;
        asv[j] = (col < N) ? as_[col] : 0.f;
        adv[j] = (col < N) ? ad_[col] : 0.f;
    }
#pragma unroll
    for (int i = 0; i < 4; ++i) {
        int m = m0 + ty * 4 + i;
        bool mok = m < M;
        if (mok && colok) {
            int pk = __builtin_amdgcn_cvt_pk_fp8_f32(acc[i][0], acc[i][1], 0, false);
            pk = __builtin_amdgcn_cvt_pk_fp8_f32(acc[i][2], acc[i][3], pk, true);
            *(unsigned*)&C8[(size_t)m * N + n0 + tx * 4] = (unsigned)pk;
        }
        float ps = 0.f, pd = 0.f;
#pragma unroll
        for (int j = 0; j < 4; ++j) {
            ps += acc[i][j] * asv[j];
            pd += acc[i][j] * adv[j];
        }
        ps += __shfl_down(ps, 2, 4);
        ps += __shfl_down(ps, 1, 4);
        pd += __shfl_down(pd, 2, 4);
        pd += __shfl_down(pd, 1, 4);
        if (mok && colok && (tx & 3) == 0) {
            int hd = (n0 + tx * 4) >> 4;  // F=16
            es[(size_t)m * HHEADS + hd] = ps;
            ed[(size_t)m * HHEADS + hd] = pd;
        }
    }
}

// ---------------- MFMA bf16 GEMM + fused attn (layers 2/3) ----------------
// MT M-tiles per block; persistent B in LDS; R33: 3-buffer A with counted
// vmcnt(2) (stage t+2 during phase t; never drain to 0 in the main loop).
// fp8 row-major C. F==64: gmax slots 0-5. F==32: gmax slots 6-11.
template <int K, int NREAL, int NPAD, int F, int MT>
__global__ __launch_bounds__(256) void gemm_attn_mfma(
    const unsigned short* __restrict__ Ah, const unsigned short* __restrict__ Bh,
    unsigned char* __restrict__ C8, const float* __restrict__ as_,
    const float* __restrict__ ad_, float* __restrict__ es, float* __restrict__ ed,
    unsigned* __restrict__ gmax, int M) {
    constexpr int NKT = K / 32;
    __shared__ unsigned short sB[NKT * 4096];  // persistent B panel
    __shared__ unsigned short sA[3][4096];     // A triple buffer (R33)
    int tid = threadIdx.x;
    int lane = tid & 63, wave = tid >> 6;
    int wrow = wave >> 1, wcol = wave & 1;
    int quad = lane >> 4, c16 = lane & 15;

    // XCD-bijective swizzle (m204): co-locate blocks sharing B panels.
    int nwg = gridDim.x * gridDim.y;
    int hh = blockIdx.y * gridDim.x + blockIdx.x;
    int q = nwg >> 3, r = nwg & 7;
    int xcd = hh & 7, pos = hh >> 3;
    int wk = (xcd < r ? xcd * (q + 1) : r * (q + 1) + (xcd - r) * q) + pos;
    int bx = wk % gridDim.x, by = wk / gridDim.x;

    int n0 = bx * 128;
    int bn16 = n0 >> 4;
    int nmt = (M + 127) >> 7;  // number of valid 128-row M-tiles

    // ---- stage entire B panel (once) ----
#pragma unroll
    for (int kt2 = 0; kt2 < NKT; ++kt2) {
#pragma unroll
        for (int rep = 0; rep < 2; ++rep) {
            int chunk = tid + rep * 256;
            int tile = chunk >> 6, e8 = chunk & 63;
            size_t boff = ((size_t)((bn16 + tile) * NKT + kt2) * 64 + e8) * 8;
            __builtin_amdgcn_global_load_lds((glb_uint*)&Bh[boff],
                                             (lds_uint*)&sB[kt2 * 4096 + chunk * 8], 16, 0, 0);
        }
    }
    auto STAGE_A = [&](int mti, int kt2, int buf) {
#pragma unroll
        for (int rep = 0; rep < 2; ++rep) {
            int chunk = tid + rep * 256;
            int tile = chunk >> 6, e8 = chunk & 63;
            size_t aoff = ((size_t)((mti * 8 + tile) * NKT + kt2) * 64 + e8) * 8;
            __builtin_amdgcn_global_load_lds((glb_uint*)&Ah[aoff],
                                             (lds_uint*)&sA[buf][chunk * 8], 16, 0, 0);
        }
    };
    auto STAGE_PH = [&](int u) {  // stage phase u's A-tile into buf u%3
        int um = u / NKT, uk = u - um * NKT;
        STAGE_A(min(by * MT + um, nmt - 1), uk, u % 3);
    };
    const int T = MT * NKT;  // T >= 12
    STAGE_PH(0);
    STAGE_PH(1);
    asm volatile("s_waitcnt vmcnt(2)" ::: "memory");  // B + A(0) landed
    __builtin_amdgcn_s_barrier();

    float asv[4], adv[4];
#pragma unroll
    for (int j = 0; j < 4; ++j) {
        int col = n0 + wcol * 64 + j * 16 + c16;
        bool ok = col < NREAL;
        asv[j] = ok ? as_[col] : 0.f;
        adv[j] = ok ? ad_[col] : 0.f;
    }
    float mx = -1e30f;                 // F==64 per-wave head max (across mts)
    float mxA = -1e30f, mxB = -1e30f;  // F==32 per-wave 2-head max
    bool colvalid = (n0 + wcol * 64) < NREAL;
    int b4 = lane & 3;

    f32x4 acc[4][4] = {};
    int mt = 0, kt = 0;
    for (int t = 0; t < T; ++t) {
        int cur = t % 3;
        if (t + 2 < T) STAGE_PH(t + 2);  // 2-deep prefetch
        bf16x8 fah[4], fbh[4];
#pragma unroll
        for (int i = 0; i < 4; ++i) {
            fah[i] = *(const bf16x8*)&sA[cur][(wrow * 4 + i) * 512 + lane * 8];
            fbh[i] = *(const bf16x8*)&sB[kt * 4096 + (wcol * 4 + i) * 512 + lane * 8];
        }
        asm volatile("s_waitcnt lgkmcnt(0)" ::: "memory");
        __builtin_amdgcn_sched_barrier(0);  // rule #18
#pragma unroll
        for (int i = 0; i < 4; ++i)
#pragma unroll
            for (int j = 0; j < 4; ++j)
                acc[i][j] = __builtin_amdgcn_mfma_f32_16x16x32_bf16(fah[i], fbh[j], acc[i][j],
                                                                    0, 0, 0);
        if (kt == NKT - 1) {  // M-tile complete: epilogue (uniform branch)
            int m0 = (by * MT + mt) * 128;
            if (m0 < M) {
                // ---- es/ed + gmax partial (fragment layout) ----
#pragma unroll
                for (int i = 0; i < 4; ++i) {
#pragma unroll
                    for (int r2 = 0; r2 < 4; ++r2) {
                        int m = m0 + wrow * 64 + i * 16 + quad * 4 + r2;
                        bool mok = m < M;
                        if (F == 64) {
                            float ps = acc[i][0][r2] * asv[0] + acc[i][1][r2] * asv[1] +
                                       acc[i][2][r2] * asv[2] + acc[i][3][r2] * asv[3];
                            float pd = acc[i][0][r2] * adv[0] + acc[i][1][r2] * adv[1] +
                                       acc[i][2][r2] * adv[2] + acc[i][3][r2] * adv[3];
#pragma unroll
                            for (int off = 8; off > 0; off >>= 1) {
                                ps += __shfl_down(ps, off, 16);
                                pd += __shfl_down(pd, off, 16);
                            }
                            if (mok && c16 == 0) {
                                int hd = (n0 + wcol * 64) / 64;
                                es[(size_t)m * HHEADS + hd] = ps;
                                ed[(size_t)m * HHEADS + hd] = pd;
                                mx = fmaxf(mx, ps);
                            }
                        } else {  // F == 32: two heads per wave-column
                            float psA = acc[i][0][r2] * asv[0] + acc[i][1][r2] * asv[1];
                            float pdA = acc[i][0][r2] * adv[0] + acc[i][1][r2] * adv[1];
                            float psB = acc[i][2][r2] * asv[2] + acc[i][3][r2] * asv[3];
                            float pdB = acc[i][2][r2] * adv[2] + acc[i][3][r2] * adv[3];
#pragma unroll
                            for (int off = 8; off > 0; off >>= 1) {
                                psA += __shfl_down(psA, off, 16);
                                pdA += __shfl_down(pdA, off, 16);
                                psB += __shfl_down(psB, off, 16);
                                pdB += __shfl_down(pdB, off, 16);
                            }
                            if (mok && c16 == 0 && colvalid) {
                                int colbase = n0 + wcol * 64;
                                int hd = colbase / 32;
                                es[(size_t)m * HHEADS + hd] = psA;
                                ed[(size_t)m * HHEADS + hd] = pdA;
                                es[(size_t)m * HHEADS + hd + 1] = psB;
                                ed[(size_t)m * HHEADS + hd + 1] = pdB;
                                mxA = fmaxf(mxA, psA);
                                mxB = fmaxf(mxB, psB);
                            }
                        }
                    }
                }
                // ---- C store (fp8): transpose 16x16 blocks, dword stores ----
#pragma unroll
                for (int i = 0; i < 4; ++i) {
                    int m = m0 + wrow * 64 + i * 16 + quad * 4 + b4;
                    bool mok = m < M;
#pragma unroll
                    for (int j = 0; j < 4; ++j) {
                        float v0 = acc[i][j][0], v1 = acc[i][j][1], v2 = acc[i][j][2],
                              v3 = acc[i][j][3];
                        xpose4(v0, v1, v2, v3, b4);
                        int colb = n0 + wcol * 64 + j * 16 + (c16 & 12);
                        if (mok && (F == 64 || colvalid)) {
                            int pk = __builtin_amdgcn_cvt_pk_fp8_f32(v0, v1, 0, false);
                            pk = __builtin_amdgcn_cvt_pk_fp8_f32(v2, v3, pk, true);
                            *(unsigned*)&C8[(size_t)m * NREAL + colb] = (unsigned)pk;
                        }
                    }
                }
            }
#pragma unroll
            for (int i = 0; i < 4; ++i)
#pragma unroll
                for (int j = 0; j < 4; ++j) acc[i][j] = (f32x4){0.f, 0.f, 0.f, 0.f};
        }
        // counted wait: A(t+1) guaranteed landed; A(t+2)'s 2 loads in flight
        if (t + 2 < T)
            asm volatile("s_waitcnt vmcnt(2)" ::: "memory");
        else
            asm volatile("s_waitcnt vmcnt(0)" ::: "memory");
        __builtin_amdgcn_s_barrier();
        ++kt;
        if (kt == NKT) {
            kt = 0;
            ++mt;
        }
    }

    if (F == 64) {  // per-head global es max, one atomic per wave per block
#pragma unroll
        for (int off = 32; off > 0; off >>= 1) mx = fmaxf(mx, __shfl_xor(mx, off));
        if (lane == 0) atomicMax(&gmax[(n0 + wcol * 64) / 64], fkey(mx));
    } else {
        mxA = fmaxf(mxA, __shfl_xor(mxA, 16));
        mxA = fmaxf(mxA, __shfl_xor(mxA, 32));
        mxB = fmaxf(mxB, __shfl_xor(mxB, 16));
        mxB = fmaxf(mxB, __shfl_xor(mxB, 32));
        if (lane == 0 && colvalid) {
            int hd = (n0 + wcol * 64) / 32;
            atomicMax(&gmax[6 + hd], fkey(mxA));
            atomicMax(&gmax[6 + hd + 1], fkey(mxB));
        }
    }
}

// ---------------- online-rescale softmax-aggregate (layer 1, fp8 h) -----------
// Thread per (node, 8ch); fp8 gather + HW unpack; packed f32x2 FMA accum.
template <int F>
__global__ __launch_bounds__(256) void aggregate_fused(
    const unsigned char* __restrict__ h8, const float* __restrict__ es,
    const float* __restrict__ ed, const int* __restrict__ offsets,
    const int* __restrict__ ssrc, unsigned short* __restrict__ oh, int n) {
    constexpr int HF = HHEADS * F;
    constexpr int C8 = HF / 8;
    int tid = blockIdx.x * blockDim.x + threadIdx.x;
    if (tid >= n * C8) return;
    int node = tid / C8, q = tid % C8;
    int c = q * 8, hd = c / F;
    int a = offsets[node], b = offsets[node + 1];
    float edv = ed[node * HHEADS + hd];
    float m = -1e30f, l = 0.f;
    f32x2 a0 = {0.f, 0.f}, a1 = {0.f, 0.f}, a2 = {0.f, 0.f}, a3 = {0.f, 0.f};
    for (int j = a; j < b; ++j) {
        int s = ssrc[j];
        float v = es[s * HHEADS + hd] + edv;
        v = v > 0.f ? v : 0.2f * v;  // leaky relu 0.2
        float mn = fmaxf(m, v);
        float r = __expf(m - mn);
        float wgt = __expf(v - mn);
        uint2 hv = *(const uint2*)&h8[(size_t)s * HF + c];
        f32x2 p0 = __builtin_amdgcn_cvt_pk_f32_fp8((int)hv.x, false);
        f32x2 p1 = __builtin_amdgcn_cvt_pk_f32_fp8((int)hv.x, true);
        f32x2 p2 = __builtin_amdgcn_cvt_pk_f32_fp8((int)hv.y, false);
        f32x2 p3 = __builtin_amdgcn_cvt_pk_f32_fp8((int)hv.y, true);
        l = l * r + wgt;
        f32x2 rv = {r, r}, wv = {wgt, wgt};
        a0 = a0 * rv + wv * p0;
        a1 = a1 * rv + wv * p1;
        a2 = a2 * rv + wv * p2;
        a3 = a3 * rv + wv * p3;
        m = mn;
    }
    float invd = 1.0f / (l + 1e-16f);
    float res[8] = {a0[0], a0[1], a1[0], a1[1], a2[0], a2[1], a3[0], a3[1]};
    unsigned short th[8];
#pragma unroll
    for (int k = 0; k < 8; ++k) {
        float v = res[k] * invd;
        v = v > 0.f ? v : (__expf(v) - 1.0f);  // elu
        th[k] = f2bf(v);
    }
    constexpr int NKT = HF / 32;
    int lq = (node & 15) | (((c >> 3) & 3) << 4);
    size_t base = ((size_t)((node >> 4) * NKT + (c >> 5)) * 64 + lq) * 8;
    *(uint4*)&oh[base] = *(uint4*)th;
}

// ---------------- wave-per-node single-pass aggregate (layer 2, fp8 h) --------
// Lanes 0..47 own 4 channels (uint = 4 fp8); packed f32x2 FMA; 4-edge unroll.
__global__ __launch_bounds__(256) void aggregate_wpn2(
    const unsigned char* __restrict__ h8, const float* __restrict__ es,
    const float* __restrict__ ed, const unsigned* __restrict__ gmax,
    const int* __restrict__ offsets, const int* __restrict__ ssrc,
    unsigned short* __restrict__ oh, int n) {
    constexpr int HF = 192;
    int wid = (int)((blockIdx.x * (unsigned)blockDim.x + threadIdx.x) >> 6);
    int lane = threadIdx.x & 63;
    if (wid >= n || lane >= 48) return;
    int node = wid;
    int hd = lane >> 3;  // F=32: 8 lanes (32ch) per head
    int c = lane * 4;
    int a = offsets[node], b = offsets[node + 1];
    float edv = ed[node * HHEADS + hd];
    float mv = funkey(gmax[6 + hd]) + edv;
    float m = mv > 0.f ? mv : 0.2f * mv;
    float l = 0.f;
    f32x2 a0 = {0.f, 0.f}, a1 = {0.f, 0.f};
    const unsigned char* hbase = h8 + c;
    int j = a;
    for (; j + 3 < b; j += 4) {
        int s0 = ssrc[j], s1 = ssrc[j + 1], s2 = ssrc[j + 2], s3 = ssrc[j + 3];
        float ev0 = es[(size_t)s0 * HHEADS + hd];
        float ev1 = es[(size_t)s1 * HHEADS + hd];
        float ev2 = es[(size_t)s2 * HHEADS + hd];
        float ev3 = es[(size_t)s3 * HHEADS + hd];
        unsigned h0 = *(const unsigned*)(hbase + (size_t)s0 * HF);
        unsigned h1 = *(const unsigned*)(hbase + (size_t)s1 * HF);
        unsigned h2 = *(const unsigned*)(hbase + (size_t)s2 * HF);
        unsigned h3 = *(const unsigned*)(hbase + (size_t)s3 * HF);
        float v0 = ev0 + edv;
        v0 = v0 > 0.f ? v0 : 0.2f * v0;
        float v1 = ev1 + edv;
        v1 = v1 > 0.f ? v1 : 0.2f * v1;
        float v2 = ev2 + edv;
        v2 = v2 > 0.f ? v2 : 0.2f * v2;
        float v3 = ev3 + edv;
        v3 = v3 > 0.f ? v3 : 0.2f * v3;
        float w0 = __expf(v0 - m);
        float w1 = __expf(v1 - m);
        float w2 = __expf(v2 - m);
        float w3 = __expf(v3 - m);
        {
            f32x2 p0 = __builtin_amdgcn_cvt_pk_f32_fp8((int)h0, false);
            f32x2 p1 = __builtin_amdgcn_cvt_pk_f32_fp8((int)h0, true);
            f32x2 wv = {w0, w0};
            l += w0;
            a0 = a0 + wv * p0;
            a1 = a1 + wv * p1;
        }
        {
            f32x2 p0 = __builtin_amdgcn_cvt_pk_f32_fp8((int)h1, false);
            f32x2 p1 = __builtin_amdgcn_cvt_pk_f32_fp8((int)h1, true);
            f32x2 wv = {w1, w1};
            l += w1;
            a0 = a0 + wv * p0;
            a1 = a1 + wv * p1;
        }
        {
            f32x2 p0 = __builtin_amdgcn_cvt_pk_f32_fp8((int)h2, false);
            f32x2 p1 = __builtin_amdgcn_cvt_pk_f32_fp8((int)h2, true);
            f32x2 wv = {w2, w2};
            l += w2;
            a0 = a0 + wv * p0;
            a1 = a1 + wv * p1;
        }
        {
            f32x2 p0 = __builtin_amdgcn_cvt_pk_f32_fp8((int)h3, false);
            f32x2 p1 = __builtin_amdgcn_cvt_pk_f32_fp8((int)h3, true);
            f32x2 wv = {w3, w3};
            l += w3;
            a0 = a0 + wv * p0;
            a1 = a1 + wv * p1;
        }
    }
    for (; j < b; ++j) {
        int s0 = ssrc[j];
        float ev0 = es[(size_t)s0 * HHEADS + hd];
        unsigned h0 = *(const unsigned*)(hbase + (size_t)s0 * HF);
        float v0 = ev0 + edv;
        v0 = v0 > 0.f ? v0 : 0.2f * v0;
        float w0 = __expf(v0 - m);
        f32x2 p0 = __builtin_amdgcn_cvt_pk_f32_fp8((int)h0, false);
        f32x2 p1 = __builtin_amdgcn_cvt_pk_f32_fp8((int)h0, true);
        f32x2 wv = {w0, w0};
        l += w0;
        a0 = a0 + wv * p0;
        a1 = a1 + wv * p1;
    }
    float invd = 1.0f / (l + 1e-16f);
    float res[4] = {a0[0], a0[1], a1[0], a1[1]};
    unsigned short th[4];
#pragma unroll
    for (int k = 0; k < 4; ++k) {
        float v = res[k] * invd;
        v = v > 0.f ? v : (__expf(v) - 1.0f);  // elu
        th[k] = f2bf(v);
    }
    int lq = (node & 15) | (((c >> 3) & 3) << 4);
    size_t base = ((size_t)((node >> 4) * (HF / 32) + (c >> 5)) * 64 + lq) * 8 + (c & 7);
    *(uint2*)&oh[base] = *(uint2*)th;
}

// ---------------- wave-per-node aggregate + fused sum-pool (layer 3) ----------
// Lanes 0..47 own 8 fp8 ch (uint2); coalesced 384B row/edge; 4-edge unroll;
// packed f32x2 FMA. No bufO write: per-wave res -> LDS gp[4][384] ->
// 64-replica global accumulator gmid (blockIdx&63).
__global__ __launch_bounds__(256) void aggregate_wpn3(
    const unsigned char* __restrict__ h8, const float* __restrict__ es,
    const float* __restrict__ ed, const unsigned* __restrict__ gmax,
    const int* __restrict__ offsets, const int* __restrict__ ssrc,
    float* __restrict__ gmid, int n) {
    constexpr int HF = 384;
    __shared__ float gp[4][384];
    int wave = threadIdx.x >> 6, lane = threadIdx.x & 63;
    int wid = blockIdx.x * 4 + wave;
    int node = wid;
    int hd = lane >> 3;  // 8 lanes (64ch) per head
    int c = lane * 8;    // lane<48 guard covers all uses
    bool active = (wid < n) && (lane < 48);
    float res[8] = {};
    if (active) {
        int a = offsets[node], b = offsets[node + 1];
        float edv = ed[node * HHEADS + hd];
        float mv = funkey(gmax[hd]) + edv;
        float m = mv > 0.f ? mv : 0.2f * mv;
        float l = 0.f;
        f32x2 a0 = {0.f, 0.f}, a1 = {0.f, 0.f}, a2 = {0.f, 0.f}, a3 = {0.f, 0.f};
        const unsigned char* hbase = h8 + c;
        int j = a;
        for (; j + 3 < b; j += 4) {
            int s0 = ssrc[j], s1 = ssrc[j + 1], s2 = ssrc[j + 2], s3 = ssrc[j + 3];
            float ev0 = es[(size_t)s0 * HHEADS + hd];
            float ev1 = es[(size_t)s1 * HHEADS + hd];
            float ev2 = es[(size_t)s2 * HHEADS + hd];
            float ev3 = es[(size_t)s3 * HHEADS + hd];
            uint2 h0 = *(const uint2*)(hbase + (size_t)s0 * HF);
            uint2 h1 = *(const uint2*)(hbase + (size_t)s1 * HF);
            uint2 h2 = *(const uint2*)(hbase + (size_t)s2 * HF);
            uint2 h3 = *(const uint2*)(hbase + (size_t)s3 * HF);
            float v0 = ev0 + edv;
            v0 = v0 > 0.f ? v0 : 0.2f * v0;
            float v1 = ev1 + edv;
            v1 = v1 > 0.f ? v1 : 0.2f * v1;
            float v2 = ev2 + edv;
            v2 = v2 > 0.f ? v2 : 0.2f * v2;
            float v3 = ev3 + edv;
            v3 = v3 > 0.f ? v3 : 0.2f * v3;
            float w0 = __expf(v0 - m);
            float w1 = __expf(v1 - m);
            float w2 = __expf(v2 - m);
            float w3 = __expf(v3 - m);
            {
                f32x2 p0 = __builtin_amdgcn_cvt_pk_f32_fp8((int)h0.x, false);
                f32x2 p1 = __builtin_amdgcn_cvt_pk_f32_fp8((int)h0.x, true);
                f32x2 p2 = __builtin_amdgcn_cvt_pk_f32_fp8((int)h0.y, false);
                f32x2 p3 = __builtin_amdgcn_cvt_pk_f32_fp8((int)h0.y, true);
                f32x2 wv = {w0, w0};
                l += w0;
                a0 = a0 + wv * p0;
                a1 = a1 + wv * p1;
                a2 = a2 + wv * p2;
                a3 = a3 + wv * p3;
            }
            {
                f32x2 p0 = __builtin_amdgcn_cvt_pk_f32_fp8((int)h1.x, false);
                f32x2 p1 = __builtin_amdgcn_cvt_pk_f32_fp8((int)h1.x, true);
                f32x2 p2 = __builtin_amdgcn_cvt_pk_f32_fp8((int)h1.y, false);
                f32x2 p3 = __builtin_amdgcn_cvt_pk_f32_fp8((int)h1.y, true);
                f32x2 wv = {w1, w1};
                l += w1;
                a0 = a0 + wv * p0;
                a1 = a1 + wv * p1;
                a2 = a2 + wv * p2;
                a3 = a3 + wv * p3;
            }
            {
                f32x2 p0 = __builtin_amdgcn_cvt_pk_f32_fp8((int)h2.x, false);
                f32x2 p1 = __builtin_amdgcn_cvt_pk_f32_fp8((int)h2.x, true);
                f32x2 p2 = __builtin_amdgcn_cvt_pk_f32_fp8((int)h2.y, false);
                f32x2 p3 = __builtin_amdgcn_cvt_pk_f32_fp8((int)h2.y, true);
                f32x2 wv = {w2, w2};
                l += w2;
                a0 = a0 + wv * p0;
                a1 = a1 + wv * p1;
                a2 = a2 + wv * p2;
                a3 = a3 + wv * p3;
            }
            {
                f32x2 p0 = __builtin_amdgcn_cvt_pk_f32_fp8((int)h3.x, false);
                f32x2 p1 = __builtin_amdgcn_cvt_pk_f32_fp8((int)h3.x, true);
                f32x2 p2 = __builtin_amdgcn_cvt_pk_f32_fp8((int)h3.y, false);
                f32x2 p3 = __builtin_amdgcn_cvt_pk_f32_fp8((int)h3.y, true);
                f32x2 wv = {w3, w3};
                l += w3;
                a0 = a0 + wv * p0;
                a1 = a1 + wv * p1;
                a2 = a2 + wv * p2;
                a3 = a3 + wv * p3;
            }
        }
        for (; j < b; ++j) {
            int s0 = ssrc[j];
            float ev0 = es[(size_t)s0 * HHEADS + hd];
            uint2 h0 = *(const uint2*)(hbase + (size_t)s0 * HF);
            float v0 = ev0 + edv;
            v0 = v0 > 0.f ? v0 : 0.2f * v0;
            float w0 = __expf(v0 - m);
            f32x2 p0 = __builtin_amdgcn_cvt_pk_f32_fp8((int)h0.x, false);
            f32x2 p1 = __builtin_amdgcn_cvt_pk_f32_fp8((int)h0.x, true);
            f32x2 p2 = __builtin_amdgcn_cvt_pk_f32_fp8((int)h0.y, false);
            f32x2 p3 = __builtin_amdgcn_cvt_pk_f32_fp8((int)h0.y, true);
            f32x2 wv = {w0, w0};
            l += w0;
            a0 = a0 + wv * p0;
            a1 = a1 + wv * p1;
            a2 = a2 + wv * p2;
            a3 = a3 + wv * p3;
        }
        float invd = 1.0f / (l + 1e-16f);
        float t[8] = {a0[0], a0[1], a1[0], a1[1], a2[0], a2[1], a3[0], a3[1]};
#pragma unroll
        for (int k = 0; k < 8; ++k) {
            float v = t[k] * invd;
            res[k] = v > 0.f ? v : (__expf(v) - 1.0f);  // elu
        }
    }
    if (lane < 48) {
#pragma unroll
        for (int k = 0; k < 8; ++k) gp[wave][c + k] = res[k];
    }
    __syncthreads();
    int rep = blockIdx.x & 63;
    for (int i = threadIdx.x; i < 384; i += 256) {
        float s = gp[0][i] + gp[1][i] + gp[2][i] + gp[3][i];
        atomicAdd(&gmid[rep * 384 + i], s);
    }
}

// ---------------- final: reduce 64 replicas -> normalize -> dense ----------------
__global__ void final_kernel(const float* __restrict__ gmid, const float* __restrict__ Wd,
                             const float* __restrict__ bd, float* __restrict__ outp) {
    __shared__ float red[384];
    int t = threadIdx.x;  // blockDim = 384
    float v = 0.f;
    for (int r = 0; r < 64; ++r) v += gmid[r * 384 + t];
    red[t] = v * v;
    __syncthreads();
    for (int s = 192; s >= 3; s >>= 1) {
        if (t < s) red[t] += red[t + s];
        __syncthreads();
    }
    __shared__ float scale_s;
    if (t == 0) {
        float norm = sqrtf(red[0] + red[1] + red[2]);
        scale_s = 1.0f / fmaxf(norm, 1e-12f);
    }
    __syncthreads();
    float scale = scale_s;
    red[t] = v * scale * Wd[t];
    __syncthreads();
    for (int s = 192; s >= 3; s >>= 1) {
        if (t < s) red[t] += red[t + s];
        __syncthreads();
    }
    if (t == 0) outp[0] = red[0] + red[1] + red[2] + bd[0];
}

// ---------------- host side ----------------
extern "C" void kernel_launch(void* const* d_in, const int* in_sizes, int n_in, void* d_out,
                              int out_size, void* d_ws, size_t ws_size, hipStream_t stream) {
    const float* x = (const float*)d_in[0];
    const int* ei = (const int*)d_in[1];
    const float* W1 = (const float*)d_in[2];
    const float* a1s = (const float*)d_in[3];
    const float* a1d = (const float*)d_in[4];
    const float* W2 = (const float*)d_in[5];
    const float* a2s = (const float*)d_in[6];
    const float* a2d = (const float*)d_in[7];
    const float* W3 = (const float*)d_in[8];
    const float* a3s = (const float*)d_in[9];
    const float* a3d = (const float*)d_in[10];
    const float* Wd = (const float*)d_in[11];
    const float* bd = (const float*)d_in[12];
    float* outp = (float*)d_out;

    const int N = in_sizes[0] / 11;
    const int E = in_sizes[1] / 2;
    const int* src = ei;
    const int* dst = ei + E;

    const int NT16 = ((N + 127) / 128) * 8;  // padded 16-row tiles
    const int NMT = (N + 127) / 128;         // 128-row M-tiles

    char* w = (char*)d_ws;
    size_t off = 0;
    auto A = [&](size_t bytes) {
        size_t o = off;
        off += (bytes + 255) & ~(size_t)255;
        return o;
    };
    unsigned char* bufH = (unsigned char*)(w + A((size_t)N * 384 * 2));   // h (fp8 all layers)
    float* gmid = (float*)(w + A((size_t)N * 384 * 2));  // 64x384 pool replicas (ex-bufO)
    unsigned short* apH = (unsigned short*)(w + A((size_t)NT16 * 6 * 512 * 2));  // A-pack
    unsigned short* b2H = (unsigned short*)(w + A((size_t)16 * 3 * 512 * 2));    // W2 pack
    unsigned short* b3H = (unsigned short*)(w + A((size_t)24 * 6 * 512 * 2));    // W3 pack
    float* es = (float*)(w + A((size_t)N * HHEADS * 4));
    float* ed = (float*)(w + A((size_t)N * HHEADS * 4));
    unsigned* gmax = (unsigned*)(w + A(256));
    float* wp = (float*)(w + A((size_t)11 * 96 * 4));  // layer-1 f32 repack
    int* count = (int*)(w + A((size_t)(N + 1) * 4));
    int* cursor = (int*)(w + A((size_t)(N + 1) * 4));
    int* offsets = (int*)(w + A((size_t)(N + 1) * 4));
    int* bsum = (int*)(w + A(64 * 4));
    int* ssrc = (int*)(w + A((size_t)E * 4));

    // one-shot zero of all small scratch (count, cursor, gmid, gmax, pads)
    const long t16v = N / 16;
    const long padT = NT16 - t16v;
    zero_misc<<<(N + 255) / 256, 256, 0, stream>>>(count, cursor, gmid, gmax, apH,
                                                   t16v * 3 * 512, padT * 3 * 512,
                                                   t16v * 6 * 512, padT * 6 * 512, N);

    // CSR build (by dst)
    hist_kernel<<<(E + 255) / 256, 256, 0, stream>>>(dst, count, E);
    int nb = (N + 1023) / 1024;
    scan_block<<<nb, 1024, 0, stream>>>(count, offsets, bsum, N);
    scan_tops<<<1, 64, 0, stream>>>(bsum, nb);
    scan_add<<<nb, 1024, 0, stream>>>(offsets, bsum, N, E);
    scatter_kernel<<<(E + 255) / 256, 256, 0, stream>>>(src, dst, offsets, cursor, ssrc, E);

    // weight packs
    repack_w<<<(11 * 96 + 255) / 256, 256, 0, stream>>>(W1, wp, 11, 16);
    repack_w_mfma<<<(96 * 256 + 255) / 256, 256, 0, stream>>>(W2, b2H, 96, 32, 256);
    repack_w_mfma<<<(192 * 384 + 255) / 256, 256, 0, stream>>>(W3, b3H, 192, 64, 384);

    // ---- layer 1 (FIN=11, F=16): gemm (fp8 C) + fused attn terms ----
    {
        dim3 grid((96 + 63) / 64, (N + 63) / 64);
        gemm_small_attn<64, 64, 32><<<grid, 256, 0, stream>>>(x, wp, bufH, a1s, a1d, es, ed, N,
                                                              11, 96);
    }
    {
        long total = (long)N * (96 / 8);
        aggregate_fused<16><<<(total + 255) / 256, 256, 0, stream>>>(bufH, es, ed, offsets,
                                                                     ssrc, apH, N);
    }

    // ---- layer 2 (K=96, N=192 pad 256, F=32): fp8 C + fused gmax(6-11) ----
    {
        dim3 grid(2, (NMT + 3) / 4);
        gemm_attn_mfma<96, 192, 256, 32, 4><<<grid, 256, 0, stream>>>(apH, b2H, bufH, a2s,
                                                                      a2d, es, ed, gmax, N);
    }
    {
        int grid = (N + 3) / 4;  // 4 waves/block, wave-per-node
        aggregate_wpn2<<<grid, 256, 0, stream>>>(bufH, es, ed, gmax, offsets, ssrc, apH, N);
    }

    // ---- layer 3 (K=192, N=384, F=64): fp8 C + fused gmax(0-5) ----
    {
        dim3 grid(3, (NMT + 3) / 4);
        gemm_attn_mfma<192, 384, 384, 64, 4><<<grid, 256, 0, stream>>>(apH, b3H, bufH, a3s,
                                                                       a3d, es, ed, gmax, N);
    }
    {
        int grid = (N + 3) / 4;  // fused aggregate + sum-pool (no bufO)
        aggregate_wpn3<<<grid, 256, 0, stream>>>(bufH, es, ed, gmax, offsets, ssrc, gmid, N);
    }

    // reduce replicas -> normalize -> dense
    final_kernel<<<1, 384, 0, stream>>>(gmid, Wd, bd, outp);
}